// Round 3
// baseline (3005.698 us; speedup 1.0000x reference)
//
#include <hip/hip_runtime.h>

#define BB 4
#define NN 4096
#define DIMM 512
#define HH 8
#define DH 64
#define GSZ 128
#define NGRP 32
#define WSZ 256
#define CHUNK 32

#define MK 8388608u     // 16384*512 elements (x / q / k / v / o planes)
#define WK 262144u      // 512*512

typedef short short8 __attribute__((ext_vector_type(8)));
typedef float f32x4 __attribute__((ext_vector_type(4)));

__device__ inline unsigned short bf16rne(float f) {
  unsigned u = __float_as_uint(f);
  unsigned r = u + 0x7FFFu + ((u >> 16) & 1u);
  return (unsigned short)(r >> 16);
}
__device__ inline float bf16tof(unsigned short h) {
  return __uint_as_float(((unsigned)h) << 16);
}

// ---------------------------------------------------------------------------
// split_planes: fp32 -> 3 bf16 planes (hi, mid, lo); exact residual split
// ---------------------------------------------------------------------------
__global__ __launch_bounds__(256) void split_planes(
    const float* __restrict__ X, unsigned short* __restrict__ P)
{
  unsigned idx = (blockIdx.x * 256u + threadIdx.x) * 4u;
  float4 xv = *(const float4*)&X[idx];
  float xs[4] = {xv.x, xv.y, xv.z, xv.w};
  ushort4 hv, mv, lv;
  unsigned short* hp = (unsigned short*)&hv;
  unsigned short* mp = (unsigned short*)&mv;
  unsigned short* lp = (unsigned short*)&lv;
#pragma unroll
  for (int i = 0; i < 4; ++i) {
    unsigned short h = bf16rne(xs[i]);
    float r1 = xs[i] - bf16tof(h);
    unsigned short m = bf16rne(r1);
    float r2 = r1 - bf16tof(m);
    hp[i] = h;
    mp[i] = m;
    lp[i] = bf16rne(r2);
  }
  *(ushort4*)&P[idx] = hv;
  *(ushort4*)&P[MK + idx] = mv;
  *(ushort4*)&P[2u * MK + idx] = lv;
}

// ---------------------------------------------------------------------------
// split_w: weights -> transposed (N x K) bf16 planes.
// ---------------------------------------------------------------------------
__global__ __launch_bounds__(256) void split_w(
    const float* __restrict__ Wq, const float* __restrict__ Wk,
    const float* __restrict__ Wv, const float* __restrict__ Wpj,
    unsigned short* __restrict__ wqkv, unsigned short* __restrict__ wproj)
{
  unsigned e = blockIdx.x * 256u + threadIdx.x;     // over 4 * 2^18
  int mz = e >> 18;
  unsigned rem = e & (WK - 1u);
  unsigned kk = rem >> 9, n = rem & 511u;
  const float* src = (mz == 0) ? Wq : (mz == 1) ? Wk : (mz == 2) ? Wv : Wpj;
  float w = src[kk * 512u + n];
  unsigned short h = bf16rne(w);
  float r1 = w - bf16tof(h);
  unsigned short m = bf16rne(r1);
  float r2 = r1 - bf16tof(m);
  unsigned short l = bf16rne(r2);
  unsigned o = n * 512u + kk;
  if (mz < 3) {
    unsigned short* base = wqkv + (unsigned)mz * 3u * WK;
    base[o] = h;
    base[WK + o] = m;
    base[2u * WK + o] = l;
  } else {
    wproj[o] = h;
    wproj[WK + o] = m;
  }
}

// ---------------------------------------------------------------------------
// mfma_gemm: C[z] = A(16384x512) @ W[z](512x512) via split-bf16 MFMA.
// ---------------------------------------------------------------------------
template <int NP, int NT>
__global__ __launch_bounds__(256) void mfma_gemm(
    const unsigned short* __restrict__ Ap,   // NP planes, plane stride MK
    const unsigned short* __restrict__ Wp,   // [z][NP][n][k], plane stride WK
    float* __restrict__ C)
{
  constexpr int ta[6] = {0, 0, 1, 1, 0, 2};
  constexpr int tw[6] = {0, 1, 0, 1, 2, 0};
  const int z = blockIdx.z;
  const int n0 = blockIdx.x * 128;
  const int m0 = blockIdx.y * 128;
  const int tid = threadIdx.x;
  const int lane = tid & 63, wv = tid >> 6;
  const int wm = (wv >> 1) * 64, wn = (wv & 1) * 64;
  const int lm = lane & 15, lk = (lane >> 4) * 8;

  __shared__ unsigned short As[NP * 128 * 40];   // stride 40 bf16 = 80 B
  __shared__ unsigned short Ws[NP * 128 * 40];

  f32x4 acc[4][4];
#pragma unroll
  for (int i = 0; i < 4; ++i)
#pragma unroll
    for (int j = 0; j < 4; ++j) acc[i][j] = (f32x4){0.f, 0.f, 0.f, 0.f};

  const unsigned short* Wz = Wp + (size_t)z * NP * WK;

  for (int k0 = 0; k0 < 512; k0 += 32) {
#pragma unroll
    for (int i = 0; i < NP * 2; ++i) {
      int idx = i * 256 + tid;
      int p = idx >> 9, rem = idx & 511;
      int r = rem >> 2, cc = rem & 3;
      *(short8*)&As[p * 5120 + r * 40 + cc * 8] =
          *(const short8*)&Ap[(size_t)p * MK + (size_t)(m0 + r) * 512 + k0 + cc * 8];
      *(short8*)&Ws[p * 5120 + r * 40 + cc * 8] =
          *(const short8*)&Wz[(size_t)p * WK + (size_t)(n0 + r) * 512 + k0 + cc * 8];
    }
    __syncthreads();

    short8 a[NP][4];
#pragma unroll
    for (int p = 0; p < NP; ++p)
#pragma unroll
      for (int fm = 0; fm < 4; ++fm)
        a[p][fm] = *(const short8*)&As[p * 5120 + (wm + fm * 16 + lm) * 40 + lk];

#pragma unroll
    for (int fn = 0; fn < 4; ++fn) {
      short8 bf[NP];
#pragma unroll
      for (int p = 0; p < NP; ++p)
        bf[p] = *(const short8*)&Ws[p * 5120 + (wn + fn * 16 + lm) * 40 + lk];
#pragma unroll
      for (int fm = 0; fm < 4; ++fm) {
#pragma unroll
        for (int t = 0; t < NT; ++t)
          acc[fm][fn] = __builtin_amdgcn_mfma_f32_16x16x32_bf16(
              a[ta[t]][fm], bf[tw[t]], acc[fm][fn], 0, 0, 0);
      }
    }
    __syncthreads();
  }

  const int rq = (lane >> 4) * 4;
  float* Cz = C + (size_t)z * 8388608u;
#pragma unroll
  for (int fm = 0; fm < 4; ++fm)
#pragma unroll
    for (int fn = 0; fn < 4; ++fn) {
      int row = m0 + wm + fm * 16 + rq;
      int col = n0 + wn + fn * 16 + lm;
#pragma unroll
      for (int r = 0; r < 4; ++r)
        Cz[(size_t)(row + r) * 512 + col] = acc[fm][fn][r];
    }
}

// ---------------------------------------------------------------------------
// Fallback fp32 GEMM (only if ws too small for planes).
// ---------------------------------------------------------------------------
__global__ __launch_bounds__(256) void gemm512(
    const float* __restrict__ A,
    const float* __restrict__ W0, const float* __restrict__ W1, const float* __restrict__ W2,
    float* __restrict__ C0, float* __restrict__ C1, float* __restrict__ C2)
{
  const int z = blockIdx.z;
  const float* Wm = (z == 0) ? W0 : (z == 1 ? W1 : W2);
  float* Cm = (z == 0) ? C0 : (z == 1 ? C1 : C2);
  const int n0 = blockIdx.x * 128;
  const int m0 = blockIdx.y * 128;
  const int tid = threadIdx.x;
  const int tx = tid & 15, ty = tid >> 4;

  __shared__ float As[32][132];
  __shared__ float Bs[32][132];

  float acc[8][8];
#pragma unroll
  for (int i = 0; i < 8; ++i)
#pragma unroll
    for (int j = 0; j < 8; ++j) acc[i][j] = 0.f;

  for (int k0 = 0; k0 < 512; k0 += 32) {
    {
      const int c4 = tid & 7, r = tid >> 3;
#pragma unroll
      for (int p = 0; p < 128; p += 32) {
        float4 av = *(const float4*)&A[(size_t)(m0 + r + p) * 512 + k0 + c4 * 4];
        As[c4 * 4 + 0][r + p] = av.x;
        As[c4 * 4 + 1][r + p] = av.y;
        As[c4 * 4 + 2][r + p] = av.z;
        As[c4 * 4 + 3][r + p] = av.w;
      }
      const int j4 = tid & 31, rb = tid >> 5;
#pragma unroll
      for (int p = 0; p < 32; p += 8) {
        *(float4*)&Bs[rb + p][j4 * 4] =
            *(const float4*)&Wm[(size_t)(k0 + rb + p) * 512 + n0 + j4 * 4];
      }
    }
    __syncthreads();
#pragma unroll
    for (int kk = 0; kk < 32; ++kk) {
      float4 a0 = *(const float4*)&As[kk][ty * 8];
      float4 a1 = *(const float4*)&As[kk][ty * 8 + 4];
      float4 b0 = *(const float4*)&Bs[kk][tx * 8];
      float4 b1 = *(const float4*)&Bs[kk][tx * 8 + 4];
      float av[8] = {a0.x, a0.y, a0.z, a0.w, a1.x, a1.y, a1.z, a1.w};
      float bv[8] = {b0.x, b0.y, b0.z, b0.w, b1.x, b1.y, b1.z, b1.w};
#pragma unroll
      for (int i = 0; i < 8; ++i)
#pragma unroll
        for (int j = 0; j < 8; ++j) acc[i][j] += av[i] * bv[j];
    }
    __syncthreads();
  }
#pragma unroll
  for (int i = 0; i < 8; ++i) {
    size_t row = (size_t)(m0 + ty * 8 + i);
    float4 o0 = make_float4(acc[i][0], acc[i][1], acc[i][2], acc[i][3]);
    float4 o1 = make_float4(acc[i][4], acc[i][5], acc[i][6], acc[i][7]);
    *(float4*)&Cm[row * 512 + n0 + tx * 8] = o0;
    *(float4*)&Cm[row * 512 + n0 + tx * 8 + 4] = o1;
  }
}

// ---------------------------------------------------------------------------
// focus/keep computation (shared).
// ---------------------------------------------------------------------------
__device__ __forceinline__ void focus_keep(
    const unsigned char* klab, const float* kscr, int* hist8, float* s_var,
    int* s_sk, int* s_ck, int tid, int lane, int wv)
{
  if (tid < GSZ) atomicAdd(&hist8[klab[tid]], 1);
  if (wv == 0) {
    double x0 = (double)kscr[lane], x1 = (double)kscr[lane + 64];
    double s = x0 + x1;
#pragma unroll
    for (int off = 32; off > 0; off >>= 1) s += __shfl_xor(s, off);
    double mean = s * (1.0 / 128.0);
    double d0 = x0 - mean, d1 = x1 - mean;
    double vs = d0 * d0 + d1 * d1;
#pragma unroll
    for (int off = 32; off > 0; off >>= 1) vs += __shfl_xor(vs, off);
    if (lane == 0) *s_var = (float)(vs * (1.0 / 128.0));
  }
  __syncthreads();
  if (tid == 0) {
    int bc = hist8[0];
    for (int l = 1; l < 8; ++l)
      if (hist8[l] > bc) bc = hist8[l];
    float purity = (float)bc * (1.0f / GSZ);
    float focus = 0.5f + 0.25f * purity - 0.25f * (*s_var);
    focus = fminf(fmaxf(focus, 0.25f), 0.75f);
    int keep = (int)ceilf(focus * (float)WSZ);
    keep = min(max(keep, 1), WSZ);
    int ck = keep >> 3, rem = keep & 7;          // round-half-even(keep/8)
    if (rem > 4 || (rem == 4 && (ck & 1))) ck++;
    if (ck < 1) ck = 1;
    int sk = keep - ck;
    if (sk < 1) sk = 1;
    *s_sk = sk;
    *s_ck = ck;
  }
  __syncthreads();
}

// ---------------------------------------------------------------------------
// attn v12: QK in the rank mapping (wave wv owns rows wv*8..+7; lane l owns
// cols l+64m, ktile slice jt == rank slot m) bridged through the SAME
// att[32][264] LDS buffer; rank phase is byte-for-byte v9's verified code.
// v11 failed on Output 1 after changing BOTH the QK mapping and the rank
// register path; v12 keeps only the QK mapping and reverts rank to v9.
// ktile is aliased INSIDE the att region (17.4KB <= 33.8KB; att is written
// only after the post-QK barrier), qtile is gone (q rows are wave-uniform
// global loads, L1/SMEM-served, as in v9), and PV's V-staging is gone
// (B-fragments direct from global, values bit-identical to v9's staged
// bf16s, same MFMA order). LDS 53.8 -> ~35.2KB => 4 blocks/CU; barriers
// 19 -> 13. Per-logit FMA chain keeps v9's exact expression shape:
// dd-ascending, acc += qx*kx + qy*ky + qz*kz + qw*kw, *0.125f at store.
// ---------------------------------------------------------------------------
__global__ __launch_bounds__(256, 4) void attn_v12(
    const float* __restrict__ q, const float* __restrict__ k,
    const float* __restrict__ vf,
    const int* __restrict__ labels, const float* __restrict__ scores,
    float* __restrict__ attn_out, unsigned short* __restrict__ opl)
{
  const int bx = blockIdx.x;
  const int c = bx >> 10;
  const int rblk = bx & 1023;
  const int h = rblk & 7;
  const int g = (rblk >> 3) & 31;
  const int b = rblk >> 8;
  const int r0 = c * CHUNK;
  const int tid = threadIdx.x;
  const int lane = tid & 63, wv = tid >> 6;
  const int lm = lane & 15, lq = lane >> 4;

  // att row = 264 fp32 (1056 B): fp32 logits, later hosts phi[0..263] (528B)
  // + pmid[0..263] (528B) overlays in the SAME row (wave-private, race-free).
  // During QK, the front of this region doubles as ktile f32[64][68] (17408B);
  // att logits are only written after the post-QK barrier.
  __shared__ __align__(16) unsigned char smem[32 * 264 * 4];
  float (*att)[264] = (float (*)[264])smem;
  float (*ktile)[68] = (float (*)[68])smem;
  __shared__ unsigned char klab[WSZ];
  __shared__ float kscr[WSZ];
  __shared__ int hist8[8];
  __shared__ float s_var;
  __shared__ int s_sk, s_ck;

  {
    int j = tid;
    int pos = g * GSZ + j;
    int tok = pos < NN ? pos : (2 * NN - 1 - pos);
    klab[j] = (unsigned char)labels[b * NN + tok];
    kscr[j] = scores[b * NN + tok];
  }
  if (tid < 8) hist8[tid] = 0;
  __syncthreads();
  focus_keep(klab, kscr, hist8, &s_var, &s_sk, &s_ck, tid, lane, wv);
  const int same_keep = s_sk, cross_keep = s_ck;

  const int srow = tid >> 4, sd4 = (tid & 15) * 4;

  // ---- QK^T: per jt, stage ktile (v9 staging verbatim), then lane l
  // accumulates its own column (col = jt*64 + l) against the wave's 8 q rows.
  // Per-(row,col) FMA chain identical to v9: dd 0..60 step 4, 4-term sum.
  const float* qrow[8];
#pragma unroll
  for (int rr = 0; rr < 8; ++rr)
    qrow[rr] = q + (size_t)(b * NN + g * GSZ + r0 + wv * 8 + rr) * DIMM + h * DH;

  float acc[8][4];
#pragma unroll
  for (int rr = 0; rr < 8; ++rr)
#pragma unroll
    for (int m = 0; m < 4; ++m) acc[rr][m] = 0.f;

#pragma unroll
  for (int jt = 0; jt < 4; ++jt) {
#pragma unroll
    for (int p = 0; p < 64; p += 16) {
      int j = jt * 64 + srow + p;
      int pos = g * GSZ + j;
      int tok = pos < NN ? pos : (2 * NN - 1 - pos);
      *(float4*)&ktile[srow + p][sd4] =
          *(const float4*)&k[(size_t)(b * NN + tok) * DIMM + h * DH + sd4];
    }
    __syncthreads();
#pragma unroll
    for (int dd = 0; dd < DH; dd += 4) {
      float4 kv = *(const float4*)&ktile[lane][dd];
#pragma unroll
      for (int rr = 0; rr < 8; ++rr) {
        float4 q0 = *(const float4*)(qrow[rr] + dd);
        acc[rr][jt] += q0.x * kv.x + q0.y * kv.y + q0.z * kv.z + q0.w * kv.w;
      }
    }
    __syncthreads();   // ktile reads done (also guards att writes below)
  }

  // ---- bridge: write logits into att in the v9 layout (row, col l+64m) ----
#pragma unroll
  for (int rr = 0; rr < 8; ++rr)
#pragma unroll
    for (int m = 0; m < 4; ++m)
      att[wv * 8 + rr][lane + 64 * m] = acc[rr][m] * 0.125f;
  __syncthreads();

  // ---- rank: v9 VERBATIM (reads att, writes attn_out + phi/pmid overlays) --
  {
    int kl0[4];
    float ks0[4];
#pragma unroll
    for (int m = 0; m < 4; ++m) {
      kl0[m] = klab[lane + 64 * m];
      ks0[m] = kscr[lane + 64 * m];
    }
    for (int sp = 0; sp < 4; ++sp) {
      const int rA = wv * 8 + 2 * sp, rB = rA + 1;
      const int qLA = klab[r0 + rA], qLB = klab[r0 + rB];
      const float qSA = kscr[r0 + rA], qSB = kscr[r0 + rB];
      float aA[4], aB[4];
      float mxA = -INFINITY, mxB = -INFINITY;
#pragma unroll
      for (int m = 0; m < 4; ++m) {
        aA[m] = att[rA][lane + 64 * m];
        aB[m] = att[rB][lane + 64 * m];
        mxA = fmaxf(mxA, aA[m]);
        mxB = fmaxf(mxB, aB[m]);
      }
#pragma unroll
      for (int off = 32; off > 0; off >>= 1) {
        mxA = fmaxf(mxA, __shfl_xor(mxA, off));
        mxB = fmaxf(mxB, __shfl_xor(mxB, off));
      }
      unsigned fsA[4], fcA[4], fsB[4], fcB[4];
      bool cdA[4], cdB[4];
#pragma unroll
      for (int m = 0; m < 4; ++m) {
        aA[m] = expf(aA[m] - mxA);
        aB[m] = expf(aB[m] - mxB);
        cdA[m] = (kl0[m] == qLA);
        cdB[m] = (kl0[m] == qLB);
        fsA[m] = cdA[m] ? __float_as_uint(aA[m]) : 0u;
        fsB[m] = cdB[m] ? __float_as_uint(aB[m]) : 0u;
        fcA[m] = __float_as_uint(aA[m] * (qSA * ks0[m]));
        fcB[m] = __float_as_uint(aB[m] * (qSB * ks0[m]));
      }
      unsigned tsA = 0, tcA = 0, tsB = 0, tcB = 0;
      for (int bit = 29; bit >= 0; --bit) {
        unsigned csA = tsA | (1u << bit), ccA = tcA | (1u << bit);
        unsigned csB = tsB | (1u << bit), ccB = tcB | (1u << bit);
        int nsA = 0, ncA = 0, nsB = 0, ncB = 0;
#pragma unroll
        for (int m = 0; m < 4; ++m) {
          nsA += __popcll(__ballot(fsA[m] >= csA));
          ncA += __popcll(__ballot(fcA[m] >= ccA));
          nsB += __popcll(__ballot(fsB[m] >= csB));
          ncB += __popcll(__ballot(fcB[m] >= ccB));
        }
        if (nsA >= same_keep) tsA = csA;
        if (ncA >= cross_keep) tcA = ccA;
        if (nsB >= same_keep) tsB = csB;
        if (ncB >= cross_keep) tcB = ccB;
      }
#pragma unroll
      for (int rsel = 0; rsel < 2; ++rsel) {
        const int rr = rsel ? rB : rA;
        const unsigned ts = rsel ? tsB : tsA, tc = rsel ? tcB : tcA;
        unsigned* fs = rsel ? fsB : fsA;
        unsigned* fc = rsel ? fcB : fcA;
        float* a = rsel ? aB : aA;
        bool* cand = rsel ? cdB : cdA;
        unsigned long long beqs[4], beqc[4];
        int gts = 0, gtc = 0;
#pragma unroll
        for (int m = 0; m < 4; ++m) {
          gts += __popcll(__ballot(fs[m] > ts));
          gtc += __popcll(__ballot(fc[m] > tc));
          beqs[m] = __ballot(fs[m] == ts);
          beqc[m] = __ballot(fc[m] == tc);
        }
        const int rs = same_keep - gts, rc = cross_keep - gtc;
        float pv[4];
        float S = 0.f;
        int pres = 0, prec = 0;
#pragma unroll
        for (int m = 0; m < 4; ++m) {
          int mbs = __builtin_amdgcn_mbcnt_hi((unsigned)(beqs[m] >> 32),
                     __builtin_amdgcn_mbcnt_lo((unsigned)beqs[m], 0));
          int mbc = __builtin_amdgcn_mbcnt_hi((unsigned)(beqc[m] >> 32),
                     __builtin_amdgcn_mbcnt_lo((unsigned)beqc[m], 0));
          bool keep_s = cand[m] && ((fs[m] > ts) || ((fs[m] == ts) && (pres + mbs < rs)));
          bool keep_c = (!cand[m]) && ((fc[m] > tc) || ((fc[m] == tc) && (prec + mbc < rc)));
          pv[m] = (keep_s || keep_c) ? a[m] : 0.f;
          S += pv[m];
          pres += __popcll(beqs[m]);
          prec += __popcll(beqc[m]);
        }
#pragma unroll
        for (int off = 32; off > 0; off >>= 1) S += __shfl_xor(S, off);
        const float inv = 1.0f / S;
        size_t gb = ((((size_t)b * NGRP + g) * HH + h) * GSZ + (r0 + rr)) * WSZ + lane;
        unsigned short* prow = (unsigned short*)&att[rr][0];
#pragma unroll
        for (int m = 0; m < 4; ++m) {
          float p = pv[m] * inv;
          attn_out[gb + 64 * m] = p;
          unsigned short hh = bf16rne(p);
          prow[lane + 64 * m] = hh;                          // phi
          prow[264 + lane + 64 * m] = bf16rne(p - bf16tof(hh)); // pmid
        }
      }
    }
  }
  __syncthreads();   // overlays visible to all waves for PV

  // ---- PV via MFMA: D(32x64) = P(32x256) @ V(256x64), 3-term split.
  // A-fragments from att overlays (v9 layout); V B-fragments direct from
  // global (values == v9's staged bf16s; same MFMA order -> out bit-identical).
  f32x4 acc2[2] = {(f32x4){0.f, 0.f, 0.f, 0.f}, (f32x4){0.f, 0.f, 0.f, 0.f}};
#pragma unroll
  for (int jt = 0; jt < 4; ++jt) {
    float vv[2][8];
#pragma unroll
    for (int kt = 0; kt < 2; ++kt)
#pragma unroll
      for (int i = 0; i < 8; ++i) {
        int pos = g * GSZ + jt * 64 + kt * 32 + lq * 8 + i;
        int tok = pos < NN ? pos : (2 * NN - 1 - pos);
        vv[kt][i] = vf[(size_t)(b * NN + tok) * DIMM + h * DH + wv * 16 + lm];
      }
#pragma unroll
    for (int kt = 0; kt < 2; ++kt) {
      const int koff = jt * 64 + kt * 32 + lq * 8;
      short8 ahi[2], ami[2];
#pragma unroll
      for (int mt = 0; mt < 2; ++mt) {
        const unsigned short* arow = (const unsigned short*)&att[mt * 16 + lm][0];
        ahi[mt] = *(const short8*)&arow[koff];
        ami[mt] = *(const short8*)&arow[264 + koff];
      }
      short8 bhi, bmi;
#pragma unroll
      for (int i = 0; i < 8; ++i) {
        unsigned short h0 = bf16rne(vv[kt][i]);
        bhi[i] = (short)h0;
        bmi[i] = (short)bf16rne(vv[kt][i] - bf16tof(h0));
      }
#pragma unroll
      for (int mt = 0; mt < 2; ++mt) {
        acc2[mt] = __builtin_amdgcn_mfma_f32_16x16x32_bf16(ahi[mt], bhi, acc2[mt], 0, 0, 0);
        acc2[mt] = __builtin_amdgcn_mfma_f32_16x16x32_bf16(ahi[mt], bmi, acc2[mt], 0, 0, 0);
        acc2[mt] = __builtin_amdgcn_mfma_f32_16x16x32_bf16(ami[mt], bhi, acc2[mt], 0, 0, 0);
      }
    }
  }

  // ---- o epilogue: C/D col=lane&15 (d), row=lq*4+r (+mt*16); 2 bf16 planes --
  {
    size_t rowbase = (size_t)(b * NN + g * GSZ + r0);
#pragma unroll
    for (int mt = 0; mt < 2; ++mt)
#pragma unroll
      for (int r = 0; r < 4; ++r) {
        int row = mt * 16 + lq * 4 + r;
        float val = acc2[mt][r];
        unsigned short hh = bf16rne(val);
        size_t oaddr = (rowbase + row) * 512 + h * 64 + wv * 16 + lm;
        opl[oaddr] = hh;
        opl[MK + oaddr] = bf16rne(val - bf16tof(hh));
      }
  }
}

// ---------------------------------------------------------------------------
// Fallback attn (fp32 q/k/v in, fp32 o out aliasing q) — small-ws path only.
// ---------------------------------------------------------------------------
__global__ __launch_bounds__(256, 3) void attn_f32(
    const float* q, const float* __restrict__ k, const float* __restrict__ v,
    const int* __restrict__ labels, const float* __restrict__ scores,
    float* __restrict__ attn_out, float* o)
{
  const int bx = blockIdx.x;
  const int c = bx >> 10;
  const int rblk = bx & 1023;
  const int h = rblk & 7;
  const int g = (rblk >> 3) & 31;
  const int b = rblk >> 8;
  const int r0 = c * CHUNK;
  const int tid = threadIdx.x;
  const int lane = tid & 63, wv = tid >> 6;

  __shared__ float att[CHUNK][WSZ + 4];
  __shared__ float ktile[64][DH + 4];
  __shared__ unsigned char klab[WSZ];
  __shared__ float kscr[WSZ];
  __shared__ int hist8[8];
  __shared__ float s_var;
  __shared__ int s_sk, s_ck;

  {
    int j = tid;
    int pos = g * GSZ + j;
    int tok = pos < NN ? pos : (2 * NN - 1 - pos);
    klab[j] = (unsigned char)labels[b * NN + tok];
    kscr[j] = scores[b * NN + tok];
  }
  if (tid < 8) hist8[tid] = 0;
  __syncthreads();
  focus_keep(klab, kscr, hist8, &s_var, &s_sk, &s_ck, tid, lane, wv);
  const int same_keep = s_sk, cross_keep = s_ck;

  const int rp = tid >> 4, jx = tid & 15;
  const int srow = tid >> 4, sd4 = (tid & 15) * 4;
  const float* q0p = q + (size_t)(b * NN + g * GSZ + r0 + rp) * DIMM + h * DH;
  const float* q1p = q0p + (size_t)16 * DIMM;

  for (int jt = 0; jt < 4; ++jt) {
#pragma unroll
    for (int p = 0; p < 64; p += 16) {
      int j = jt * 64 + srow + p;
      int pos = g * GSZ + j;
      int tok = pos < NN ? pos : (2 * NN - 1 - pos);
      *(float4*)&ktile[srow + p][sd4] =
          *(const float4*)&k[(size_t)(b * NN + tok) * DIMM + h * DH + sd4];
    }
    __syncthreads();
    float acc0[4] = {0.f, 0.f, 0.f, 0.f}, acc1[4] = {0.f, 0.f, 0.f, 0.f};
#pragma unroll
    for (int dd = 0; dd < DH; dd += 4) {
      float4 q0 = *(const float4*)(q0p + dd);
      float4 q1 = *(const float4*)(q1p + dd);
#pragma unroll
      for (int jj = 0; jj < 4; ++jj) {
        float4 kv = *(const float4*)&ktile[jx + 16 * jj][dd];
        acc0[jj] += q0.x * kv.x + q0.y * kv.y + q0.z * kv.z + q0.w * kv.w;
        acc1[jj] += q1.x * kv.x + q1.y * kv.y + q1.z * kv.z + q1.w * kv.w;
      }
    }
#pragma unroll
    for (int jj = 0; jj < 4; ++jj) {
      att[rp][jt * 64 + jx + 16 * jj] = acc0[jj] * 0.125f;
      att[rp + 16][jt * 64 + jx + 16 * jj] = acc1[jj] * 0.125f;
    }
    __syncthreads();
  }

  {
    int kl0[4];
    float ks0[4];
#pragma unroll
    for (int m = 0; m < 4; ++m) {
      kl0[m] = klab[lane + 64 * m];
      ks0[m] = kscr[lane + 64 * m];
    }
    for (int sp = 0; sp < 4; ++sp) {
      const int rA = wv * 8 + 2 * sp, rB = rA + 1;
      const int qLA = klab[r0 + rA], qLB = klab[r0 + rB];
      const float qSA = kscr[r0 + rA], qSB = kscr[r0 + rB];
      float aA[4], aB[4];
      float mxA = -INFINITY, mxB = -INFINITY;
#pragma unroll
      for (int m = 0; m < 4; ++m) {
        aA[m] = att[rA][lane + 64 * m];
        aB[m] = att[rB][lane + 64 * m];
        mxA = fmaxf(mxA, aA[m]);
        mxB = fmaxf(mxB, aB[m]);
      }
#pragma unroll
      for (int off = 32; off > 0; off >>= 1) {
        mxA = fmaxf(mxA, __shfl_xor(mxA, off));
        mxB = fmaxf(mxB, __shfl_xor(mxB, off));
      }
      unsigned fsA[4], fcA[4], fsB[4], fcB[4];
      bool cdA[4], cdB[4];
#pragma unroll
      for (int m = 0; m < 4; ++m) {
        aA[m] = expf(aA[m] - mxA);
        aB[m] = expf(aB[m] - mxB);
        cdA[m] = (kl0[m] == qLA);
        cdB[m] = (kl0[m] == qLB);
        fsA[m] = cdA[m] ? __float_as_uint(aA[m]) : 0u;
        fsB[m] = cdB[m] ? __float_as_uint(aB[m]) : 0u;
        fcA[m] = __float_as_uint(aA[m] * (qSA * ks0[m]));
        fcB[m] = __float_as_uint(aB[m] * (qSB * ks0[m]));
      }
      unsigned tsA = 0, tcA = 0, tsB = 0, tcB = 0;
      for (int bit = 29; bit >= 0; --bit) {
        unsigned csA = tsA | (1u << bit), ccA = tcA | (1u << bit);
        unsigned csB = tsB | (1u << bit), ccB = tcB | (1u << bit);
        int nsA = 0, ncA = 0, nsB = 0, ncB = 0;
#pragma unroll
        for (int m = 0; m < 4; ++m) {
          nsA += __popcll(__ballot(fsA[m] >= csA));
          ncA += __popcll(__ballot(fcA[m] >= ccA));
          nsB += __popcll(__ballot(fsB[m] >= csB));
          ncB += __popcll(__ballot(fcB[m] >= ccB));
        }
        if (nsA >= same_keep) tsA = csA;
        if (ncA >= cross_keep) tcA = ccA;
        if (nsB >= same_keep) tsB = csB;
        if (ncB >= cross_keep) tcB = ccB;
      }
#pragma unroll
      for (int rsel = 0; rsel < 2; ++rsel) {
        const int rr = rsel ? rB : rA;
        const unsigned ts = rsel ? tsB : tsA, tc = rsel ? tcB : tcA;
        unsigned* fs = rsel ? fsB : fsA;
        unsigned* fc = rsel ? fcB : fcA;
        float* a = rsel ? aB : aA;
        bool* cand = rsel ? cdB : cdA;
        unsigned long long beqs[4], beqc[4];
        int gts = 0, gtc = 0;
#pragma unroll
        for (int m = 0; m < 4; ++m) {
          gts += __popcll(__ballot(fs[m] > ts));
          gtc += __popcll(__ballot(fc[m] > tc));
          beqs[m] = __ballot(fs[m] == ts);
          beqc[m] = __ballot(fc[m] == tc);
        }
        const int rs = same_keep - gts, rc = cross_keep - gtc;
        float pv[4];
        float S = 0.f;
        int pres = 0, prec = 0;
#pragma unroll
        for (int m = 0; m < 4; ++m) {
          int mbs = __builtin_amdgcn_mbcnt_hi((unsigned)(beqs[m] >> 32),
                     __builtin_amdgcn_mbcnt_lo((unsigned)beqs[m], 0));
          int mbc = __builtin_amdgcn_mbcnt_hi((unsigned)(beqc[m] >> 32),
                     __builtin_amdgcn_mbcnt_lo((unsigned)beqc[m], 0));
          bool keep_s = cand[m] && ((fs[m] > ts) || ((fs[m] == ts) && (pres + mbs < rs)));
          bool keep_c = (!cand[m]) && ((fc[m] > tc) || ((fc[m] == tc) && (prec + mbc < rc)));
          pv[m] = (keep_s || keep_c) ? a[m] : 0.f;
          S += pv[m];
          pres += __popcll(beqs[m]);
          prec += __popcll(beqc[m]);
        }
#pragma unroll
        for (int off = 32; off > 0; off >>= 1) S += __shfl_xor(S, off);
        const float inv = 1.0f / S;
        size_t gb = ((((size_t)b * NGRP + g) * HH + h) * GSZ + (r0 + rr)) * WSZ + lane;
#pragma unroll
        for (int m = 0; m < 4; ++m) {
          float p = pv[m] * inv;
          att[rr][lane + 64 * m] = p;
          attn_out[gb + 64 * m] = p;
        }
      }
    }
  }
  __syncthreads();

  const int dx = jx;
  float oa0[4] = {0.f, 0.f, 0.f, 0.f}, oa1[4] = {0.f, 0.f, 0.f, 0.f};
  for (int jt = 0; jt < 4; ++jt) {
#pragma unroll
    for (int p = 0; p < 64; p += 16) {
      int j = jt * 64 + srow + p;
      int pos = g * GSZ + j;
      int tok = pos < NN ? pos : (2 * NN - 1 - pos);
      *(float4*)&ktile[srow + p][sd4] =
          *(const float4*)&v[(size_t)(b * NN + tok) * DIMM + h * DH + sd4];
    }
    __syncthreads();
#pragma unroll 4
    for (int jg = 0; jg < 16; ++jg) {
      float4 p0 = *(const float4*)&att[rp][jt * 64 + jg * 4];
      float4 p1 = *(const float4*)&att[rp + 16][jt * 64 + jg * 4];
      float4 v0 = *(const float4*)&ktile[jg * 4 + 0][dx * 4];
      float4 v1 = *(const float4*)&ktile[jg * 4 + 1][dx * 4];
      float4 v2 = *(const float4*)&ktile[jg * 4 + 2][dx * 4];
      float4 v3 = *(const float4*)&ktile[jg * 4 + 3][dx * 4];
      oa0[0] += p0.x * v0.x + p0.y * v1.x + p0.z * v2.x + p0.w * v3.x;
      oa0[1] += p0.x * v0.y + p0.y * v1.y + p0.z * v2.y + p0.w * v3.y;
      oa0[2] += p0.x * v0.z + p0.y * v1.z + p0.z * v2.z + p0.w * v3.z;
      oa0[3] += p0.x * v0.w + p0.y * v1.w + p0.z * v2.w + p0.w * v3.w;
      oa1[0] += p1.x * v0.x + p1.y * v1.x + p1.z * v2.x + p1.w * v3.x;
      oa1[1] += p1.x * v0.y + p1.y * v1.y + p1.z * v2.y + p1.w * v3.y;
      oa1[2] += p1.x * v0.z + p1.y * v1.z + p1.z * v2.z + p1.w * v3.z;
      oa1[3] += p1.x * v0.w + p1.y * v1.w + p1.z * v2.w + p1.w * v3.w;
    }
    __syncthreads();
  }
  {
    size_t ob0 = (size_t)(b * NN + g * GSZ + r0 + rp) * DIMM + h * DH + dx * 4;
    *(float4*)&o[ob0] = make_float4(oa0[0], oa0[1], oa0[2], oa0[3]);
    *(float4*)&o[ob0 + (size_t)16 * DIMM] = make_float4(oa1[0], oa1[1], oa1[2], oa1[3]);
  }
}

// ---------------------------------------------------------------------------
extern "C" void kernel_launch(void* const* d_in, const int* in_sizes, int n_in,
                              void* d_out, int out_size, void* d_ws, size_t ws_size,
                              hipStream_t stream) {
  const float* x      = (const float*)d_in[0];
  const int*   labels = (const int*)d_in[1];
  const float* scores = (const float*)d_in[2];
  const float* Wq     = (const float*)d_in[3];
  const float* Wk     = (const float*)d_in[4];
  const float* Wv     = (const float*)d_in[5];
  const float* Wproj  = (const float*)d_in[6];

  float* out = (float*)d_out;                               // (B, N, DIM)
  float* attn_out = out + (size_t)BB * NN * DIMM;           // (B, ng, H, gs, ws)

  // layout: qb|kb|vf (fp32) | xpl (3 planes; reused as opl) | weights
  float* qb = (float*)d_ws;
  float* kb = qb + (size_t)MK;
  float* vf = kb + (size_t)MK;
  unsigned short* xpl  = (unsigned short*)(vf + (size_t)MK);
  unsigned short* wqkv = xpl + 3 * (size_t)MK;
  unsigned short* wpp  = wqkv + 9 * (size_t)WK;
  const size_t required = 3 * (size_t)MK * 4 + 3 * (size_t)MK * 2 + 11 * (size_t)WK * 2;

  if (ws_size >= required) {
    split_planes<<<dim3(MK / 1024), 256, 0, stream>>>(x, xpl);
    split_w<<<dim3(4 * WK / 256), 256, 0, stream>>>(Wq, Wk, Wv, Wproj, wqkv, wpp);
    // q,k fp32 via 6-term (bit-identical to R5/R8 selection inputs); v 3-term
    mfma_gemm<3, 6><<<dim3(4, 128, 2), 256, 0, stream>>>(xpl, wqkv, qb);
    mfma_gemm<2, 3><<<dim3(4, 128, 1), 256, 0, stream>>>(xpl, wqkv + 6 * (size_t)WK, vf);
    attn_v12<<<dim3(BB * NGRP * HH * 4), 256, 0, stream>>>(
        qb, kb, vf, labels, scores, attn_out, xpl);
    mfma_gemm<2, 3><<<dim3(4, 128, 1), 256, 0, stream>>>(xpl, wpp, out);
  } else {
    const size_t SZ = (size_t)BB * NN * DIMM;
    float* q2 = (float*)d_ws;
    float* k2 = q2 + SZ;
    float* v2 = k2 + SZ;
    gemm512<<<dim3(4, 128, 3), 256, 0, stream>>>(x, Wq, Wk, Wv, q2, k2, v2);
    attn_f32<<<dim3(BB * NGRP * HH * 4), 256, 0, stream>>>(
        q2, k2, v2, labels, scores, attn_out, q2);
    gemm512<<<dim3(4, 128, 1), 256, 0, stream>>>(q2, Wproj, Wproj, Wproj, out, out, out);
  }
}

// Round 4
// 2733.824 us; speedup vs baseline: 1.0994x; 1.0994x over previous
//
#include <hip/hip_runtime.h>

#define BB 4
#define NN 4096
#define DIMM 512
#define HH 8
#define DH 64
#define GSZ 128
#define NGRP 32
#define WSZ 256
#define CHUNK 32

#define MK 8388608u     // 16384*512 elements (x / q / k / v / o planes)
#define WK 262144u      // 512*512

typedef short short8 __attribute__((ext_vector_type(8)));
typedef float f32x4 __attribute__((ext_vector_type(4)));

__device__ inline unsigned short bf16rne(float f) {
  unsigned u = __float_as_uint(f);
  unsigned r = u + 0x7FFFu + ((u >> 16) & 1u);
  return (unsigned short)(r >> 16);
}
__device__ inline float bf16tof(unsigned short h) {
  return __uint_as_float(((unsigned)h) << 16);
}

// ---------------------------------------------------------------------------
// split_planes: fp32 -> 3 bf16 planes (hi, mid, lo); exact residual split
// ---------------------------------------------------------------------------
__global__ __launch_bounds__(256) void split_planes(
    const float* __restrict__ X, unsigned short* __restrict__ P)
{
  unsigned idx = (blockIdx.x * 256u + threadIdx.x) * 4u;
  float4 xv = *(const float4*)&X[idx];
  float xs[4] = {xv.x, xv.y, xv.z, xv.w};
  ushort4 hv, mv, lv;
  unsigned short* hp = (unsigned short*)&hv;
  unsigned short* mp = (unsigned short*)&mv;
  unsigned short* lp = (unsigned short*)&lv;
#pragma unroll
  for (int i = 0; i < 4; ++i) {
    unsigned short h = bf16rne(xs[i]);
    float r1 = xs[i] - bf16tof(h);
    unsigned short m = bf16rne(r1);
    float r2 = r1 - bf16tof(m);
    hp[i] = h;
    mp[i] = m;
    lp[i] = bf16rne(r2);
  }
  *(ushort4*)&P[idx] = hv;
  *(ushort4*)&P[MK + idx] = mv;
  *(ushort4*)&P[2u * MK + idx] = lv;
}

// ---------------------------------------------------------------------------
// split_w: weights -> transposed (N x K) bf16 planes.
// ---------------------------------------------------------------------------
__global__ __launch_bounds__(256) void split_w(
    const float* __restrict__ Wq, const float* __restrict__ Wk,
    const float* __restrict__ Wv, const float* __restrict__ Wpj,
    unsigned short* __restrict__ wqkv, unsigned short* __restrict__ wproj)
{
  unsigned e = blockIdx.x * 256u + threadIdx.x;     // over 4 * 2^18
  int mz = e >> 18;
  unsigned rem = e & (WK - 1u);
  unsigned kk = rem >> 9, n = rem & 511u;
  const float* src = (mz == 0) ? Wq : (mz == 1) ? Wk : (mz == 2) ? Wv : Wpj;
  float w = src[kk * 512u + n];
  unsigned short h = bf16rne(w);
  float r1 = w - bf16tof(h);
  unsigned short m = bf16rne(r1);
  float r2 = r1 - bf16tof(m);
  unsigned short l = bf16rne(r2);
  unsigned o = n * 512u + kk;
  if (mz < 3) {
    unsigned short* base = wqkv + (unsigned)mz * 3u * WK;
    base[o] = h;
    base[WK + o] = m;
    base[2u * WK + o] = l;
  } else {
    wproj[o] = h;
    wproj[WK + o] = m;
  }
}

// ---------------------------------------------------------------------------
// mfma_gemm: C[z] = A(16384x512) @ W[z](512x512) via split-bf16 MFMA.
// ---------------------------------------------------------------------------
template <int NP, int NT>
__global__ __launch_bounds__(256) void mfma_gemm(
    const unsigned short* __restrict__ Ap,   // NP planes, plane stride MK
    const unsigned short* __restrict__ Wp,   // [z][NP][n][k], plane stride WK
    float* __restrict__ C)
{
  constexpr int ta[6] = {0, 0, 1, 1, 0, 2};
  constexpr int tw[6] = {0, 1, 0, 1, 2, 0};
  const int z = blockIdx.z;
  const int n0 = blockIdx.x * 128;
  const int m0 = blockIdx.y * 128;
  const int tid = threadIdx.x;
  const int lane = tid & 63, wv = tid >> 6;
  const int wm = (wv >> 1) * 64, wn = (wv & 1) * 64;
  const int lm = lane & 15, lk = (lane >> 4) * 8;

  __shared__ unsigned short As[NP * 128 * 40];   // stride 40 bf16 = 80 B
  __shared__ unsigned short Ws[NP * 128 * 40];

  f32x4 acc[4][4];
#pragma unroll
  for (int i = 0; i < 4; ++i)
#pragma unroll
    for (int j = 0; j < 4; ++j) acc[i][j] = (f32x4){0.f, 0.f, 0.f, 0.f};

  const unsigned short* Wz = Wp + (size_t)z * NP * WK;

  for (int k0 = 0; k0 < 512; k0 += 32) {
#pragma unroll
    for (int i = 0; i < NP * 2; ++i) {
      int idx = i * 256 + tid;
      int p = idx >> 9, rem = idx & 511;
      int r = rem >> 2, cc = rem & 3;
      *(short8*)&As[p * 5120 + r * 40 + cc * 8] =
          *(const short8*)&Ap[(size_t)p * MK + (size_t)(m0 + r) * 512 + k0 + cc * 8];
      *(short8*)&Ws[p * 5120 + r * 40 + cc * 8] =
          *(const short8*)&Wz[(size_t)p * WK + (size_t)(n0 + r) * 512 + k0 + cc * 8];
    }
    __syncthreads();

    short8 a[NP][4];
#pragma unroll
    for (int p = 0; p < NP; ++p)
#pragma unroll
      for (int fm = 0; fm < 4; ++fm)
        a[p][fm] = *(const short8*)&As[p * 5120 + (wm + fm * 16 + lm) * 40 + lk];

#pragma unroll
    for (int fn = 0; fn < 4; ++fn) {
      short8 bf[NP];
#pragma unroll
      for (int p = 0; p < NP; ++p)
        bf[p] = *(const short8*)&Ws[p * 5120 + (wn + fn * 16 + lm) * 40 + lk];
#pragma unroll
      for (int fm = 0; fm < 4; ++fm) {
#pragma unroll
        for (int t = 0; t < NT; ++t)
          acc[fm][fn] = __builtin_amdgcn_mfma_f32_16x16x32_bf16(
              a[ta[t]][fm], bf[tw[t]], acc[fm][fn], 0, 0, 0);
      }
    }
    __syncthreads();
  }

  const int rq = (lane >> 4) * 4;
  float* Cz = C + (size_t)z * 8388608u;
#pragma unroll
  for (int fm = 0; fm < 4; ++fm)
#pragma unroll
    for (int fn = 0; fn < 4; ++fn) {
      int row = m0 + wm + fm * 16 + rq;
      int col = n0 + wn + fn * 16 + lm;
#pragma unroll
      for (int r = 0; r < 4; ++r)
        Cz[(size_t)(row + r) * 512 + col] = acc[fm][fn][r];
    }
}

// ---------------------------------------------------------------------------
// Fallback fp32 GEMM (only if ws too small for planes).
// ---------------------------------------------------------------------------
__global__ __launch_bounds__(256) void gemm512(
    const float* __restrict__ A,
    const float* __restrict__ W0, const float* __restrict__ W1, const float* __restrict__ W2,
    float* __restrict__ C0, float* __restrict__ C1, float* __restrict__ C2)
{
  const int z = blockIdx.z;
  const float* Wm = (z == 0) ? W0 : (z == 1 ? W1 : W2);
  float* Cm = (z == 0) ? C0 : (z == 1 ? C1 : C2);
  const int n0 = blockIdx.x * 128;
  const int m0 = blockIdx.y * 128;
  const int tid = threadIdx.x;
  const int tx = tid & 15, ty = tid >> 4;

  __shared__ float As[32][132];
  __shared__ float Bs[32][132];

  float acc[8][8];
#pragma unroll
  for (int i = 0; i < 8; ++i)
#pragma unroll
    for (int j = 0; j < 8; ++j) acc[i][j] = 0.f;

  for (int k0 = 0; k0 < 512; k0 += 32) {
    {
      const int c4 = tid & 7, r = tid >> 3;
#pragma unroll
      for (int p = 0; p < 128; p += 32) {
        float4 av = *(const float4*)&A[(size_t)(m0 + r + p) * 512 + k0 + c4 * 4];
        As[c4 * 4 + 0][r + p] = av.x;
        As[c4 * 4 + 1][r + p] = av.y;
        As[c4 * 4 + 2][r + p] = av.z;
        As[c4 * 4 + 3][r + p] = av.w;
      }
      const int j4 = tid & 31, rb = tid >> 5;
#pragma unroll
      for (int p = 0; p < 32; p += 8) {
        *(float4*)&Bs[rb + p][j4 * 4] =
            *(const float4*)&Wm[(size_t)(k0 + rb + p) * 512 + n0 + j4 * 4];
      }
    }
    __syncthreads();
#pragma unroll
    for (int kk = 0; kk < 32; ++kk) {
      float4 a0 = *(const float4*)&As[kk][ty * 8];
      float4 a1 = *(const float4*)&As[kk][ty * 8 + 4];
      float4 b0 = *(const float4*)&Bs[kk][tx * 8];
      float4 b1 = *(const float4*)&Bs[kk][tx * 8 + 4];
      float av[8] = {a0.x, a0.y, a0.z, a0.w, a1.x, a1.y, a1.z, a1.w};
      float bv[8] = {b0.x, b0.y, b0.z, b0.w, b1.x, b1.y, b1.z, b1.w};
#pragma unroll
      for (int i = 0; i < 8; ++i)
#pragma unroll
        for (int j = 0; j < 8; ++j) acc[i][j] += av[i] * bv[j];
    }
    __syncthreads();
  }
#pragma unroll
  for (int i = 0; i < 8; ++i) {
    size_t row = (size_t)(m0 + ty * 8 + i);
    float4 o0 = make_float4(acc[i][0], acc[i][1], acc[i][2], acc[i][3]);
    float4 o1 = make_float4(acc[i][4], acc[i][5], acc[i][6], acc[i][7]);
    *(float4*)&Cm[row * 512 + n0 + tx * 8] = o0;
    *(float4*)&Cm[row * 512 + n0 + tx * 8 + 4] = o1;
  }
}

// ---------------------------------------------------------------------------
// focus/keep computation (shared).
// ---------------------------------------------------------------------------
__device__ __forceinline__ void focus_keep(
    const unsigned char* klab, const float* kscr, int* hist8, float* s_var,
    int* s_sk, int* s_ck, int tid, int lane, int wv)
{
  if (tid < GSZ) atomicAdd(&hist8[klab[tid]], 1);
  if (wv == 0) {
    double x0 = (double)kscr[lane], x1 = (double)kscr[lane + 64];
    double s = x0 + x1;
#pragma unroll
    for (int off = 32; off > 0; off >>= 1) s += __shfl_xor(s, off);
    double mean = s * (1.0 / 128.0);
    double d0 = x0 - mean, d1 = x1 - mean;
    double vs = d0 * d0 + d1 * d1;
#pragma unroll
    for (int off = 32; off > 0; off >>= 1) vs += __shfl_xor(vs, off);
    if (lane == 0) *s_var = (float)(vs * (1.0 / 128.0));
  }
  __syncthreads();
  if (tid == 0) {
    int bc = hist8[0];
    for (int l = 1; l < 8; ++l)
      if (hist8[l] > bc) bc = hist8[l];
    float purity = (float)bc * (1.0f / GSZ);
    float focus = 0.5f + 0.25f * purity - 0.25f * (*s_var);
    focus = fminf(fmaxf(focus, 0.25f), 0.75f);
    int keep = (int)ceilf(focus * (float)WSZ);
    keep = min(max(keep, 1), WSZ);
    int ck = keep >> 3, rem = keep & 7;          // round-half-even(keep/8)
    if (rem > 4 || (rem == 4 && (ck & 1))) ck++;
    if (ck < 1) ck = 1;
    int sk = keep - ck;
    if (sk < 1) sk = 1;
    *s_sk = sk;
    *s_ck = ck;
  }
  __syncthreads();
}

// ---------------------------------------------------------------------------
// attn v13 == v12 numerics (verified correct, absmax 0.0039) with ONE change:
// __launch_bounds__(256,4) -> __launch_bounds__(256). v12's counters showed
// VGPR_Count=64 (the 8-waves/SIMD breakpoint) + 6.4 GB/dispatch of HBM traffic
// (FETCH 2.26 GB / WRITE 3.99 GB vs ~0.3 GB algorithmic) + VALUBusy 9.8%:
// the min-waves request made the allocator squeeze to 64 VGPRs and spill
// ~5.5 KB/thread to scratch. Without the request the allocator uses what the
// kernel needs (~96-128 VGPRs, no spill); occupancy stays 4 blocks/CU via the
// 35.3 KB LDS cap. Structure: QK in the rank mapping bridged through the
// att[32][264] buffer; rank phase byte-for-byte v9; ktile aliased inside att;
// PV A-fragments from att overlays, V B-fragments direct from global.
// ---------------------------------------------------------------------------
__global__ __launch_bounds__(256) void attn_v13(
    const float* __restrict__ q, const float* __restrict__ k,
    const float* __restrict__ vf,
    const int* __restrict__ labels, const float* __restrict__ scores,
    float* __restrict__ attn_out, unsigned short* __restrict__ opl)
{
  const int bx = blockIdx.x;
  const int c = bx >> 10;
  const int rblk = bx & 1023;
  const int h = rblk & 7;
  const int g = (rblk >> 3) & 31;
  const int b = rblk >> 8;
  const int r0 = c * CHUNK;
  const int tid = threadIdx.x;
  const int lane = tid & 63, wv = tid >> 6;
  const int lm = lane & 15, lq = lane >> 4;

  // att row = 264 fp32 (1056 B): fp32 logits, later hosts phi[0..263] (528B)
  // + pmid[0..263] (528B) overlays in the SAME row (wave-private, race-free).
  // During QK, the front of this region doubles as ktile f32[64][68] (17408B);
  // att logits are only written after the post-QK barrier.
  __shared__ __align__(16) unsigned char smem[32 * 264 * 4];
  float (*att)[264] = (float (*)[264])smem;
  float (*ktile)[68] = (float (*)[68])smem;
  __shared__ unsigned char klab[WSZ];
  __shared__ float kscr[WSZ];
  __shared__ int hist8[8];
  __shared__ float s_var;
  __shared__ int s_sk, s_ck;

  {
    int j = tid;
    int pos = g * GSZ + j;
    int tok = pos < NN ? pos : (2 * NN - 1 - pos);
    klab[j] = (unsigned char)labels[b * NN + tok];
    kscr[j] = scores[b * NN + tok];
  }
  if (tid < 8) hist8[tid] = 0;
  __syncthreads();
  focus_keep(klab, kscr, hist8, &s_var, &s_sk, &s_ck, tid, lane, wv);
  const int same_keep = s_sk, cross_keep = s_ck;

  const int srow = tid >> 4, sd4 = (tid & 15) * 4;

  // ---- QK^T: per jt, stage ktile (v9 staging verbatim), then lane l
  // accumulates its own column (col = jt*64 + l) against the wave's 8 q rows.
  // Per-(row,col) FMA chain identical to v9: dd 0..60 step 4, 4-term sum.
  const float* qrow[8];
#pragma unroll
  for (int rr = 0; rr < 8; ++rr)
    qrow[rr] = q + (size_t)(b * NN + g * GSZ + r0 + wv * 8 + rr) * DIMM + h * DH;

  float acc[8][4];
#pragma unroll
  for (int rr = 0; rr < 8; ++rr)
#pragma unroll
    for (int m = 0; m < 4; ++m) acc[rr][m] = 0.f;

#pragma unroll
  for (int jt = 0; jt < 4; ++jt) {
#pragma unroll
    for (int p = 0; p < 64; p += 16) {
      int j = jt * 64 + srow + p;
      int pos = g * GSZ + j;
      int tok = pos < NN ? pos : (2 * NN - 1 - pos);
      *(float4*)&ktile[srow + p][sd4] =
          *(const float4*)&k[(size_t)(b * NN + tok) * DIMM + h * DH + sd4];
    }
    __syncthreads();
#pragma unroll
    for (int dd = 0; dd < DH; dd += 4) {
      float4 kv = *(const float4*)&ktile[lane][dd];
#pragma unroll
      for (int rr = 0; rr < 8; ++rr) {
        float4 q0 = *(const float4*)(qrow[rr] + dd);
        acc[rr][jt] += q0.x * kv.x + q0.y * kv.y + q0.z * kv.z + q0.w * kv.w;
      }
    }
    __syncthreads();   // ktile reads done (also guards att writes below)
  }

  // ---- bridge: write logits into att in the v9 layout (row, col l+64m) ----
#pragma unroll
  for (int rr = 0; rr < 8; ++rr)
#pragma unroll
    for (int m = 0; m < 4; ++m)
      att[wv * 8 + rr][lane + 64 * m] = acc[rr][m] * 0.125f;
  __syncthreads();

  // ---- rank: v9 VERBATIM (reads att, writes attn_out + phi/pmid overlays) --
  {
    int kl0[4];
    float ks0[4];
#pragma unroll
    for (int m = 0; m < 4; ++m) {
      kl0[m] = klab[lane + 64 * m];
      ks0[m] = kscr[lane + 64 * m];
    }
    for (int sp = 0; sp < 4; ++sp) {
      const int rA = wv * 8 + 2 * sp, rB = rA + 1;
      const int qLA = klab[r0 + rA], qLB = klab[r0 + rB];
      const float qSA = kscr[r0 + rA], qSB = kscr[r0 + rB];
      float aA[4], aB[4];
      float mxA = -INFINITY, mxB = -INFINITY;
#pragma unroll
      for (int m = 0; m < 4; ++m) {
        aA[m] = att[rA][lane + 64 * m];
        aB[m] = att[rB][lane + 64 * m];
        mxA = fmaxf(mxA, aA[m]);
        mxB = fmaxf(mxB, aB[m]);
      }
#pragma unroll
      for (int off = 32; off > 0; off >>= 1) {
        mxA = fmaxf(mxA, __shfl_xor(mxA, off));
        mxB = fmaxf(mxB, __shfl_xor(mxB, off));
      }
      unsigned fsA[4], fcA[4], fsB[4], fcB[4];
      bool cdA[4], cdB[4];
#pragma unroll
      for (int m = 0; m < 4; ++m) {
        aA[m] = expf(aA[m] - mxA);
        aB[m] = expf(aB[m] - mxB);
        cdA[m] = (kl0[m] == qLA);
        cdB[m] = (kl0[m] == qLB);
        fsA[m] = cdA[m] ? __float_as_uint(aA[m]) : 0u;
        fsB[m] = cdB[m] ? __float_as_uint(aB[m]) : 0u;
        fcA[m] = __float_as_uint(aA[m] * (qSA * ks0[m]));
        fcB[m] = __float_as_uint(aB[m] * (qSB * ks0[m]));
      }
      unsigned tsA = 0, tcA = 0, tsB = 0, tcB = 0;
      for (int bit = 29; bit >= 0; --bit) {
        unsigned csA = tsA | (1u << bit), ccA = tcA | (1u << bit);
        unsigned csB = tsB | (1u << bit), ccB = tcB | (1u << bit);
        int nsA = 0, ncA = 0, nsB = 0, ncB = 0;
#pragma unroll
        for (int m = 0; m < 4; ++m) {
          nsA += __popcll(__ballot(fsA[m] >= csA));
          ncA += __popcll(__ballot(fcA[m] >= ccA));
          nsB += __popcll(__ballot(fsB[m] >= csB));
          ncB += __popcll(__ballot(fcB[m] >= ccB));
        }
        if (nsA >= same_keep) tsA = csA;
        if (ncA >= cross_keep) tcA = ccA;
        if (nsB >= same_keep) tsB = csB;
        if (ncB >= cross_keep) tcB = ccB;
      }
#pragma unroll
      for (int rsel = 0; rsel < 2; ++rsel) {
        const int rr = rsel ? rB : rA;
        const unsigned ts = rsel ? tsB : tsA, tc = rsel ? tcB : tcA;
        unsigned* fs = rsel ? fsB : fsA;
        unsigned* fc = rsel ? fcB : fcA;
        float* a = rsel ? aB : aA;
        bool* cand = rsel ? cdB : cdA;
        unsigned long long beqs[4], beqc[4];
        int gts = 0, gtc = 0;
#pragma unroll
        for (int m = 0; m < 4; ++m) {
          gts += __popcll(__ballot(fs[m] > ts));
          gtc += __popcll(__ballot(fc[m] > tc));
          beqs[m] = __ballot(fs[m] == ts);
          beqc[m] = __ballot(fc[m] == tc);
        }
        const int rs = same_keep - gts, rc = cross_keep - gtc;
        float pv[4];
        float S = 0.f;
        int pres = 0, prec = 0;
#pragma unroll
        for (int m = 0; m < 4; ++m) {
          int mbs = __builtin_amdgcn_mbcnt_hi((unsigned)(beqs[m] >> 32),
                     __builtin_amdgcn_mbcnt_lo((unsigned)beqs[m], 0));
          int mbc = __builtin_amdgcn_mbcnt_hi((unsigned)(beqc[m] >> 32),
                     __builtin_amdgcn_mbcnt_lo((unsigned)beqc[m], 0));
          bool keep_s = cand[m] && ((fs[m] > ts) || ((fs[m] == ts) && (pres + mbs < rs)));
          bool keep_c = (!cand[m]) && ((fc[m] > tc) || ((fc[m] == tc) && (prec + mbc < rc)));
          pv[m] = (keep_s || keep_c) ? a[m] : 0.f;
          S += pv[m];
          pres += __popcll(beqs[m]);
          prec += __popcll(beqc[m]);
        }
#pragma unroll
        for (int off = 32; off > 0; off >>= 1) S += __shfl_xor(S, off);
        const float inv = 1.0f / S;
        size_t gb = ((((size_t)b * NGRP + g) * HH + h) * GSZ + (r0 + rr)) * WSZ + lane;
        unsigned short* prow = (unsigned short*)&att[rr][0];
#pragma unroll
        for (int m = 0; m < 4; ++m) {
          float p = pv[m] * inv;
          attn_out[gb + 64 * m] = p;
          unsigned short hh = bf16rne(p);
          prow[lane + 64 * m] = hh;                          // phi
          prow[264 + lane + 64 * m] = bf16rne(p - bf16tof(hh)); // pmid
        }
      }
    }
  }
  __syncthreads();   // overlays visible to all waves for PV

  // ---- PV via MFMA: D(32x64) = P(32x256) @ V(256x64), 3-term split.
  // A-fragments from att overlays (v9 layout); V B-fragments direct from
  // global (values == v9's staged bf16s; same MFMA order -> out bit-identical).
  f32x4 acc2[2] = {(f32x4){0.f, 0.f, 0.f, 0.f}, (f32x4){0.f, 0.f, 0.f, 0.f}};
#pragma unroll
  for (int jt = 0; jt < 4; ++jt) {
    float vv[2][8];
#pragma unroll
    for (int kt = 0; kt < 2; ++kt)
#pragma unroll
      for (int i = 0; i < 8; ++i) {
        int pos = g * GSZ + jt * 64 + kt * 32 + lq * 8 + i;
        int tok = pos < NN ? pos : (2 * NN - 1 - pos);
        vv[kt][i] = vf[(size_t)(b * NN + tok) * DIMM + h * DH + wv * 16 + lm];
      }
#pragma unroll
    for (int kt = 0; kt < 2; ++kt) {
      const int koff = jt * 64 + kt * 32 + lq * 8;
      short8 ahi[2], ami[2];
#pragma unroll
      for (int mt = 0; mt < 2; ++mt) {
        const unsigned short* arow = (const unsigned short*)&att[mt * 16 + lm][0];
        ahi[mt] = *(const short8*)&arow[koff];
        ami[mt] = *(const short8*)&arow[264 + koff];
      }
      short8 bhi, bmi;
#pragma unroll
      for (int i = 0; i < 8; ++i) {
        unsigned short h0 = bf16rne(vv[kt][i]);
        bhi[i] = (short)h0;
        bmi[i] = (short)bf16rne(vv[kt][i] - bf16tof(h0));
      }
#pragma unroll
      for (int mt = 0; mt < 2; ++mt) {
        acc2[mt] = __builtin_amdgcn_mfma_f32_16x16x32_bf16(ahi[mt], bhi, acc2[mt], 0, 0, 0);
        acc2[mt] = __builtin_amdgcn_mfma_f32_16x16x32_bf16(ahi[mt], bmi, acc2[mt], 0, 0, 0);
        acc2[mt] = __builtin_amdgcn_mfma_f32_16x16x32_bf16(ami[mt], bhi, acc2[mt], 0, 0, 0);
      }
    }
  }

  // ---- o epilogue: C/D col=lane&15 (d), row=lq*4+r (+mt*16); 2 bf16 planes --
  {
    size_t rowbase = (size_t)(b * NN + g * GSZ + r0);
#pragma unroll
    for (int mt = 0; mt < 2; ++mt)
#pragma unroll
      for (int r = 0; r < 4; ++r) {
        int row = mt * 16 + lq * 4 + r;
        float val = acc2[mt][r];
        unsigned short hh = bf16rne(val);
        size_t oaddr = (rowbase + row) * 512 + h * 64 + wv * 16 + lm;
        opl[oaddr] = hh;
        opl[MK + oaddr] = bf16rne(val - bf16tof(hh));
      }
  }
}

// ---------------------------------------------------------------------------
// Fallback attn (fp32 q/k/v in, fp32 o out aliasing q) — small-ws path only.
// ---------------------------------------------------------------------------
__global__ __launch_bounds__(256, 3) void attn_f32(
    const float* q, const float* __restrict__ k, const float* __restrict__ v,
    const int* __restrict__ labels, const float* __restrict__ scores,
    float* __restrict__ attn_out, float* o)
{
  const int bx = blockIdx.x;
  const int c = bx >> 10;
  const int rblk = bx & 1023;
  const int h = rblk & 7;
  const int g = (rblk >> 3) & 31;
  const int b = rblk >> 8;
  const int r0 = c * CHUNK;
  const int tid = threadIdx.x;
  const int lane = tid & 63, wv = tid >> 6;

  __shared__ float att[CHUNK][WSZ + 4];
  __shared__ float ktile[64][DH + 4];
  __shared__ unsigned char klab[WSZ];
  __shared__ float kscr[WSZ];
  __shared__ int hist8[8];
  __shared__ float s_var;
  __shared__ int s_sk, s_ck;

  {
    int j = tid;
    int pos = g * GSZ + j;
    int tok = pos < NN ? pos : (2 * NN - 1 - pos);
    klab[j] = (unsigned char)labels[b * NN + tok];
    kscr[j] = scores[b * NN + tok];
  }
  if (tid < 8) hist8[tid] = 0;
  __syncthreads();
  focus_keep(klab, kscr, hist8, &s_var, &s_sk, &s_ck, tid, lane, wv);
  const int same_keep = s_sk, cross_keep = s_ck;

  const int rp = tid >> 4, jx = tid & 15;
  const int srow = tid >> 4, sd4 = (tid & 15) * 4;
  const float* q0p = q + (size_t)(b * NN + g * GSZ + r0 + rp) * DIMM + h * DH;
  const float* q1p = q0p + (size_t)16 * DIMM;

  for (int jt = 0; jt < 4; ++jt) {
#pragma unroll
    for (int p = 0; p < 64; p += 16) {
      int j = jt * 64 + srow + p;
      int pos = g * GSZ + j;
      int tok = pos < NN ? pos : (2 * NN - 1 - pos);
      *(float4*)&ktile[srow + p][sd4] =
          *(const float4*)&k[(size_t)(b * NN + tok) * DIMM + h * DH + sd4];
    }
    __syncthreads();
    float acc0[4] = {0.f, 0.f, 0.f, 0.f}, acc1[4] = {0.f, 0.f, 0.f, 0.f};
#pragma unroll
    for (int dd = 0; dd < DH; dd += 4) {
      float4 q0 = *(const float4*)(q0p + dd);
      float4 q1 = *(const float4*)(q1p + dd);
#pragma unroll
      for (int jj = 0; jj < 4; ++jj) {
        float4 kv = *(const float4*)&ktile[jx + 16 * jj][dd];
        acc0[jj] += q0.x * kv.x + q0.y * kv.y + q0.z * kv.z + q0.w * kv.w;
        acc1[jj] += q1.x * kv.x + q1.y * kv.y + q1.z * kv.z + q1.w * kv.w;
      }
    }
#pragma unroll
    for (int jj = 0; jj < 4; ++jj) {
      att[rp][jt * 64 + jx + 16 * jj] = acc0[jj] * 0.125f;
      att[rp + 16][jt * 64 + jx + 16 * jj] = acc1[jj] * 0.125f;
    }
    __syncthreads();
  }

  {
    int kl0[4];
    float ks0[4];
#pragma unroll
    for (int m = 0; m < 4; ++m) {
      kl0[m] = klab[lane + 64 * m];
      ks0[m] = kscr[lane + 64 * m];
    }
    for (int sp = 0; sp < 4; ++sp) {
      const int rA = wv * 8 + 2 * sp, rB = rA + 1;
      const int qLA = klab[r0 + rA], qLB = klab[r0 + rB];
      const float qSA = kscr[r0 + rA], qSB = kscr[r0 + rB];
      float aA[4], aB[4];
      float mxA = -INFINITY, mxB = -INFINITY;
#pragma unroll
      for (int m = 0; m < 4; ++m) {
        aA[m] = att[rA][lane + 64 * m];
        aB[m] = att[rB][lane + 64 * m];
        mxA = fmaxf(mxA, aA[m]);
        mxB = fmaxf(mxB, aB[m]);
      }
#pragma unroll
      for (int off = 32; off > 0; off >>= 1) {
        mxA = fmaxf(mxA, __shfl_xor(mxA, off));
        mxB = fmaxf(mxB, __shfl_xor(mxB, off));
      }
      unsigned fsA[4], fcA[4], fsB[4], fcB[4];
      bool cdA[4], cdB[4];
#pragma unroll
      for (int m = 0; m < 4; ++m) {
        aA[m] = expf(aA[m] - mxA);
        aB[m] = expf(aB[m] - mxB);
        cdA[m] = (kl0[m] == qLA);
        cdB[m] = (kl0[m] == qLB);
        fsA[m] = cdA[m] ? __float_as_uint(aA[m]) : 0u;
        fsB[m] = cdB[m] ? __float_as_uint(aB[m]) : 0u;
        fcA[m] = __float_as_uint(aA[m] * (qSA * ks0[m]));
        fcB[m] = __float_as_uint(aB[m] * (qSB * ks0[m]));
      }
      unsigned tsA = 0, tcA = 0, tsB = 0, tcB = 0;
      for (int bit = 29; bit >= 0; --bit) {
        unsigned csA = tsA | (1u << bit), ccA = tcA | (1u << bit);
        unsigned csB = tsB | (1u << bit), ccB = tcB | (1u << bit);
        int nsA = 0, ncA = 0, nsB = 0, ncB = 0;
#pragma unroll
        for (int m = 0; m < 4; ++m) {
          nsA += __popcll(__ballot(fsA[m] >= csA));
          ncA += __popcll(__ballot(fcA[m] >= ccA));
          nsB += __popcll(__ballot(fsB[m] >= csB));
          ncB += __popcll(__ballot(fcB[m] >= ccB));
        }
        if (nsA >= same_keep) tsA = csA;
        if (ncA >= cross_keep) tcA = ccA;
        if (nsB >= same_keep) tsB = csB;
        if (ncB >= cross_keep) tcB = ccB;
      }
#pragma unroll
      for (int rsel = 0; rsel < 2; ++rsel) {
        const int rr = rsel ? rB : rA;
        const unsigned ts = rsel ? tsB : tsA, tc = rsel ? tcB : tcA;
        unsigned* fs = rsel ? fsB : fsA;
        unsigned* fc = rsel ? fcB : fcA;
        float* a = rsel ? aB : aA;
        bool* cand = rsel ? cdB : cdA;
        unsigned long long beqs[4], beqc[4];
        int gts = 0, gtc = 0;
#pragma unroll
        for (int m = 0; m < 4; ++m) {
          gts += __popcll(__ballot(fs[m] > ts));
          gtc += __popcll(__ballot(fc[m] > tc));
          beqs[m] = __ballot(fs[m] == ts);
          beqc[m] = __ballot(fc[m] == tc);
        }
        const int rs = same_keep - gts, rc = cross_keep - gtc;
        float pv[4];
        float S = 0.f;
        int pres = 0, prec = 0;
#pragma unroll
        for (int m = 0; m < 4; ++m) {
          int mbs = __builtin_amdgcn_mbcnt_hi((unsigned)(beqs[m] >> 32),
                     __builtin_amdgcn_mbcnt_lo((unsigned)beqs[m], 0));
          int mbc = __builtin_amdgcn_mbcnt_hi((unsigned)(beqc[m] >> 32),
                     __builtin_amdgcn_mbcnt_lo((unsigned)beqc[m], 0));
          bool keep_s = cand[m] && ((fs[m] > ts) || ((fs[m] == ts) && (pres + mbs < rs)));
          bool keep_c = (!cand[m]) && ((fc[m] > tc) || ((fc[m] == tc) && (prec + mbc < rc)));
          pv[m] = (keep_s || keep_c) ? a[m] : 0.f;
          S += pv[m];
          pres += __popcll(beqs[m]);
          prec += __popcll(beqc[m]);
        }
#pragma unroll
        for (int off = 32; off > 0; off >>= 1) S += __shfl_xor(S, off);
        const float inv = 1.0f / S;
        size_t gb = ((((size_t)b * NGRP + g) * HH + h) * GSZ + (r0 + rr)) * WSZ + lane;
#pragma unroll
        for (int m = 0; m < 4; ++m) {
          float p = pv[m] * inv;
          att[rr][lane + 64 * m] = p;
          attn_out[gb + 64 * m] = p;
        }
      }
    }
  }
  __syncthreads();

  const int dx = jx;
  float oa0[4] = {0.f, 0.f, 0.f, 0.f}, oa1[4] = {0.f, 0.f, 0.f, 0.f};
  for (int jt = 0; jt < 4; ++jt) {
#pragma unroll
    for (int p = 0; p < 64; p += 16) {
      int j = jt * 64 + srow + p;
      int pos = g * GSZ + j;
      int tok = pos < NN ? pos : (2 * NN - 1 - pos);
      *(float4*)&ktile[srow + p][sd4] =
          *(const float4*)&v[(size_t)(b * NN + tok) * DIMM + h * DH + sd4];
    }
    __syncthreads();
#pragma unroll 4
    for (int jg = 0; jg < 16; ++jg) {
      float4 p0 = *(const float4*)&att[rp][jt * 64 + jg * 4];
      float4 p1 = *(const float4*)&att[rp + 16][jt * 64 + jg * 4];
      float4 v0 = *(const float4*)&ktile[jg * 4 + 0][dx * 4];
      float4 v1 = *(const float4*)&ktile[jg * 4 + 1][dx * 4];
      float4 v2 = *(const float4*)&ktile[jg * 4 + 2][dx * 4];
      float4 v3 = *(const float4*)&ktile[jg * 4 + 3][dx * 4];
      oa0[0] += p0.x * v0.x + p0.y * v1.x + p0.z * v2.x + p0.w * v3.x;
      oa0[1] += p0.x * v0.y + p0.y * v1.y + p0.z * v2.y + p0.w * v3.y;
      oa0[2] += p0.x * v0.z + p0.y * v1.z + p0.z * v2.z + p0.w * v3.z;
      oa0[3] += p0.x * v0.w + p0.y * v1.w + p0.z * v2.w + p0.w * v3.w;
      oa1[0] += p1.x * v0.x + p1.y * v1.x + p1.z * v2.x + p1.w * v3.x;
      oa1[1] += p1.x * v0.y + p1.y * v1.y + p1.z * v2.y + p1.w * v3.y;
      oa1[2] += p1.x * v0.z + p1.y * v1.z + p1.z * v2.z + p1.w * v3.z;
      oa1[3] += p1.x * v0.w + p1.y * v1.w + p1.z * v2.w + p1.w * v3.w;
    }
    __syncthreads();
  }
  {
    size_t ob0 = (size_t)(b * NN + g * GSZ + r0 + rp) * DIMM + h * DH + dx * 4;
    *(float4*)&o[ob0] = make_float4(oa0[0], oa0[1], oa0[2], oa0[3]);
    *(float4*)&o[ob0 + (size_t)16 * DIMM] = make_float4(oa1[0], oa1[1], oa1[2], oa1[3]);
  }
}

// ---------------------------------------------------------------------------
extern "C" void kernel_launch(void* const* d_in, const int* in_sizes, int n_in,
                              void* d_out, int out_size, void* d_ws, size_t ws_size,
                              hipStream_t stream) {
  const float* x      = (const float*)d_in[0];
  const int*   labels = (const int*)d_in[1];
  const float* scores = (const float*)d_in[2];
  const float* Wq     = (const float*)d_in[3];
  const float* Wk     = (const float*)d_in[4];
  const float* Wv     = (const float*)d_in[5];
  const float* Wproj  = (const float*)d_in[6];

  float* out = (float*)d_out;                               // (B, N, DIM)
  float* attn_out = out + (size_t)BB * NN * DIMM;           // (B, ng, H, gs, ws)

  // layout: qb|kb|vf (fp32) | xpl (3 planes; reused as opl) | weights
  float* qb = (float*)d_ws;
  float* kb = qb + (size_t)MK;
  float* vf = kb + (size_t)MK;
  unsigned short* xpl  = (unsigned short*)(vf + (size_t)MK);
  unsigned short* wqkv = xpl + 3 * (size_t)MK;
  unsigned short* wpp  = wqkv + 9 * (size_t)WK;
  const size_t required = 3 * (size_t)MK * 4 + 3 * (size_t)MK * 2 + 11 * (size_t)WK * 2;

  if (ws_size >= required) {
    split_planes<<<dim3(MK / 1024), 256, 0, stream>>>(x, xpl);
    split_w<<<dim3(4 * WK / 256), 256, 0, stream>>>(Wq, Wk, Wv, Wproj, wqkv, wpp);
    // q,k fp32 via 6-term (bit-identical to R5/R8 selection inputs); v 3-term
    mfma_gemm<3, 6><<<dim3(4, 128, 2), 256, 0, stream>>>(xpl, wqkv, qb);
    mfma_gemm<2, 3><<<dim3(4, 128, 1), 256, 0, stream>>>(xpl, wqkv + 6 * (size_t)WK, vf);
    attn_v13<<<dim3(BB * NGRP * HH * 4), 256, 0, stream>>>(
        qb, kb, vf, labels, scores, attn_out, xpl);
    mfma_gemm<2, 3><<<dim3(4, 128, 1), 256, 0, stream>>>(xpl, wpp, out);
  } else {
    const size_t SZ = (size_t)BB * NN * DIMM;
    float* q2 = (float*)d_ws;
    float* k2 = q2 + SZ;
    float* v2 = k2 + SZ;
    gemm512<<<dim3(4, 128, 3), 256, 0, stream>>>(x, Wq, Wk, Wv, q2, k2, v2);
    attn_f32<<<dim3(BB * NGRP * HH * 4), 256, 0, stream>>>(
        q2, k2, v2, labels, scores, attn_out, q2);
    gemm512<<<dim3(4, 128, 1), 256, 0, stream>>>(q2, Wproj, Wproj, Wproj, out, out, out);
  }
}

// Round 5
// 1279.743 us; speedup vs baseline: 2.3487x; 2.1362x over previous
//
#include <hip/hip_runtime.h>

#define BB 4
#define NN 4096
#define DIMM 512
#define HH 8
#define DH 64
#define GSZ 128
#define NGRP 32
#define WSZ 256
#define CHUNK 32

#define MK 8388608u     // 16384*512 elements (x / q / k / v / o planes)
#define WK 262144u      // 512*512

typedef short short8 __attribute__((ext_vector_type(8)));
typedef float f32x4 __attribute__((ext_vector_type(4)));

__device__ inline unsigned short bf16rne(float f) {
  unsigned u = __float_as_uint(f);
  unsigned r = u + 0x7FFFu + ((u >> 16) & 1u);
  return (unsigned short)(r >> 16);
}
__device__ inline float bf16tof(unsigned short h) {
  return __uint_as_float(((unsigned)h) << 16);
}

// ---------------------------------------------------------------------------
// split_planes: fp32 -> 3 bf16 planes (hi, mid, lo); exact residual split
// ---------------------------------------------------------------------------
__global__ __launch_bounds__(256) void split_planes(
    const float* __restrict__ X, unsigned short* __restrict__ P)
{
  unsigned idx = (blockIdx.x * 256u + threadIdx.x) * 4u;
  float4 xv = *(const float4*)&X[idx];
  float xs[4] = {xv.x, xv.y, xv.z, xv.w};
  ushort4 hv, mv, lv;
  unsigned short* hp = (unsigned short*)&hv;
  unsigned short* mp = (unsigned short*)&mv;
  unsigned short* lp = (unsigned short*)&lv;
#pragma unroll
  for (int i = 0; i < 4; ++i) {
    unsigned short h = bf16rne(xs[i]);
    float r1 = xs[i] - bf16tof(h);
    unsigned short m = bf16rne(r1);
    float r2 = r1 - bf16tof(m);
    hp[i] = h;
    mp[i] = m;
    lp[i] = bf16rne(r2);
  }
  *(ushort4*)&P[idx] = hv;
  *(ushort4*)&P[MK + idx] = mv;
  *(ushort4*)&P[2u * MK + idx] = lv;
}

// ---------------------------------------------------------------------------
// split_w: weights -> transposed (N x K) bf16 planes.
// ---------------------------------------------------------------------------
__global__ __launch_bounds__(256) void split_w(
    const float* __restrict__ Wq, const float* __restrict__ Wk,
    const float* __restrict__ Wv, const float* __restrict__ Wpj,
    unsigned short* __restrict__ wqkv, unsigned short* __restrict__ wproj)
{
  unsigned e = blockIdx.x * 256u + threadIdx.x;     // over 4 * 2^18
  int mz = e >> 18;
  unsigned rem = e & (WK - 1u);
  unsigned kk = rem >> 9, n = rem & 511u;
  const float* src = (mz == 0) ? Wq : (mz == 1) ? Wk : (mz == 2) ? Wv : Wpj;
  float w = src[kk * 512u + n];
  unsigned short h = bf16rne(w);
  float r1 = w - bf16tof(h);
  unsigned short m = bf16rne(r1);
  float r2 = r1 - bf16tof(m);
  unsigned short l = bf16rne(r2);
  unsigned o = n * 512u + kk;
  if (mz < 3) {
    unsigned short* base = wqkv + (unsigned)mz * 3u * WK;
    base[o] = h;
    base[WK + o] = m;
    base[2u * WK + o] = l;
  } else {
    wproj[o] = h;
    wproj[WK + o] = m;
  }
}

// ---------------------------------------------------------------------------
// mfma_gemm: C[z] = A(16384x512) @ W[z](512x512) via split-bf16 MFMA.
// ---------------------------------------------------------------------------
template <int NP, int NT>
__global__ __launch_bounds__(256) void mfma_gemm(
    const unsigned short* __restrict__ Ap,   // NP planes, plane stride MK
    const unsigned short* __restrict__ Wp,   // [z][NP][n][k], plane stride WK
    float* __restrict__ C)
{
  constexpr int ta[6] = {0, 0, 1, 1, 0, 2};
  constexpr int tw[6] = {0, 1, 0, 1, 2, 0};
  const int z = blockIdx.z;
  const int n0 = blockIdx.x * 128;
  const int m0 = blockIdx.y * 128;
  const int tid = threadIdx.x;
  const int lane = tid & 63, wv = tid >> 6;
  const int wm = (wv >> 1) * 64, wn = (wv & 1) * 64;
  const int lm = lane & 15, lk = (lane >> 4) * 8;

  __shared__ unsigned short As[NP * 128 * 40];   // stride 40 bf16 = 80 B
  __shared__ unsigned short Ws[NP * 128 * 40];

  f32x4 acc[4][4];
#pragma unroll
  for (int i = 0; i < 4; ++i)
#pragma unroll
    for (int j = 0; j < 4; ++j) acc[i][j] = (f32x4){0.f, 0.f, 0.f, 0.f};

  const unsigned short* Wz = Wp + (size_t)z * NP * WK;

  for (int k0 = 0; k0 < 512; k0 += 32) {
#pragma unroll
    for (int i = 0; i < NP * 2; ++i) {
      int idx = i * 256 + tid;
      int p = idx >> 9, rem = idx & 511;
      int r = rem >> 2, cc = rem & 3;
      *(short8*)&As[p * 5120 + r * 40 + cc * 8] =
          *(const short8*)&Ap[(size_t)p * MK + (size_t)(m0 + r) * 512 + k0 + cc * 8];
      *(short8*)&Ws[p * 5120 + r * 40 + cc * 8] =
          *(const short8*)&Wz[(size_t)p * WK + (size_t)(n0 + r) * 512 + k0 + cc * 8];
    }
    __syncthreads();

    short8 a[NP][4];
#pragma unroll
    for (int p = 0; p < NP; ++p)
#pragma unroll
      for (int fm = 0; fm < 4; ++fm)
        a[p][fm] = *(const short8*)&As[p * 5120 + (wm + fm * 16 + lm) * 40 + lk];

#pragma unroll
    for (int fn = 0; fn < 4; ++fn) {
      short8 bf[NP];
#pragma unroll
      for (int p = 0; p < NP; ++p)
        bf[p] = *(const short8*)&Ws[p * 5120 + (wn + fn * 16 + lm) * 40 + lk];
#pragma unroll
      for (int fm = 0; fm < 4; ++fm) {
#pragma unroll
        for (int t = 0; t < NT; ++t)
          acc[fm][fn] = __builtin_amdgcn_mfma_f32_16x16x32_bf16(
              a[ta[t]][fm], bf[tw[t]], acc[fm][fn], 0, 0, 0);
      }
    }
    __syncthreads();
  }

  const int rq = (lane >> 4) * 4;
  float* Cz = C + (size_t)z * 8388608u;
#pragma unroll
  for (int fm = 0; fm < 4; ++fm)
#pragma unroll
    for (int fn = 0; fn < 4; ++fn) {
      int row = m0 + wm + fm * 16 + rq;
      int col = n0 + wn + fn * 16 + lm;
#pragma unroll
      for (int r = 0; r < 4; ++r)
        Cz[(size_t)(row + r) * 512 + col] = acc[fm][fn][r];
    }
}

// ---------------------------------------------------------------------------
// Fallback fp32 GEMM (only if ws too small for planes).
// ---------------------------------------------------------------------------
__global__ __launch_bounds__(256) void gemm512(
    const float* __restrict__ A,
    const float* __restrict__ W0, const float* __restrict__ W1, const float* __restrict__ W2,
    float* __restrict__ C0, float* __restrict__ C1, float* __restrict__ C2)
{
  const int z = blockIdx.z;
  const float* Wm = (z == 0) ? W0 : (z == 1 ? W1 : W2);
  float* Cm = (z == 0) ? C0 : (z == 1 ? C1 : C2);
  const int n0 = blockIdx.x * 128;
  const int m0 = blockIdx.y * 128;
  const int tid = threadIdx.x;
  const int tx = tid & 15, ty = tid >> 4;

  __shared__ float As[32][132];
  __shared__ float Bs[32][132];

  float acc[8][8];
#pragma unroll
  for (int i = 0; i < 8; ++i)
#pragma unroll
    for (int j = 0; j < 8; ++j) acc[i][j] = 0.f;

  for (int k0 = 0; k0 < 512; k0 += 32) {
    {
      const int c4 = tid & 7, r = tid >> 3;
#pragma unroll
      for (int p = 0; p < 128; p += 32) {
        float4 av = *(const float4*)&A[(size_t)(m0 + r + p) * 512 + k0 + c4 * 4];
        As[c4 * 4 + 0][r + p] = av.x;
        As[c4 * 4 + 1][r + p] = av.y;
        As[c4 * 4 + 2][r + p] = av.z;
        As[c4 * 4 + 3][r + p] = av.w;
      }
      const int j4 = tid & 31, rb = tid >> 5;
#pragma unroll
      for (int p = 0; p < 32; p += 8) {
        *(float4*)&Bs[rb + p][j4 * 4] =
            *(const float4*)&Wm[(size_t)(k0 + rb + p) * 512 + n0 + j4 * 4];
      }
    }
    __syncthreads();
#pragma unroll
    for (int kk = 0; kk < 32; ++kk) {
      float4 a0 = *(const float4*)&As[kk][ty * 8];
      float4 a1 = *(const float4*)&As[kk][ty * 8 + 4];
      float4 b0 = *(const float4*)&Bs[kk][tx * 8];
      float4 b1 = *(const float4*)&Bs[kk][tx * 8 + 4];
      float av[8] = {a0.x, a0.y, a0.z, a0.w, a1.x, a1.y, a1.z, a1.w};
      float bv[8] = {b0.x, b0.y, b0.z, b0.w, b1.x, b1.y, b1.z, b1.w};
#pragma unroll
      for (int i = 0; i < 8; ++i)
#pragma unroll
        for (int j = 0; j < 8; ++j) acc[i][j] += av[i] * bv[j];
    }
    __syncthreads();
  }
#pragma unroll
  for (int i = 0; i < 8; ++i) {
    size_t row = (size_t)(m0 + ty * 8 + i);
    float4 o0 = make_float4(acc[i][0], acc[i][1], acc[i][2], acc[i][3]);
    float4 o1 = make_float4(acc[i][4], acc[i][5], acc[i][6], acc[i][7]);
    *(float4*)&Cm[row * 512 + n0 + tx * 8] = o0;
    *(float4*)&Cm[row * 512 + n0 + tx * 8 + 4] = o1;
  }
}

// ---------------------------------------------------------------------------
// focus/keep computation (shared).
// ---------------------------------------------------------------------------
__device__ __forceinline__ void focus_keep(
    const unsigned char* klab, const float* kscr, int* hist8, float* s_var,
    int* s_sk, int* s_ck, int tid, int lane, int wv)
{
  if (tid < GSZ) atomicAdd(&hist8[klab[tid]], 1);
  if (wv == 0) {
    double x0 = (double)kscr[lane], x1 = (double)kscr[lane + 64];
    double s = x0 + x1;
#pragma unroll
    for (int off = 32; off > 0; off >>= 1) s += __shfl_xor(s, off);
    double mean = s * (1.0 / 128.0);
    double d0 = x0 - mean, d1 = x1 - mean;
    double vs = d0 * d0 + d1 * d1;
#pragma unroll
    for (int off = 32; off > 0; off >>= 1) vs += __shfl_xor(vs, off);
    if (lane == 0) *s_var = (float)(vs * (1.0 / 128.0));
  }
  __syncthreads();
  if (tid == 0) {
    int bc = hist8[0];
    for (int l = 1; l < 8; ++l)
      if (hist8[l] > bc) bc = hist8[l];
    float purity = (float)bc * (1.0f / GSZ);
    float focus = 0.5f + 0.25f * purity - 0.25f * (*s_var);
    focus = fminf(fmaxf(focus, 0.25f), 0.75f);
    int keep = (int)ceilf(focus * (float)WSZ);
    keep = min(max(keep, 1), WSZ);
    int ck = keep >> 3, rem = keep & 7;          // round-half-even(keep/8)
    if (rem > 4 || (rem == 4 && (ck & 1))) ck++;
    if (ck < 1) ck = 1;
    int sk = keep - ck;
    if (sk < 1) sk = 1;
    *s_sk = sk;
    *s_ck = ck;
  }
  __syncthreads();
}

// ---------------------------------------------------------------------------
// attn v14: v9's QK mapping (2 q-row streams/thread -> low register pressure,
// 84 VGPR in v9) with DEFERRED att stores: acc0/acc1[jt][jj] accumulate in
// regs across the 4 jt tiles (32 regs), att written once after the jt loop.
// That deferral is what makes the v13 LDS aliasing legal (ktile f32[64][68]
// occupies the front of the att[32][264] region; att is only written after
// the last ktile read). v13's 256-VGPR + 1.9GB-scratch disaster came from its
// rank-mapped QK body streaming 8 q rows x 16 dd steps = 128 pipelined global
// loads; v9's 2-stream body avoids that. Logit values bit-identical to v9
// (same FMA chains, same *0.125f, just deferred stores). Rank phase is v9
// VERBATIM. PV = v13's verified direct-from-global V path, jt loop ROLLED
// (#pragma unroll 1) so its 16 V-loads/iter don't get hoisted x4.
// LDS 35.3KB -> 4 blocks/CU; plain __launch_bounds__(256).
// ---------------------------------------------------------------------------
__global__ __launch_bounds__(256) void attn_v14(
    const float* __restrict__ q, const float* __restrict__ k,
    const float* __restrict__ vf,
    const int* __restrict__ labels, const float* __restrict__ scores,
    float* __restrict__ attn_out, unsigned short* __restrict__ opl)
{
  const int bx = blockIdx.x;
  const int c = bx >> 10;
  const int rblk = bx & 1023;
  const int h = rblk & 7;
  const int g = (rblk >> 3) & 31;
  const int b = rblk >> 8;
  const int r0 = c * CHUNK;
  const int tid = threadIdx.x;
  const int lane = tid & 63, wv = tid >> 6;
  const int lm = lane & 15, lq = lane >> 4;

  // att row = 264 fp32 (1056 B): fp32 logits, later hosts phi[0..263] (528B)
  // + pmid[0..263] (528B) overlays in the SAME row (wave-private, race-free).
  // During QK, the front of this region doubles as ktile f32[64][68] (17408B);
  // att is only written after the last ktile read (deferred stores).
  __shared__ __align__(16) unsigned char smem[32 * 264 * 4];
  float (*att)[264] = (float (*)[264])smem;
  float (*ktile)[68] = (float (*)[68])smem;
  __shared__ unsigned char klab[WSZ];
  __shared__ float kscr[WSZ];
  __shared__ int hist8[8];
  __shared__ float s_var;
  __shared__ int s_sk, s_ck;

  {
    int j = tid;
    int pos = g * GSZ + j;
    int tok = pos < NN ? pos : (2 * NN - 1 - pos);
    klab[j] = (unsigned char)labels[b * NN + tok];
    kscr[j] = scores[b * NN + tok];
  }
  if (tid < 8) hist8[tid] = 0;
  __syncthreads();
  focus_keep(klab, kscr, hist8, &s_var, &s_sk, &s_ck, tid, lane, wv);
  const int same_keep = s_sk, cross_keep = s_ck;

  const int rp = tid >> 4, jx = tid & 15;
  const int srow = tid >> 4, sd4 = (tid & 15) * 4;
  const float* q0p = q + (size_t)(b * NN + g * GSZ + r0 + rp) * DIMM + h * DH;
  const float* q1p = q0p + (size_t)16 * DIMM;

  // ---- QK^T: v9 mapping & expressions; acc kept in regs across jt ----
  float acc0[4][4], acc1[4][4];
#pragma unroll
  for (int jt = 0; jt < 4; ++jt)
#pragma unroll
    for (int jj = 0; jj < 4; ++jj) { acc0[jt][jj] = 0.f; acc1[jt][jj] = 0.f; }

#pragma unroll
  for (int jt = 0; jt < 4; ++jt) {
#pragma unroll
    for (int p = 0; p < 64; p += 16) {
      int j = jt * 64 + srow + p;
      int pos = g * GSZ + j;
      int tok = pos < NN ? pos : (2 * NN - 1 - pos);
      *(float4*)&ktile[srow + p][sd4] =
          *(const float4*)&k[(size_t)(b * NN + tok) * DIMM + h * DH + sd4];
    }
    __syncthreads();
#pragma unroll
    for (int dd = 0; dd < DH; dd += 4) {
      float4 q0 = *(const float4*)(q0p + dd);
      float4 q1 = *(const float4*)(q1p + dd);
#pragma unroll
      for (int jj = 0; jj < 4; ++jj) {
        float4 kv = *(const float4*)&ktile[jx + 16 * jj][dd];
        acc0[jt][jj] += q0.x * kv.x + q0.y * kv.y + q0.z * kv.z + q0.w * kv.w;
        acc1[jt][jj] += q1.x * kv.x + q1.y * kv.y + q1.z * kv.z + q1.w * kv.w;
      }
    }
    __syncthreads();   // ktile reads done before next staging / att writes
  }

  // ---- deferred att stores (v9 values, v9 layout) ----
#pragma unroll
  for (int jt = 0; jt < 4; ++jt)
#pragma unroll
    for (int jj = 0; jj < 4; ++jj) {
      att[rp][jt * 64 + jx + 16 * jj] = acc0[jt][jj] * 0.125f;
      att[rp + 16][jt * 64 + jx + 16 * jj] = acc1[jt][jj] * 0.125f;
    }
  __syncthreads();

  // ---- rank: v9 VERBATIM (reads att, writes attn_out + phi/pmid overlays) --
  {
    int kl0[4];
    float ks0[4];
#pragma unroll
    for (int m = 0; m < 4; ++m) {
      kl0[m] = klab[lane + 64 * m];
      ks0[m] = kscr[lane + 64 * m];
    }
    for (int sp = 0; sp < 4; ++sp) {
      const int rA = wv * 8 + 2 * sp, rB = rA + 1;
      const int qLA = klab[r0 + rA], qLB = klab[r0 + rB];
      const float qSA = kscr[r0 + rA], qSB = kscr[r0 + rB];
      float aA[4], aB[4];
      float mxA = -INFINITY, mxB = -INFINITY;
#pragma unroll
      for (int m = 0; m < 4; ++m) {
        aA[m] = att[rA][lane + 64 * m];
        aB[m] = att[rB][lane + 64 * m];
        mxA = fmaxf(mxA, aA[m]);
        mxB = fmaxf(mxB, aB[m]);
      }
#pragma unroll
      for (int off = 32; off > 0; off >>= 1) {
        mxA = fmaxf(mxA, __shfl_xor(mxA, off));
        mxB = fmaxf(mxB, __shfl_xor(mxB, off));
      }
      unsigned fsA[4], fcA[4], fsB[4], fcB[4];
      bool cdA[4], cdB[4];
#pragma unroll
      for (int m = 0; m < 4; ++m) {
        aA[m] = expf(aA[m] - mxA);
        aB[m] = expf(aB[m] - mxB);
        cdA[m] = (kl0[m] == qLA);
        cdB[m] = (kl0[m] == qLB);
        fsA[m] = cdA[m] ? __float_as_uint(aA[m]) : 0u;
        fsB[m] = cdB[m] ? __float_as_uint(aB[m]) : 0u;
        fcA[m] = __float_as_uint(aA[m] * (qSA * ks0[m]));
        fcB[m] = __float_as_uint(aB[m] * (qSB * ks0[m]));
      }
      unsigned tsA = 0, tcA = 0, tsB = 0, tcB = 0;
      for (int bit = 29; bit >= 0; --bit) {
        unsigned csA = tsA | (1u << bit), ccA = tcA | (1u << bit);
        unsigned csB = tsB | (1u << bit), ccB = tcB | (1u << bit);
        int nsA = 0, ncA = 0, nsB = 0, ncB = 0;
#pragma unroll
        for (int m = 0; m < 4; ++m) {
          nsA += __popcll(__ballot(fsA[m] >= csA));
          ncA += __popcll(__ballot(fcA[m] >= ccA));
          nsB += __popcll(__ballot(fsB[m] >= csB));
          ncB += __popcll(__ballot(fcB[m] >= ccB));
        }
        if (nsA >= same_keep) tsA = csA;
        if (ncA >= cross_keep) tcA = ccA;
        if (nsB >= same_keep) tsB = csB;
        if (ncB >= cross_keep) tcB = ccB;
      }
#pragma unroll
      for (int rsel = 0; rsel < 2; ++rsel) {
        const int rr = rsel ? rB : rA;
        const unsigned ts = rsel ? tsB : tsA, tc = rsel ? tcB : tcA;
        unsigned* fs = rsel ? fsB : fsA;
        unsigned* fc = rsel ? fcB : fcA;
        float* a = rsel ? aB : aA;
        bool* cand = rsel ? cdB : cdA;
        unsigned long long beqs[4], beqc[4];
        int gts = 0, gtc = 0;
#pragma unroll
        for (int m = 0; m < 4; ++m) {
          gts += __popcll(__ballot(fs[m] > ts));
          gtc += __popcll(__ballot(fc[m] > tc));
          beqs[m] = __ballot(fs[m] == ts);
          beqc[m] = __ballot(fc[m] == tc);
        }
        const int rs = same_keep - gts, rc = cross_keep - gtc;
        float pv[4];
        float S = 0.f;
        int pres = 0, prec = 0;
#pragma unroll
        for (int m = 0; m < 4; ++m) {
          int mbs = __builtin_amdgcn_mbcnt_hi((unsigned)(beqs[m] >> 32),
                     __builtin_amdgcn_mbcnt_lo((unsigned)beqs[m], 0));
          int mbc = __builtin_amdgcn_mbcnt_hi((unsigned)(beqc[m] >> 32),
                     __builtin_amdgcn_mbcnt_lo((unsigned)beqc[m], 0));
          bool keep_s = cand[m] && ((fs[m] > ts) || ((fs[m] == ts) && (pres + mbs < rs)));
          bool keep_c = (!cand[m]) && ((fc[m] > tc) || ((fc[m] == tc) && (prec + mbc < rc)));
          pv[m] = (keep_s || keep_c) ? a[m] : 0.f;
          S += pv[m];
          pres += __popcll(beqs[m]);
          prec += __popcll(beqc[m]);
        }
#pragma unroll
        for (int off = 32; off > 0; off >>= 1) S += __shfl_xor(S, off);
        const float inv = 1.0f / S;
        size_t gb = ((((size_t)b * NGRP + g) * HH + h) * GSZ + (r0 + rr)) * WSZ + lane;
        unsigned short* prow = (unsigned short*)&att[rr][0];
#pragma unroll
        for (int m = 0; m < 4; ++m) {
          float p = pv[m] * inv;
          attn_out[gb + 64 * m] = p;
          unsigned short hh = bf16rne(p);
          prow[lane + 64 * m] = hh;                          // phi
          prow[264 + lane + 64 * m] = bf16rne(p - bf16tof(hh)); // pmid
        }
      }
    }
  }
  __syncthreads();   // overlays visible to all waves for PV

  // ---- PV via MFMA: D(32x64) = P(32x256) @ V(256x64), 3-term split.
  // A-fragments from att overlays (v9 layout); V B-fragments direct from
  // global (values == v9's staged bf16s; same MFMA order). jt loop ROLLED to
  // keep the 16 V-loads/iter from being hoisted x4 (register pressure).
  f32x4 acc2[2] = {(f32x4){0.f, 0.f, 0.f, 0.f}, (f32x4){0.f, 0.f, 0.f, 0.f}};
#pragma unroll 1
  for (int jt = 0; jt < 4; ++jt) {
    float vv[2][8];
#pragma unroll
    for (int kt = 0; kt < 2; ++kt)
#pragma unroll
      for (int i = 0; i < 8; ++i) {
        int pos = g * GSZ + jt * 64 + kt * 32 + lq * 8 + i;
        int tok = pos < NN ? pos : (2 * NN - 1 - pos);
        vv[kt][i] = vf[(size_t)(b * NN + tok) * DIMM + h * DH + wv * 16 + lm];
      }
#pragma unroll
    for (int kt = 0; kt < 2; ++kt) {
      const int koff = jt * 64 + kt * 32 + lq * 8;
      short8 ahi[2], ami[2];
#pragma unroll
      for (int mt = 0; mt < 2; ++mt) {
        const unsigned short* arow = (const unsigned short*)&att[mt * 16 + lm][0];
        ahi[mt] = *(const short8*)&arow[koff];
        ami[mt] = *(const short8*)&arow[264 + koff];
      }
      short8 bhi, bmi;
#pragma unroll
      for (int i = 0; i < 8; ++i) {
        unsigned short h0 = bf16rne(vv[kt][i]);
        bhi[i] = (short)h0;
        bmi[i] = (short)bf16rne(vv[kt][i] - bf16tof(h0));
      }
#pragma unroll
      for (int mt = 0; mt < 2; ++mt) {
        acc2[mt] = __builtin_amdgcn_mfma_f32_16x16x32_bf16(ahi[mt], bhi, acc2[mt], 0, 0, 0);
        acc2[mt] = __builtin_amdgcn_mfma_f32_16x16x32_bf16(ahi[mt], bmi, acc2[mt], 0, 0, 0);
        acc2[mt] = __builtin_amdgcn_mfma_f32_16x16x32_bf16(ami[mt], bhi, acc2[mt], 0, 0, 0);
      }
    }
  }

  // ---- o epilogue: C/D col=lane&15 (d), row=lq*4+r (+mt*16); 2 bf16 planes --
  {
    size_t rowbase = (size_t)(b * NN + g * GSZ + r0);
#pragma unroll
    for (int mt = 0; mt < 2; ++mt)
#pragma unroll
      for (int r = 0; r < 4; ++r) {
        int row = mt * 16 + lq * 4 + r;
        float val = acc2[mt][r];
        unsigned short hh = bf16rne(val);
        size_t oaddr = (rowbase + row) * 512 + h * 64 + wv * 16 + lm;
        opl[oaddr] = hh;
        opl[MK + oaddr] = bf16rne(val - bf16tof(hh));
      }
  }
}

// ---------------------------------------------------------------------------
// Fallback attn (fp32 q/k/v in, fp32 o out aliasing q) — small-ws path only.
// ---------------------------------------------------------------------------
__global__ __launch_bounds__(256, 3) void attn_f32(
    const float* q, const float* __restrict__ k, const float* __restrict__ v,
    const int* __restrict__ labels, const float* __restrict__ scores,
    float* __restrict__ attn_out, float* o)
{
  const int bx = blockIdx.x;
  const int c = bx >> 10;
  const int rblk = bx & 1023;
  const int h = rblk & 7;
  const int g = (rblk >> 3) & 31;
  const int b = rblk >> 8;
  const int r0 = c * CHUNK;
  const int tid = threadIdx.x;
  const int lane = tid & 63, wv = tid >> 6;

  __shared__ float att[CHUNK][WSZ + 4];
  __shared__ float ktile[64][DH + 4];
  __shared__ unsigned char klab[WSZ];
  __shared__ float kscr[WSZ];
  __shared__ int hist8[8];
  __shared__ float s_var;
  __shared__ int s_sk, s_ck;

  {
    int j = tid;
    int pos = g * GSZ + j;
    int tok = pos < NN ? pos : (2 * NN - 1 - pos);
    klab[j] = (unsigned char)labels[b * NN + tok];
    kscr[j] = scores[b * NN + tok];
  }
  if (tid < 8) hist8[tid] = 0;
  __syncthreads();
  focus_keep(klab, kscr, hist8, &s_var, &s_sk, &s_ck, tid, lane, wv);
  const int same_keep = s_sk, cross_keep = s_ck;

  const int rp = tid >> 4, jx = tid & 15;
  const int srow = tid >> 4, sd4 = (tid & 15) * 4;
  const float* q0p = q + (size_t)(b * NN + g * GSZ + r0 + rp) * DIMM + h * DH;
  const float* q1p = q0p + (size_t)16 * DIMM;

  for (int jt = 0; jt < 4; ++jt) {
#pragma unroll
    for (int p = 0; p < 64; p += 16) {
      int j = jt * 64 + srow + p;
      int pos = g * GSZ + j;
      int tok = pos < NN ? pos : (2 * NN - 1 - pos);
      *(float4*)&ktile[srow + p][sd4] =
          *(const float4*)&k[(size_t)(b * NN + tok) * DIMM + h * DH + sd4];
    }
    __syncthreads();
    float acc0[4] = {0.f, 0.f, 0.f, 0.f}, acc1[4] = {0.f, 0.f, 0.f, 0.f};
#pragma unroll
    for (int dd = 0; dd < DH; dd += 4) {
      float4 q0 = *(const float4*)(q0p + dd);
      float4 q1 = *(const float4*)(q1p + dd);
#pragma unroll
      for (int jj = 0; jj < 4; ++jj) {
        float4 kv = *(const float4*)&ktile[jx + 16 * jj][dd];
        acc0[jj] += q0.x * kv.x + q0.y * kv.y + q0.z * kv.z + q0.w * kv.w;
        acc1[jj] += q1.x * kv.x + q1.y * kv.y + q1.z * kv.z + q1.w * kv.w;
      }
    }
#pragma unroll
    for (int jj = 0; jj < 4; ++jj) {
      att[rp][jt * 64 + jx + 16 * jj] = acc0[jj] * 0.125f;
      att[rp + 16][jt * 64 + jx + 16 * jj] = acc1[jj] * 0.125f;
    }
    __syncthreads();
  }

  {
    int kl0[4];
    float ks0[4];
#pragma unroll
    for (int m = 0; m < 4; ++m) {
      kl0[m] = klab[lane + 64 * m];
      ks0[m] = kscr[lane + 64 * m];
    }
    for (int sp = 0; sp < 4; ++sp) {
      const int rA = wv * 8 + 2 * sp, rB = rA + 1;
      const int qLA = klab[r0 + rA], qLB = klab[r0 + rB];
      const float qSA = kscr[r0 + rA], qSB = kscr[r0 + rB];
      float aA[4], aB[4];
      float mxA = -INFINITY, mxB = -INFINITY;
#pragma unroll
      for (int m = 0; m < 4; ++m) {
        aA[m] = att[rA][lane + 64 * m];
        aB[m] = att[rB][lane + 64 * m];
        mxA = fmaxf(mxA, aA[m]);
        mxB = fmaxf(mxB, aB[m]);
      }
#pragma unroll
      for (int off = 32; off > 0; off >>= 1) {
        mxA = fmaxf(mxA, __shfl_xor(mxA, off));
        mxB = fmaxf(mxB, __shfl_xor(mxB, off));
      }
      unsigned fsA[4], fcA[4], fsB[4], fcB[4];
      bool cdA[4], cdB[4];
#pragma unroll
      for (int m = 0; m < 4; ++m) {
        aA[m] = expf(aA[m] - mxA);
        aB[m] = expf(aB[m] - mxB);
        cdA[m] = (kl0[m] == qLA);
        cdB[m] = (kl0[m] == qLB);
        fsA[m] = cdA[m] ? __float_as_uint(aA[m]) : 0u;
        fsB[m] = cdB[m] ? __float_as_uint(aB[m]) : 0u;
        fcA[m] = __float_as_uint(aA[m] * (qSA * ks0[m]));
        fcB[m] = __float_as_uint(aB[m] * (qSB * ks0[m]));
      }
      unsigned tsA = 0, tcA = 0, tsB = 0, tcB = 0;
      for (int bit = 29; bit >= 0; --bit) {
        unsigned csA = tsA | (1u << bit), ccA = tcA | (1u << bit);
        unsigned csB = tsB | (1u << bit), ccB = tcB | (1u << bit);
        int nsA = 0, ncA = 0, nsB = 0, ncB = 0;
#pragma unroll
        for (int m = 0; m < 4; ++m) {
          nsA += __popcll(__ballot(fsA[m] >= csA));
          ncA += __popcll(__ballot(fcA[m] >= ccA));
          nsB += __popcll(__ballot(fsB[m] >= csB));
          ncB += __popcll(__ballot(fcB[m] >= ccB));
        }
        if (nsA >= same_keep) tsA = csA;
        if (ncA >= cross_keep) tcA = ccA;
        if (nsB >= same_keep) tsB = csB;
        if (ncB >= cross_keep) tcB = ccB;
      }
#pragma unroll
      for (int rsel = 0; rsel < 2; ++rsel) {
        const int rr = rsel ? rB : rA;
        const unsigned ts = rsel ? tsB : tsA, tc = rsel ? tcB : tcA;
        unsigned* fs = rsel ? fsB : fsA;
        unsigned* fc = rsel ? fcB : fcA;
        float* a = rsel ? aB : aA;
        bool* cand = rsel ? cdB : cdA;
        unsigned long long beqs[4], beqc[4];
        int gts = 0, gtc = 0;
#pragma unroll
        for (int m = 0; m < 4; ++m) {
          gts += __popcll(__ballot(fs[m] > ts));
          gtc += __popcll(__ballot(fc[m] > tc));
          beqs[m] = __ballot(fs[m] == ts);
          beqc[m] = __ballot(fc[m] == tc);
        }
        const int rs = same_keep - gts, rc = cross_keep - gtc;
        float pv[4];
        float S = 0.f;
        int pres = 0, prec = 0;
#pragma unroll
        for (int m = 0; m < 4; ++m) {
          int mbs = __builtin_amdgcn_mbcnt_hi((unsigned)(beqs[m] >> 32),
                     __builtin_amdgcn_mbcnt_lo((unsigned)beqs[m], 0));
          int mbc = __builtin_amdgcn_mbcnt_hi((unsigned)(beqc[m] >> 32),
                     __builtin_amdgcn_mbcnt_lo((unsigned)beqc[m], 0));
          bool keep_s = cand[m] && ((fs[m] > ts) || ((fs[m] == ts) && (pres + mbs < rs)));
          bool keep_c = (!cand[m]) && ((fc[m] > tc) || ((fc[m] == tc) && (prec + mbc < rc)));
          pv[m] = (keep_s || keep_c) ? a[m] : 0.f;
          S += pv[m];
          pres += __popcll(beqs[m]);
          prec += __popcll(beqc[m]);
        }
#pragma unroll
        for (int off = 32; off > 0; off >>= 1) S += __shfl_xor(S, off);
        const float inv = 1.0f / S;
        size_t gb = ((((size_t)b * NGRP + g) * HH + h) * GSZ + (r0 + rr)) * WSZ + lane;
#pragma unroll
        for (int m = 0; m < 4; ++m) {
          float p = pv[m] * inv;
          att[rr][lane + 64 * m] = p;
          attn_out[gb + 64 * m] = p;
        }
      }
    }
  }
  __syncthreads();

  const int dx = jx;
  float oa0[4] = {0.f, 0.f, 0.f, 0.f}, oa1[4] = {0.f, 0.f, 0.f, 0.f};
  for (int jt = 0; jt < 4; ++jt) {
#pragma unroll
    for (int p = 0; p < 64; p += 16) {
      int j = jt * 64 + srow + p;
      int pos = g * GSZ + j;
      int tok = pos < NN ? pos : (2 * NN - 1 - pos);
      *(float4*)&ktile[srow + p][sd4] =
          *(const float4*)&v[(size_t)(b * NN + tok) * DIMM + h * DH + sd4];
    }
    __syncthreads();
#pragma unroll 4
    for (int jg = 0; jg < 16; ++jg) {
      float4 p0 = *(const float4*)&att[rp][jt * 64 + jg * 4];
      float4 p1 = *(const float4*)&att[rp + 16][jt * 64 + jg * 4];
      float4 v0 = *(const float4*)&ktile[jg * 4 + 0][dx * 4];
      float4 v1 = *(const float4*)&ktile[jg * 4 + 1][dx * 4];
      float4 v2 = *(const float4*)&ktile[jg * 4 + 2][dx * 4];
      float4 v3 = *(const float4*)&ktile[jg * 4 + 3][dx * 4];
      oa0[0] += p0.x * v0.x + p0.y * v1.x + p0.z * v2.x + p0.w * v3.x;
      oa0[1] += p0.x * v0.y + p0.y * v1.y + p0.z * v2.y + p0.w * v3.y;
      oa0[2] += p0.x * v0.z + p0.y * v1.z + p0.z * v2.z + p0.w * v3.z;
      oa0[3] += p0.x * v0.w + p0.y * v1.w + p0.z * v2.w + p0.w * v3.w;
      oa1[0] += p1.x * v0.x + p1.y * v1.x + p1.z * v2.x + p1.w * v3.x;
      oa1[1] += p1.x * v0.y + p1.y * v1.y + p1.z * v2.y + p1.w * v3.y;
      oa1[2] += p1.x * v0.z + p1.y * v1.z + p1.z * v2.z + p1.w * v3.z;
      oa1[3] += p1.x * v0.w + p1.y * v1.w + p1.z * v2.w + p1.w * v3.w;
    }
    __syncthreads();
  }
  {
    size_t ob0 = (size_t)(b * NN + g * GSZ + r0 + rp) * DIMM + h * DH + dx * 4;
    *(float4*)&o[ob0] = make_float4(oa0[0], oa0[1], oa0[2], oa0[3]);
    *(float4*)&o[ob0 + (size_t)16 * DIMM] = make_float4(oa1[0], oa1[1], oa1[2], oa1[3]);
  }
}

// ---------------------------------------------------------------------------
extern "C" void kernel_launch(void* const* d_in, const int* in_sizes, int n_in,
                              void* d_out, int out_size, void* d_ws, size_t ws_size,
                              hipStream_t stream) {
  const float* x      = (const float*)d_in[0];
  const int*   labels = (const int*)d_in[1];
  const float* scores = (const float*)d_in[2];
  const float* Wq     = (const float*)d_in[3];
  const float* Wk     = (const float*)d_in[4];
  const float* Wv     = (const float*)d_in[5];
  const float* Wproj  = (const float*)d_in[6];

  float* out = (float*)d_out;                               // (B, N, DIM)
  float* attn_out = out + (size_t)BB * NN * DIMM;           // (B, ng, H, gs, ws)

  // layout: qb|kb|vf (fp32) | xpl (3 planes; reused as opl) | weights
  float* qb = (float*)d_ws;
  float* kb = qb + (size_t)MK;
  float* vf = kb + (size_t)MK;
  unsigned short* xpl  = (unsigned short*)(vf + (size_t)MK);
  unsigned short* wqkv = xpl + 3 * (size_t)MK;
  unsigned short* wpp  = wqkv + 9 * (size_t)WK;
  const size_t required = 3 * (size_t)MK * 4 + 3 * (size_t)MK * 2 + 11 * (size_t)WK * 2;

  if (ws_size >= required) {
    split_planes<<<dim3(MK / 1024), 256, 0, stream>>>(x, xpl);
    split_w<<<dim3(4 * WK / 256), 256, 0, stream>>>(Wq, Wk, Wv, Wproj, wqkv, wpp);
    // q,k fp32 via 6-term (bit-identical to R5/R8 selection inputs); v 3-term
    mfma_gemm<3, 6><<<dim3(4, 128, 2), 256, 0, stream>>>(xpl, wqkv, qb);
    mfma_gemm<2, 3><<<dim3(4, 128, 1), 256, 0, stream>>>(xpl, wqkv + 6 * (size_t)WK, vf);
    attn_v14<<<dim3(BB * NGRP * HH * 4), 256, 0, stream>>>(
        qb, kb, vf, labels, scores, attn_out, xpl);
    mfma_gemm<2, 3><<<dim3(4, 128, 1), 256, 0, stream>>>(xpl, wpp, out);
  } else {
    const size_t SZ = (size_t)BB * NN * DIMM;
    float* q2 = (float*)d_ws;
    float* k2 = q2 + SZ;
    float* v2 = k2 + SZ;
    gemm512<<<dim3(4, 128, 3), 256, 0, stream>>>(x, Wq, Wk, Wv, q2, k2, v2);
    attn_f32<<<dim3(BB * NGRP * HH * 4), 256, 0, stream>>>(
        q2, k2, v2, labels, scores, attn_out, q2);
    gemm512<<<dim3(4, 128, 1), 256, 0, stream>>>(q2, Wproj, Wproj, Wproj, out, out, out);
  }
}

// Round 6
// 821.568 us; speedup vs baseline: 3.6585x; 1.5577x over previous
//
#include <hip/hip_runtime.h>

#define BB 4
#define NN 4096
#define DIMM 512
#define HH 8
#define DH 64
#define GSZ 128
#define NGRP 32
#define WSZ 256
#define CHUNK 32

#define MK 8388608u     // 16384*512 elements (x / q / k / v / o planes)
#define WK 262144u      // 512*512

typedef short short8 __attribute__((ext_vector_type(8)));
typedef float f32x4 __attribute__((ext_vector_type(4)));

__device__ inline unsigned short bf16rne(float f) {
  unsigned u = __float_as_uint(f);
  unsigned r = u + 0x7FFFu + ((u >> 16) & 1u);
  return (unsigned short)(r >> 16);
}
__device__ inline float bf16tof(unsigned short h) {
  return __uint_as_float(((unsigned)h) << 16);
}

// ---------------------------------------------------------------------------
// split_planes: fp32 -> 3 bf16 planes (hi, mid, lo); exact residual split
// ---------------------------------------------------------------------------
__global__ __launch_bounds__(256) void split_planes(
    const float* __restrict__ X, unsigned short* __restrict__ P)
{
  unsigned idx = (blockIdx.x * 256u + threadIdx.x) * 4u;
  float4 xv = *(const float4*)&X[idx];
  float xs[4] = {xv.x, xv.y, xv.z, xv.w};
  ushort4 hv, mv, lv;
  unsigned short* hp = (unsigned short*)&hv;
  unsigned short* mp = (unsigned short*)&mv;
  unsigned short* lp = (unsigned short*)&lv;
#pragma unroll
  for (int i = 0; i < 4; ++i) {
    unsigned short h = bf16rne(xs[i]);
    float r1 = xs[i] - bf16tof(h);
    unsigned short m = bf16rne(r1);
    float r2 = r1 - bf16tof(m);
    hp[i] = h;
    mp[i] = m;
    lp[i] = bf16rne(r2);
  }
  *(ushort4*)&P[idx] = hv;
  *(ushort4*)&P[MK + idx] = mv;
  *(ushort4*)&P[2u * MK + idx] = lv;
}

// ---------------------------------------------------------------------------
// split_w: weights -> transposed (N x K) bf16 planes.
// ---------------------------------------------------------------------------
__global__ __launch_bounds__(256) void split_w(
    const float* __restrict__ Wq, const float* __restrict__ Wk,
    const float* __restrict__ Wv, const float* __restrict__ Wpj,
    unsigned short* __restrict__ wqkv, unsigned short* __restrict__ wproj)
{
  unsigned e = blockIdx.x * 256u + threadIdx.x;     // over 4 * 2^18
  int mz = e >> 18;
  unsigned rem = e & (WK - 1u);
  unsigned kk = rem >> 9, n = rem & 511u;
  const float* src = (mz == 0) ? Wq : (mz == 1) ? Wk : (mz == 2) ? Wv : Wpj;
  float w = src[kk * 512u + n];
  unsigned short h = bf16rne(w);
  float r1 = w - bf16tof(h);
  unsigned short m = bf16rne(r1);
  float r2 = r1 - bf16tof(m);
  unsigned short l = bf16rne(r2);
  unsigned o = n * 512u + kk;
  if (mz < 3) {
    unsigned short* base = wqkv + (unsigned)mz * 3u * WK;
    base[o] = h;
    base[WK + o] = m;
    base[2u * WK + o] = l;
  } else {
    wproj[o] = h;
    wproj[WK + o] = m;
  }
}

// ---------------------------------------------------------------------------
// mfma_gemm: C[z] = A(16384x512) @ W[z](512x512) via split-bf16 MFMA.
// ---------------------------------------------------------------------------
template <int NP, int NT>
__global__ __launch_bounds__(256) void mfma_gemm(
    const unsigned short* __restrict__ Ap,   // NP planes, plane stride MK
    const unsigned short* __restrict__ Wp,   // [z][NP][n][k], plane stride WK
    float* __restrict__ C)
{
  constexpr int ta[6] = {0, 0, 1, 1, 0, 2};
  constexpr int tw[6] = {0, 1, 0, 1, 2, 0};
  const int z = blockIdx.z;
  const int n0 = blockIdx.x * 128;
  const int m0 = blockIdx.y * 128;
  const int tid = threadIdx.x;
  const int lane = tid & 63, wv = tid >> 6;
  const int wm = (wv >> 1) * 64, wn = (wv & 1) * 64;
  const int lm = lane & 15, lk = (lane >> 4) * 8;

  __shared__ unsigned short As[NP * 128 * 40];   // stride 40 bf16 = 80 B
  __shared__ unsigned short Ws[NP * 128 * 40];

  f32x4 acc[4][4];
#pragma unroll
  for (int i = 0; i < 4; ++i)
#pragma unroll
    for (int j = 0; j < 4; ++j) acc[i][j] = (f32x4){0.f, 0.f, 0.f, 0.f};

  const unsigned short* Wz = Wp + (size_t)z * NP * WK;

  for (int k0 = 0; k0 < 512; k0 += 32) {
#pragma unroll
    for (int i = 0; i < NP * 2; ++i) {
      int idx = i * 256 + tid;
      int p = idx >> 9, rem = idx & 511;
      int r = rem >> 2, cc = rem & 3;
      *(short8*)&As[p * 5120 + r * 40 + cc * 8] =
          *(const short8*)&Ap[(size_t)p * MK + (size_t)(m0 + r) * 512 + k0 + cc * 8];
      *(short8*)&Ws[p * 5120 + r * 40 + cc * 8] =
          *(const short8*)&Wz[(size_t)p * WK + (size_t)(n0 + r) * 512 + k0 + cc * 8];
    }
    __syncthreads();

    short8 a[NP][4];
#pragma unroll
    for (int p = 0; p < NP; ++p)
#pragma unroll
      for (int fm = 0; fm < 4; ++fm)
        a[p][fm] = *(const short8*)&As[p * 5120 + (wm + fm * 16 + lm) * 40 + lk];

#pragma unroll
    for (int fn = 0; fn < 4; ++fn) {
      short8 bf[NP];
#pragma unroll
      for (int p = 0; p < NP; ++p)
        bf[p] = *(const short8*)&Ws[p * 5120 + (wn + fn * 16 + lm) * 40 + lk];
#pragma unroll
      for (int fm = 0; fm < 4; ++fm) {
#pragma unroll
        for (int t = 0; t < NT; ++t)
          acc[fm][fn] = __builtin_amdgcn_mfma_f32_16x16x32_bf16(
              a[ta[t]][fm], bf[tw[t]], acc[fm][fn], 0, 0, 0);
      }
    }
    __syncthreads();
  }

  const int rq = (lane >> 4) * 4;
  float* Cz = C + (size_t)z * 8388608u;
#pragma unroll
  for (int fm = 0; fm < 4; ++fm)
#pragma unroll
    for (int fn = 0; fn < 4; ++fn) {
      int row = m0 + wm + fm * 16 + rq;
      int col = n0 + wn + fn * 16 + lm;
#pragma unroll
      for (int r = 0; r < 4; ++r)
        Cz[(size_t)(row + r) * 512 + col] = acc[fm][fn][r];
    }
}

// ---------------------------------------------------------------------------
// Fallback fp32 GEMM (only if ws too small for planes).
// ---------------------------------------------------------------------------
__global__ __launch_bounds__(256) void gemm512(
    const float* __restrict__ A,
    const float* __restrict__ W0, const float* __restrict__ W1, const float* __restrict__ W2,
    float* __restrict__ C0, float* __restrict__ C1, float* __restrict__ C2)
{
  const int z = blockIdx.z;
  const float* Wm = (z == 0) ? W0 : (z == 1 ? W1 : W2);
  float* Cm = (z == 0) ? C0 : (z == 1 ? C1 : C2);
  const int n0 = blockIdx.x * 128;
  const int m0 = blockIdx.y * 128;
  const int tid = threadIdx.x;
  const int tx = tid & 15, ty = tid >> 4;

  __shared__ float As[32][132];
  __shared__ float Bs[32][132];

  float acc[8][8];
#pragma unroll
  for (int i = 0; i < 8; ++i)
#pragma unroll
    for (int j = 0; j < 8; ++j) acc[i][j] = 0.f;

  for (int k0 = 0; k0 < 512; k0 += 32) {
    {
      const int c4 = tid & 7, r = tid >> 3;
#pragma unroll
      for (int p = 0; p < 128; p += 32) {
        float4 av = *(const float4*)&A[(size_t)(m0 + r + p) * 512 + k0 + c4 * 4];
        As[c4 * 4 + 0][r + p] = av.x;
        As[c4 * 4 + 1][r + p] = av.y;
        As[c4 * 4 + 2][r + p] = av.z;
        As[c4 * 4 + 3][r + p] = av.w;
      }
      const int j4 = tid & 31, rb = tid >> 5;
#pragma unroll
      for (int p = 0; p < 32; p += 8) {
        *(float4*)&Bs[rb + p][j4 * 4] =
            *(const float4*)&Wm[(size_t)(k0 + rb + p) * 512 + n0 + j4 * 4];
      }
    }
    __syncthreads();
#pragma unroll
    for (int kk = 0; kk < 32; ++kk) {
      float4 a0 = *(const float4*)&As[kk][ty * 8];
      float4 a1 = *(const float4*)&As[kk][ty * 8 + 4];
      float4 b0 = *(const float4*)&Bs[kk][tx * 8];
      float4 b1 = *(const float4*)&Bs[kk][tx * 8 + 4];
      float av[8] = {a0.x, a0.y, a0.z, a0.w, a1.x, a1.y, a1.z, a1.w};
      float bv[8] = {b0.x, b0.y, b0.z, b0.w, b1.x, b1.y, b1.z, b1.w};
#pragma unroll
      for (int i = 0; i < 8; ++i)
#pragma unroll
        for (int j = 0; j < 8; ++j) acc[i][j] += av[i] * bv[j];
    }
    __syncthreads();
  }
#pragma unroll
  for (int i = 0; i < 8; ++i) {
    size_t row = (size_t)(m0 + ty * 8 + i);
    float4 o0 = make_float4(acc[i][0], acc[i][1], acc[i][2], acc[i][3]);
    float4 o1 = make_float4(acc[i][4], acc[i][5], acc[i][6], acc[i][7]);
    *(float4*)&Cm[row * 512 + n0 + tx * 8] = o0;
    *(float4*)&Cm[row * 512 + n0 + tx * 8 + 4] = o1;
  }
}

// ---------------------------------------------------------------------------
// focus/keep computation (shared).
// ---------------------------------------------------------------------------
__device__ __forceinline__ void focus_keep(
    const unsigned char* klab, const float* kscr, int* hist8, float* s_var,
    int* s_sk, int* s_ck, int tid, int lane, int wv)
{
  if (tid < GSZ) atomicAdd(&hist8[klab[tid]], 1);
  if (wv == 0) {
    double x0 = (double)kscr[lane], x1 = (double)kscr[lane + 64];
    double s = x0 + x1;
#pragma unroll
    for (int off = 32; off > 0; off >>= 1) s += __shfl_xor(s, off);
    double mean = s * (1.0 / 128.0);
    double d0 = x0 - mean, d1 = x1 - mean;
    double vs = d0 * d0 + d1 * d1;
#pragma unroll
    for (int off = 32; off > 0; off >>= 1) vs += __shfl_xor(vs, off);
    if (lane == 0) *s_var = (float)(vs * (1.0 / 128.0));
  }
  __syncthreads();
  if (tid == 0) {
    int bc = hist8[0];
    for (int l = 1; l < 8; ++l)
      if (hist8[l] > bc) bc = hist8[l];
    float purity = (float)bc * (1.0f / GSZ);
    float focus = 0.5f + 0.25f * purity - 0.25f * (*s_var);
    focus = fminf(fmaxf(focus, 0.25f), 0.75f);
    int keep = (int)ceilf(focus * (float)WSZ);
    keep = min(max(keep, 1), WSZ);
    int ck = keep >> 3, rem = keep & 7;          // round-half-even(keep/8)
    if (rem > 4 || (rem == 4 && (ck & 1))) ck++;
    if (ck < 1) ck = 1;
    int sk = keep - ck;
    if (sk < 1) sk = 1;
    *s_sk = sk;
    *s_ck = ck;
  }
  __syncthreads();
}

// ---------------------------------------------------------------------------
// attn v15 == v10's verified kernel (passed, absmax 0.0039) with ONE change:
// __launch_bounds__(256,4) -> (256,3). v10's (256,4) capped the register
// budget at 512/4=128 and the allocator squeezed to 64 VGPR -> ~5.5KB/thread
// scratch spills -> 1.7GB HBM traffic thrashing L3 (which otherwise serves
// ALL K/V restaging: q/k/v fp32 = 96MB, fully L3-resident). Plain bounds
// (v13/v14) let total allocation (VGPR+AGPR spill-copies, unified file)
// balloon past 256/wave -> 1 wave/SIMD, 12% occupancy. (256,3) = budget
// ~170 regs: comfortably above this structure's natural ~84-110 (v9's
// near-identical phase code compiled to 84 under the same bound) -> no
// squeeze, no spill, and LDS 36.9KB still permits 4 blocks/CU.
// Structure (verified R1): TWO 16-row halves (QK -> rank -> PV each);
// att[16][264] f32 + ktile/vtT alias; selection arithmetic bit-identical
// to v9 per-(row,col).
// ---------------------------------------------------------------------------
__global__ __launch_bounds__(256, 3) void attn_v15(
    const float* __restrict__ q, const float* __restrict__ k,
    const float* __restrict__ vf,
    const int* __restrict__ labels, const float* __restrict__ scores,
    float* __restrict__ attn_out, unsigned short* __restrict__ opl)
{
  const int bx = blockIdx.x;
  const int c = bx >> 10;
  const int rblk = bx & 1023;
  const int h = rblk & 7;
  const int g = (rblk >> 3) & 31;
  const int b = rblk >> 8;
  const int r0 = c * CHUNK;
  const int tid = threadIdx.x;
  const int lane = tid & 63, wv = tid >> 6;
  const int lm = lane & 15, lq = lane >> 4;

  // att row = 264 fp32 (1056 B): fp32 logits, later hosts phi[0..263] (528B)
  // + pmid[0..263] (528B) overlays in the SAME row (wave-private, race-free).
  __shared__ float att[16][264];
  __shared__ __align__(16) unsigned char vbuf[18432];  // ktile f32[64][68] / vtT u16[2][64][72]
  float (*ktile)[68] = (float (*)[68])vbuf;
  unsigned short* vtT = (unsigned short*)vbuf;         // plane stride 4608 shorts
  __shared__ unsigned char klab[WSZ];
  __shared__ float kscr[WSZ];
  __shared__ int hist8[8];
  __shared__ float s_var;
  __shared__ int s_sk, s_ck;

  {
    int j = tid;
    int pos = g * GSZ + j;
    int tok = pos < NN ? pos : (2 * NN - 1 - pos);
    klab[j] = (unsigned char)labels[b * NN + tok];
    kscr[j] = scores[b * NN + tok];
  }
  if (tid < 8) hist8[tid] = 0;
  __syncthreads();
  focus_keep(klab, kscr, hist8, &s_var, &s_sk, &s_ck, tid, lane, wv);
  const int same_keep = s_sk, cross_keep = s_ck;

  const int srow = tid >> 4, sd4 = (tid & 15) * 4;
  const int rp2 = tid >> 5, jx2 = tid & 31;   // QK: rows (rp2, rp2+8), 32 cols

  int kl0[4];
  float ks0[4];
#pragma unroll
  for (int m = 0; m < 4; ++m) {
    kl0[m] = klab[lane + 64 * m];
    ks0[m] = kscr[lane + 64 * m];
  }

  for (int half = 0; half < 2; ++half) {
    const int rbase = r0 + half * 16;    // absolute q-row base within window
    __syncthreads();   // prev half's vtT/att reads done before restaging

    const float* q0p = q + (size_t)(b * NN + g * GSZ + rbase + rp2) * DIMM + h * DH;
    const float* q1p = q0p + (size_t)8 * DIMM;

    // ---- QK^T: fp32 VALU, FMA chain per (row,col) identical to v9 ----
    for (int jt = 0; jt < 4; ++jt) {
#pragma unroll
      for (int p = 0; p < 64; p += 16) {
        int j = jt * 64 + srow + p;
        int pos = g * GSZ + j;
        int tok = pos < NN ? pos : (2 * NN - 1 - pos);
        *(float4*)&ktile[srow + p][sd4] =
            *(const float4*)&k[(size_t)(b * NN + tok) * DIMM + h * DH + sd4];
      }
      __syncthreads();
      float acc0[2] = {0.f, 0.f}, acc1[2] = {0.f, 0.f};
#pragma unroll
      for (int dd = 0; dd < DH; dd += 4) {
        float4 q0 = *(const float4*)(q0p + dd);
        float4 q1 = *(const float4*)(q1p + dd);
#pragma unroll
        for (int jj = 0; jj < 2; ++jj) {
          float4 kv = *(const float4*)&ktile[jx2 + 32 * jj][dd];
          acc0[jj] += q0.x * kv.x + q0.y * kv.y + q0.z * kv.z + q0.w * kv.w;
          acc1[jj] += q1.x * kv.x + q1.y * kv.y + q1.z * kv.z + q1.w * kv.w;
        }
      }
#pragma unroll
      for (int jj = 0; jj < 2; ++jj) {
        att[rp2][jt * 64 + jx2 + 32 * jj] = acc0[jj] * 0.125f;
        att[rp2 + 8][jt * 64 + jx2 + 32 * jj] = acc1[jj] * 0.125f;
      }
      __syncthreads();
    }

    // ---- rank: identical compute; rows wv*4 + 2sp + {0,1} of this half ----
    {
      for (int sp = 0; sp < 2; ++sp) {
        const int rA = wv * 4 + 2 * sp, rB = rA + 1;
        const int qLA = klab[rbase + rA], qLB = klab[rbase + rB];
        const float qSA = kscr[rbase + rA], qSB = kscr[rbase + rB];
        float aA[4], aB[4];
        float mxA = -INFINITY, mxB = -INFINITY;
#pragma unroll
        for (int m = 0; m < 4; ++m) {
          aA[m] = att[rA][lane + 64 * m];
          aB[m] = att[rB][lane + 64 * m];
          mxA = fmaxf(mxA, aA[m]);
          mxB = fmaxf(mxB, aB[m]);
        }
#pragma unroll
        for (int off = 32; off > 0; off >>= 1) {
          mxA = fmaxf(mxA, __shfl_xor(mxA, off));
          mxB = fmaxf(mxB, __shfl_xor(mxB, off));
        }
        unsigned fsA[4], fcA[4], fsB[4], fcB[4];
        bool cdA[4], cdB[4];
#pragma unroll
        for (int m = 0; m < 4; ++m) {
          aA[m] = expf(aA[m] - mxA);
          aB[m] = expf(aB[m] - mxB);
          cdA[m] = (kl0[m] == qLA);
          cdB[m] = (kl0[m] == qLB);
          fsA[m] = cdA[m] ? __float_as_uint(aA[m]) : 0u;
          fsB[m] = cdB[m] ? __float_as_uint(aB[m]) : 0u;
          fcA[m] = __float_as_uint(aA[m] * (qSA * ks0[m]));
          fcB[m] = __float_as_uint(aB[m] * (qSB * ks0[m]));
        }
        unsigned tsA = 0, tcA = 0, tsB = 0, tcB = 0;
        for (int bit = 29; bit >= 0; --bit) {
          unsigned csA = tsA | (1u << bit), ccA = tcA | (1u << bit);
          unsigned csB = tsB | (1u << bit), ccB = tcB | (1u << bit);
          int nsA = 0, ncA = 0, nsB = 0, ncB = 0;
#pragma unroll
          for (int m = 0; m < 4; ++m) {
            nsA += __popcll(__ballot(fsA[m] >= csA));
            ncA += __popcll(__ballot(fcA[m] >= ccA));
            nsB += __popcll(__ballot(fsB[m] >= csB));
            ncB += __popcll(__ballot(fcB[m] >= ccB));
          }
          if (nsA >= same_keep) tsA = csA;
          if (ncA >= cross_keep) tcA = ccA;
          if (nsB >= same_keep) tsB = csB;
          if (ncB >= cross_keep) tcB = ccB;
        }
#pragma unroll
        for (int rsel = 0; rsel < 2; ++rsel) {
          const int rr = rsel ? rB : rA;
          const unsigned ts = rsel ? tsB : tsA, tc = rsel ? tcB : tcA;
          unsigned* fs = rsel ? fsB : fsA;
          unsigned* fc = rsel ? fcB : fcA;
          float* a = rsel ? aB : aA;
          bool* cand = rsel ? cdB : cdA;
          unsigned long long beqs[4], beqc[4];
          int gts = 0, gtc = 0;
#pragma unroll
          for (int m = 0; m < 4; ++m) {
            gts += __popcll(__ballot(fs[m] > ts));
            gtc += __popcll(__ballot(fc[m] > tc));
            beqs[m] = __ballot(fs[m] == ts);
            beqc[m] = __ballot(fc[m] == tc);
          }
          const int rs = same_keep - gts, rc = cross_keep - gtc;
          float pv[4];
          float S = 0.f;
          int pres = 0, prec = 0;
#pragma unroll
          for (int m = 0; m < 4; ++m) {
            int mbs = __builtin_amdgcn_mbcnt_hi((unsigned)(beqs[m] >> 32),
                       __builtin_amdgcn_mbcnt_lo((unsigned)beqs[m], 0));
            int mbc = __builtin_amdgcn_mbcnt_hi((unsigned)(beqc[m] >> 32),
                       __builtin_amdgcn_mbcnt_lo((unsigned)beqc[m], 0));
            bool keep_s = cand[m] && ((fs[m] > ts) || ((fs[m] == ts) && (pres + mbs < rs)));
            bool keep_c = (!cand[m]) && ((fc[m] > tc) || ((fc[m] == tc) && (prec + mbc < rc)));
            pv[m] = (keep_s || keep_c) ? a[m] : 0.f;
            S += pv[m];
            pres += __popcll(beqs[m]);
            prec += __popcll(beqc[m]);
          }
#pragma unroll
          for (int off = 32; off > 0; off >>= 1) S += __shfl_xor(S, off);
          const float inv = 1.0f / S;
          size_t gb = ((((size_t)b * NGRP + g) * HH + h) * GSZ + (rbase + rr)) * WSZ + lane;
          unsigned short* prow = (unsigned short*)&att[rr][0];
#pragma unroll
          for (int m = 0; m < 4; ++m) {
            float p = pv[m] * inv;
            attn_out[gb + 64 * m] = p;
            unsigned short hh = bf16rne(p);
            prow[lane + 64 * m] = hh;                          // phi
            prow[264 + lane + 64 * m] = bf16rne(p - bf16tof(hh)); // pmid
          }
        }
      }
    }

    // ---- PV via MFMA: D(16x64) = P(16x256) @ V(256x64), 3-term split ----
    f32x4 acc2 = (f32x4){0.f, 0.f, 0.f, 0.f};
    for (int jt = 0; jt < 4; ++jt) {
      __syncthreads();   // overlays done (jt=0) / prior MFMA reads done (jt>0)
      // stage V^T tile: vtT[pl][d][j], 64 j of this jt; pair-packed b32 writes
      {
        const int dx_ = tid & 15, jh = tid >> 4;      // jh 0..15
#pragma unroll
        for (int ps = 0; ps < 2; ++ps) {
          int jl0 = ps * 32 + 2 * jh;
          float4 v0, v1;
#pragma unroll
          for (int qq = 0; qq < 2; ++qq) {
            int pos = g * GSZ + jt * 64 + jl0 + qq;
            int tok = pos < NN ? pos : (2 * NN - 1 - pos);
            float4 vv = *(const float4*)&vf[(size_t)(b * NN + tok) * DIMM + h * DH + dx_ * 4];
            if (qq == 0) v0 = vv; else v1 = vv;
          }
          const float* a0 = (const float*)&v0;
          const float* a1 = (const float*)&v1;
#pragma unroll
          for (int i = 0; i < 4; ++i) {
            int d = dx_ * 4 + i;
            unsigned short h0 = bf16rne(a0[i]);
            unsigned short h1 = bf16rne(a1[i]);
            unsigned short m0 = bf16rne(a0[i] - bf16tof(h0));
            unsigned short m1 = bf16rne(a1[i] - bf16tof(h1));
            *(unsigned*)&vtT[0 * 4608 + d * 72 + jl0] = (unsigned)h0 | ((unsigned)h1 << 16);
            *(unsigned*)&vtT[1 * 4608 + d * 72 + jl0] = (unsigned)m0 | ((unsigned)m1 << 16);
          }
        }
      }
      __syncthreads();
#pragma unroll
      for (int kt = 0; kt < 2; ++kt) {
        const int koff = jt * 64 + kt * 32 + lq * 8;
        const unsigned short* arow = (const unsigned short*)&att[lm][0];
        short8 ahi = *(const short8*)&arow[koff];
        short8 ami = *(const short8*)&arow[264 + koff];
        const int vo = (wv * 16 + lm) * 72 + kt * 32 + lq * 8;
        short8 bhi = *(const short8*)&vtT[vo];
        short8 bmi = *(const short8*)&vtT[4608 + vo];
        acc2 = __builtin_amdgcn_mfma_f32_16x16x32_bf16(ahi, bhi, acc2, 0, 0, 0);
        acc2 = __builtin_amdgcn_mfma_f32_16x16x32_bf16(ahi, bmi, acc2, 0, 0, 0);
        acc2 = __builtin_amdgcn_mfma_f32_16x16x32_bf16(ami, bhi, acc2, 0, 0, 0);
      }
    }

    // ---- o epilogue: C/D col=lane&15 (d), row=lq*4+r; 2 bf16 planes ----
    {
      size_t rowbase = (size_t)(b * NN + g * GSZ + rbase);
#pragma unroll
      for (int r = 0; r < 4; ++r) {
        int row = lq * 4 + r;
        float val = acc2[r];
        unsigned short hh = bf16rne(val);
        size_t oaddr = (rowbase + row) * 512 + h * 64 + wv * 16 + lm;
        opl[oaddr] = hh;
        opl[MK + oaddr] = bf16rne(val - bf16tof(hh));
      }
    }
  }
}

// ---------------------------------------------------------------------------
// Fallback attn (fp32 q/k/v in, fp32 o out aliasing q) — small-ws path only.
// ---------------------------------------------------------------------------
__global__ __launch_bounds__(256, 3) void attn_f32(
    const float* q, const float* __restrict__ k, const float* __restrict__ v,
    const int* __restrict__ labels, const float* __restrict__ scores,
    float* __restrict__ attn_out, float* o)
{
  const int bx = blockIdx.x;
  const int c = bx >> 10;
  const int rblk = bx & 1023;
  const int h = rblk & 7;
  const int g = (rblk >> 3) & 31;
  const int b = rblk >> 8;
  const int r0 = c * CHUNK;
  const int tid = threadIdx.x;
  const int lane = tid & 63, wv = tid >> 6;

  __shared__ float att[CHUNK][WSZ + 4];
  __shared__ float ktile[64][DH + 4];
  __shared__ unsigned char klab[WSZ];
  __shared__ float kscr[WSZ];
  __shared__ int hist8[8];
  __shared__ float s_var;
  __shared__ int s_sk, s_ck;

  {
    int j = tid;
    int pos = g * GSZ + j;
    int tok = pos < NN ? pos : (2 * NN - 1 - pos);
    klab[j] = (unsigned char)labels[b * NN + tok];
    kscr[j] = scores[b * NN + tok];
  }
  if (tid < 8) hist8[tid] = 0;
  __syncthreads();
  focus_keep(klab, kscr, hist8, &s_var, &s_sk, &s_ck, tid, lane, wv);
  const int same_keep = s_sk, cross_keep = s_ck;

  const int rp = tid >> 4, jx = tid & 15;
  const int srow = tid >> 4, sd4 = (tid & 15) * 4;
  const float* q0p = q + (size_t)(b * NN + g * GSZ + r0 + rp) * DIMM + h * DH;
  const float* q1p = q0p + (size_t)16 * DIMM;

  for (int jt = 0; jt < 4; ++jt) {
#pragma unroll
    for (int p = 0; p < 64; p += 16) {
      int j = jt * 64 + srow + p;
      int pos = g * GSZ + j;
      int tok = pos < NN ? pos : (2 * NN - 1 - pos);
      *(float4*)&ktile[srow + p][sd4] =
          *(const float4*)&k[(size_t)(b * NN + tok) * DIMM + h * DH + sd4];
    }
    __syncthreads();
    float acc0[4] = {0.f, 0.f, 0.f, 0.f}, acc1[4] = {0.f, 0.f, 0.f, 0.f};
#pragma unroll
    for (int dd = 0; dd < DH; dd += 4) {
      float4 q0 = *(const float4*)(q0p + dd);
      float4 q1 = *(const float4*)(q1p + dd);
#pragma unroll
      for (int jj = 0; jj < 4; ++jj) {
        float4 kv = *(const float4*)&ktile[jx + 16 * jj][dd];
        acc0[jj] += q0.x * kv.x + q0.y * kv.y + q0.z * kv.z + q0.w * kv.w;
        acc1[jj] += q1.x * kv.x + q1.y * kv.y + q1.z * kv.z + q1.w * kv.w;
      }
    }
#pragma unroll
    for (int jj = 0; jj < 4; ++jj) {
      att[rp][jt * 64 + jx + 16 * jj] = acc0[jj] * 0.125f;
      att[rp + 16][jt * 64 + jx + 16 * jj] = acc1[jj] * 0.125f;
    }
    __syncthreads();
  }

  {
    int kl0[4];
    float ks0[4];
#pragma unroll
    for (int m = 0; m < 4; ++m) {
      kl0[m] = klab[lane + 64 * m];
      ks0[m] = kscr[lane + 64 * m];
    }
    for (int sp = 0; sp < 4; ++sp) {
      const int rA = wv * 8 + 2 * sp, rB = rA + 1;
      const int qLA = klab[r0 + rA], qLB = klab[r0 + rB];
      const float qSA = kscr[r0 + rA], qSB = kscr[r0 + rB];
      float aA[4], aB[4];
      float mxA = -INFINITY, mxB = -INFINITY;
#pragma unroll
      for (int m = 0; m < 4; ++m) {
        aA[m] = att[rA][lane + 64 * m];
        aB[m] = att[rB][lane + 64 * m];
        mxA = fmaxf(mxA, aA[m]);
        mxB = fmaxf(mxB, aB[m]);
      }
#pragma unroll
      for (int off = 32; off > 0; off >>= 1) {
        mxA = fmaxf(mxA, __shfl_xor(mxA, off));
        mxB = fmaxf(mxB, __shfl_xor(mxB, off));
      }
      unsigned fsA[4], fcA[4], fsB[4], fcB[4];
      bool cdA[4], cdB[4];
#pragma unroll
      for (int m = 0; m < 4; ++m) {
        aA[m] = expf(aA[m] - mxA);
        aB[m] = expf(aB[m] - mxB);
        cdA[m] = (kl0[m] == qLA);
        cdB[m] = (kl0[m] == qLB);
        fsA[m] = cdA[m] ? __float_as_uint(aA[m]) : 0u;
        fsB[m] = cdB[m] ? __float_as_uint(aB[m]) : 0u;
        fcA[m] = __float_as_uint(aA[m] * (qSA * ks0[m]));
        fcB[m] = __float_as_uint(aB[m] * (qSB * ks0[m]));
      }
      unsigned tsA = 0, tcA = 0, tsB = 0, tcB = 0;
      for (int bit = 29; bit >= 0; --bit) {
        unsigned csA = tsA | (1u << bit), ccA = tcA | (1u << bit);
        unsigned csB = tsB | (1u << bit), ccB = tcB | (1u << bit);
        int nsA = 0, ncA = 0, nsB = 0, ncB = 0;
#pragma unroll
        for (int m = 0; m < 4; ++m) {
          nsA += __popcll(__ballot(fsA[m] >= csA));
          ncA += __popcll(__ballot(fcA[m] >= ccA));
          nsB += __popcll(__ballot(fsB[m] >= csB));
          ncB += __popcll(__ballot(fcB[m] >= ccB));
        }
        if (nsA >= same_keep) tsA = csA;
        if (ncA >= cross_keep) tcA = ccA;
        if (nsB >= same_keep) tsB = csB;
        if (ncB >= cross_keep) tcB = ccB;
      }
#pragma unroll
      for (int rsel = 0; rsel < 2; ++rsel) {
        const int rr = rsel ? rB : rA;
        const unsigned ts = rsel ? tsB : tsA, tc = rsel ? tcB : tcA;
        unsigned* fs = rsel ? fsB : fsA;
        unsigned* fc = rsel ? fcB : fcA;
        float* a = rsel ? aB : aA;
        bool* cand = rsel ? cdB : cdA;
        unsigned long long beqs[4], beqc[4];
        int gts = 0, gtc = 0;
#pragma unroll
        for (int m = 0; m < 4; ++m) {
          gts += __popcll(__ballot(fs[m] > ts));
          gtc += __popcll(__ballot(fc[m] > tc));
          beqs[m] = __ballot(fs[m] == ts);
          beqc[m] = __ballot(fc[m] == tc);
        }
        const int rs = same_keep - gts, rc = cross_keep - gtc;
        float pv[4];
        float S = 0.f;
        int pres = 0, prec = 0;
#pragma unroll
        for (int m = 0; m < 4; ++m) {
          int mbs = __builtin_amdgcn_mbcnt_hi((unsigned)(beqs[m] >> 32),
                     __builtin_amdgcn_mbcnt_lo((unsigned)beqs[m], 0));
          int mbc = __builtin_amdgcn_mbcnt_hi((unsigned)(beqc[m] >> 32),
                     __builtin_amdgcn_mbcnt_lo((unsigned)beqc[m], 0));
          bool keep_s = cand[m] && ((fs[m] > ts) || ((fs[m] == ts) && (pres + mbs < rs)));
          bool keep_c = (!cand[m]) && ((fc[m] > tc) || ((fc[m] == tc) && (prec + mbc < rc)));
          pv[m] = (keep_s || keep_c) ? a[m] : 0.f;
          S += pv[m];
          pres += __popcll(beqs[m]);
          prec += __popcll(beqc[m]);
        }
#pragma unroll
        for (int off = 32; off > 0; off >>= 1) S += __shfl_xor(S, off);
        const float inv = 1.0f / S;
        size_t gb = ((((size_t)b * NGRP + g) * HH + h) * GSZ + (r0 + rr)) * WSZ + lane;
#pragma unroll
        for (int m = 0; m < 4; ++m) {
          float p = pv[m] * inv;
          att[rr][lane + 64 * m] = p;
          attn_out[gb + 64 * m] = p;
        }
      }
    }
  }
  __syncthreads();

  const int dx = jx;
  float oa0[4] = {0.f, 0.f, 0.f, 0.f}, oa1[4] = {0.f, 0.f, 0.f, 0.f};
  for (int jt = 0; jt < 4; ++jt) {
#pragma unroll
    for (int p = 0; p < 64; p += 16) {
      int j = jt * 64 + srow + p;
      int pos = g * GSZ + j;
      int tok = pos < NN ? pos : (2 * NN - 1 - pos);
      *(float4*)&ktile[srow + p][sd4] =
          *(const float4*)&v[(size_t)(b * NN + tok) * DIMM + h * DH + sd4];
    }
    __syncthreads();
#pragma unroll 4
    for (int jg = 0; jg < 16; ++jg) {
      float4 p0 = *(const float4*)&att[rp][jt * 64 + jg * 4];
      float4 p1 = *(const float4*)&att[rp + 16][jt * 64 + jg * 4];
      float4 v0 = *(const float4*)&ktile[jg * 4 + 0][dx * 4];
      float4 v1 = *(const float4*)&ktile[jg * 4 + 1][dx * 4];
      float4 v2 = *(const float4*)&ktile[jg * 4 + 2][dx * 4];
      float4 v3 = *(const float4*)&ktile[jg * 4 + 3][dx * 4];
      oa0[0] += p0.x * v0.x + p0.y * v1.x + p0.z * v2.x + p0.w * v3.x;
      oa0[1] += p0.x * v0.y + p0.y * v1.y + p0.z * v2.y + p0.w * v3.y;
      oa0[2] += p0.x * v0.z + p0.y * v1.z + p0.z * v2.z + p0.w * v3.z;
      oa0[3] += p0.x * v0.w + p0.y * v1.w + p0.z * v2.w + p0.w * v3.w;
      oa1[0] += p1.x * v0.x + p1.y * v1.x + p1.z * v2.x + p1.w * v3.x;
      oa1[1] += p1.x * v0.y + p1.y * v1.y + p1.z * v2.y + p1.w * v3.y;
      oa1[2] += p1.x * v0.z + p1.y * v1.z + p1.z * v2.z + p1.w * v3.z;
      oa1[3] += p1.x * v0.w + p1.y * v1.w + p1.z * v2.w + p1.w * v3.w;
    }
    __syncthreads();
  }
  {
    size_t ob0 = (size_t)(b * NN + g * GSZ + r0 + rp) * DIMM + h * DH + dx * 4;
    *(float4*)&o[ob0] = make_float4(oa0[0], oa0[1], oa0[2], oa0[3]);
    *(float4*)&o[ob0 + (size_t)16 * DIMM] = make_float4(oa1[0], oa1[1], oa1[2], oa1[3]);
  }
}

// ---------------------------------------------------------------------------
extern "C" void kernel_launch(void* const* d_in, const int* in_sizes, int n_in,
                              void* d_out, int out_size, void* d_ws, size_t ws_size,
                              hipStream_t stream) {
  const float* x      = (const float*)d_in[0];
  const int*   labels = (const int*)d_in[1];
  const float* scores = (const float*)d_in[2];
  const float* Wq     = (const float*)d_in[3];
  const float* Wk     = (const float*)d_in[4];
  const float* Wv     = (const float*)d_in[5];
  const float* Wproj  = (const float*)d_in[6];

  float* out = (float*)d_out;                               // (B, N, DIM)
  float* attn_out = out + (size_t)BB * NN * DIMM;           // (B, ng, H, gs, ws)

  // layout: qb|kb|vf (fp32) | xpl (3 planes; reused as opl) | weights
  float* qb = (float*)d_ws;
  float* kb = qb + (size_t)MK;
  float* vf = kb + (size_t)MK;
  unsigned short* xpl  = (unsigned short*)(vf + (size_t)MK);
  unsigned short* wqkv = xpl + 3 * (size_t)MK;
  unsigned short* wpp  = wqkv + 9 * (size_t)WK;
  const size_t required = 3 * (size_t)MK * 4 + 3 * (size_t)MK * 2 + 11 * (size_t)WK * 2;

  if (ws_size >= required) {
    split_planes<<<dim3(MK / 1024), 256, 0, stream>>>(x, xpl);
    split_w<<<dim3(4 * WK / 256), 256, 0, stream>>>(Wq, Wk, Wv, Wproj, wqkv, wpp);
    // q,k fp32 via 6-term (bit-identical to R5/R8 selection inputs); v 3-term
    mfma_gemm<3, 6><<<dim3(4, 128, 2), 256, 0, stream>>>(xpl, wqkv, qb);
    mfma_gemm<2, 3><<<dim3(4, 128, 1), 256, 0, stream>>>(xpl, wqkv + 6 * (size_t)WK, vf);
    attn_v15<<<dim3(BB * NGRP * HH * 4), 256, 0, stream>>>(
        qb, kb, vf, labels, scores, attn_out, xpl);
    mfma_gemm<2, 3><<<dim3(4, 128, 1), 256, 0, stream>>>(xpl, wpp, out);
  } else {
    const size_t SZ = (size_t)BB * NN * DIMM;
    float* q2 = (float*)d_ws;
    float* k2 = q2 + SZ;
    float* v2 = k2 + SZ;
    gemm512<<<dim3(4, 128, 3), 256, 0, stream>>>(x, Wq, Wk, Wv, q2, k2, v2);
    attn_f32<<<dim3(BB * NGRP * HH * 4), 256, 0, stream>>>(
        q2, k2, v2, labels, scores, attn_out, q2);
    gemm512<<<dim3(4, 128, 1), 256, 0, stream>>>(q2, Wproj, Wproj, Wproj, out, out, out);
  }
}

// Round 7
// 729.385 us; speedup vs baseline: 4.1209x; 1.1264x over previous
//
#include <hip/hip_runtime.h>

#define BB 4
#define NN 4096
#define DIMM 512
#define HH 8
#define DH 64
#define GSZ 128
#define NGRP 32
#define WSZ 256
#define CHUNK 32

#define MK 8388608u     // 16384*512 elements (x / q / k / v / o planes)
#define WK 262144u      // 512*512

typedef short short8 __attribute__((ext_vector_type(8)));
typedef float f32x4 __attribute__((ext_vector_type(4)));

__device__ inline unsigned short bf16rne(float f) {
  unsigned u = __float_as_uint(f);
  unsigned r = u + 0x7FFFu + ((u >> 16) & 1u);
  return (unsigned short)(r >> 16);
}
__device__ inline float bf16tof(unsigned short h) {
  return __uint_as_float(((unsigned)h) << 16);
}

// async global->LDS, 16B per lane; dest = wave-uniform base + lane*16.
__device__ __forceinline__ void gload_lds16(const void* g, void* l) {
  __builtin_amdgcn_global_load_lds(
      (const __attribute__((address_space(1))) void*)g,
      (__attribute__((address_space(3))) void*)l, 16, 0, 0);
}

// ---------------------------------------------------------------------------
// split_planes: fp32 -> 3 bf16 planes (hi, mid, lo); exact residual split
// ---------------------------------------------------------------------------
__global__ __launch_bounds__(256) void split_planes(
    const float* __restrict__ X, unsigned short* __restrict__ P)
{
  unsigned idx = (blockIdx.x * 256u + threadIdx.x) * 4u;
  float4 xv = *(const float4*)&X[idx];
  float xs[4] = {xv.x, xv.y, xv.z, xv.w};
  ushort4 hv, mv, lv;
  unsigned short* hp = (unsigned short*)&hv;
  unsigned short* mp = (unsigned short*)&mv;
  unsigned short* lp = (unsigned short*)&lv;
#pragma unroll
  for (int i = 0; i < 4; ++i) {
    unsigned short h = bf16rne(xs[i]);
    float r1 = xs[i] - bf16tof(h);
    unsigned short m = bf16rne(r1);
    float r2 = r1 - bf16tof(m);
    hp[i] = h;
    mp[i] = m;
    lp[i] = bf16rne(r2);
  }
  *(ushort4*)&P[idx] = hv;
  *(ushort4*)&P[MK + idx] = mv;
  *(ushort4*)&P[2u * MK + idx] = lv;
}

// ---------------------------------------------------------------------------
// split_w: weights -> transposed (N x K) bf16 planes.
// ---------------------------------------------------------------------------
__global__ __launch_bounds__(256) void split_w(
    const float* __restrict__ Wq, const float* __restrict__ Wk,
    const float* __restrict__ Wv, const float* __restrict__ Wpj,
    unsigned short* __restrict__ wqkv, unsigned short* __restrict__ wproj)
{
  unsigned e = blockIdx.x * 256u + threadIdx.x;     // over 4 * 2^18
  int mz = e >> 18;
  unsigned rem = e & (WK - 1u);
  unsigned kk = rem >> 9, n = rem & 511u;
  const float* src = (mz == 0) ? Wq : (mz == 1) ? Wk : (mz == 2) ? Wv : Wpj;
  float w = src[kk * 512u + n];
  unsigned short h = bf16rne(w);
  float r1 = w - bf16tof(h);
  unsigned short m = bf16rne(r1);
  float r2 = r1 - bf16tof(m);
  unsigned short l = bf16rne(r2);
  unsigned o = n * 512u + kk;
  if (mz < 3) {
    unsigned short* base = wqkv + (unsigned)mz * 3u * WK;
    base[o] = h;
    base[WK + o] = m;
    base[2u * WK + o] = l;
  } else {
    wproj[o] = h;
    wproj[WK + o] = m;
  }
}

// ---------------------------------------------------------------------------
// mfma_gemm: C[z] = A(16384x512) @ W[z](512x512) via split-bf16 MFMA.
// v16: staging via __builtin_amdgcn_global_load_lds width=16 into LINEAR
// (pad-free) LDS tiles [128][32] bf16 per plane. Same staged VALUES, same
// fragment assignment, same MFMA t/k0 order as before -> outputs
// bit-identical to the verified kernel. LDS shrinks (no stride-40 pad):
// NP=3: 61.4->48KB (3 blocks/CU, was 2); NP=2: 41->32KB (4, was 3).
// Per m93->m97 ladder (+69%), removing the VGPR round-trip + address VALU
// in staging is the main lever; known 8-way ds_read bank conflict on the
// linear layout is the m97 tradeoff (m98: present yet 874 TF).
// ---------------------------------------------------------------------------
template <int NP, int NT>
__global__ __launch_bounds__(256) void mfma_gemm(
    const unsigned short* __restrict__ Ap,   // NP planes, plane stride MK
    const unsigned short* __restrict__ Wp,   // [z][NP][n][k], plane stride WK
    float* __restrict__ C)
{
  constexpr int ta[6] = {0, 0, 1, 1, 0, 2};
  constexpr int tw[6] = {0, 1, 0, 1, 2, 0};
  const int z = blockIdx.z;
  const int n0 = blockIdx.x * 128;
  const int m0 = blockIdx.y * 128;
  const int tid = threadIdx.x;
  const int lane = tid & 63, wv = tid >> 6;
  const int wm = (wv >> 1) * 64, wn = (wv & 1) * 64;
  const int lm = lane & 15, lk = (lane >> 4) * 8;

  // linear tiles: per plane [128 rows][32 shorts], row stride 64B
  __shared__ unsigned short Asl[NP * 4096];
  __shared__ unsigned short Wsl[NP * 4096];

  f32x4 acc[4][4];
#pragma unroll
  for (int i = 0; i < 4; ++i)
#pragma unroll
    for (int j = 0; j < 4; ++j) acc[i][j] = (f32x4){0.f, 0.f, 0.f, 0.f};

  const unsigned short* Wz = Wp + (size_t)z * NP * WK;

  const int lrow = lane >> 2;          // 0..15 within a 16-row chunk
  const int lcol8 = (lane & 3) * 8;    // short offset within row (0,8,16,24)

  for (int k0 = 0; k0 < 512; k0 += 32) {
    // stage NP*2 plane-tiles; each = 8 chunks of 16 rows x 32 shorts (1KB).
    // total chunks = NP*16, per wave NP*4; lane l covers row r0+l/4,
    // shorts (l&3)*8.. — matches the linear LDS dest (base + lane*16B).
#pragma unroll
    for (int i = 0; i < NP * 4; ++i) {
      int c = wv * (NP * 4) + i;
      bool isW = c >= NP * 8;
      int cc = isW ? c - NP * 8 : c;
      int p = cc >> 3, r0 = (cc & 7) * 16;
      const unsigned short* gsrc =
          (isW ? Wz + (size_t)p * WK + (size_t)(n0 + r0 + lrow) * 512
               : Ap + (size_t)p * MK + (size_t)(m0 + r0 + lrow) * 512)
          + k0 + lcol8;
      unsigned short* ldst = (isW ? &Wsl[p * 4096 + r0 * 32]
                                  : &Asl[p * 4096 + r0 * 32]);
      gload_lds16(gsrc, ldst);
    }
    __syncthreads();   // drains vmcnt (compiler emits full waitcnt)

    short8 a[NP][4];
#pragma unroll
    for (int p = 0; p < NP; ++p)
#pragma unroll
      for (int fm = 0; fm < 4; ++fm)
        a[p][fm] = *(const short8*)&Asl[p * 4096 + (wm + fm * 16 + lm) * 32 + lk];

#pragma unroll
    for (int fn = 0; fn < 4; ++fn) {
      short8 bf[NP];
#pragma unroll
      for (int p = 0; p < NP; ++p)
        bf[p] = *(const short8*)&Wsl[p * 4096 + (wn + fn * 16 + lm) * 32 + lk];
#pragma unroll
      for (int fm = 0; fm < 4; ++fm) {
#pragma unroll
        for (int t = 0; t < NT; ++t)
          acc[fm][fn] = __builtin_amdgcn_mfma_f32_16x16x32_bf16(
              a[ta[t]][fm], bf[tw[t]], acc[fm][fn], 0, 0, 0);
      }
    }
    __syncthreads();
  }

  const int rq = (lane >> 4) * 4;
  float* Cz = C + (size_t)z * 8388608u;
#pragma unroll
  for (int fm = 0; fm < 4; ++fm)
#pragma unroll
    for (int fn = 0; fn < 4; ++fn) {
      int row = m0 + wm + fm * 16 + rq;
      int col = n0 + wn + fn * 16 + lm;
#pragma unroll
      for (int r = 0; r < 4; ++r)
        Cz[(size_t)(row + r) * 512 + col] = acc[fm][fn][r];
    }
}

// ---------------------------------------------------------------------------
// Fallback fp32 GEMM (only if ws too small for planes).
// ---------------------------------------------------------------------------
__global__ __launch_bounds__(256) void gemm512(
    const float* __restrict__ A,
    const float* __restrict__ W0, const float* __restrict__ W1, const float* __restrict__ W2,
    float* __restrict__ C0, float* __restrict__ C1, float* __restrict__ C2)
{
  const int z = blockIdx.z;
  const float* Wm = (z == 0) ? W0 : (z == 1 ? W1 : W2);
  float* Cm = (z == 0) ? C0 : (z == 1 ? C1 : C2);
  const int n0 = blockIdx.x * 128;
  const int m0 = blockIdx.y * 128;
  const int tid = threadIdx.x;
  const int tx = tid & 15, ty = tid >> 4;

  __shared__ float As[32][132];
  __shared__ float Bs[32][132];

  float acc[8][8];
#pragma unroll
  for (int i = 0; i < 8; ++i)
#pragma unroll
    for (int j = 0; j < 8; ++j) acc[i][j] = 0.f;

  for (int k0 = 0; k0 < 512; k0 += 32) {
    {
      const int c4 = tid & 7, r = tid >> 3;
#pragma unroll
      for (int p = 0; p < 128; p += 32) {
        float4 av = *(const float4*)&A[(size_t)(m0 + r + p) * 512 + k0 + c4 * 4];
        As[c4 * 4 + 0][r + p] = av.x;
        As[c4 * 4 + 1][r + p] = av.y;
        As[c4 * 4 + 2][r + p] = av.z;
        As[c4 * 4 + 3][r + p] = av.w;
      }
      const int j4 = tid & 31, rb = tid >> 5;
#pragma unroll
      for (int p = 0; p < 32; p += 8) {
        *(float4*)&Bs[rb + p][j4 * 4] =
            *(const float4*)&Wm[(size_t)(k0 + rb + p) * 512 + n0 + j4 * 4];
      }
    }
    __syncthreads();
#pragma unroll
    for (int kk = 0; kk < 32; ++kk) {
      float4 a0 = *(const float4*)&As[kk][ty * 8];
      float4 a1 = *(const float4*)&As[kk][ty * 8 + 4];
      float4 b0 = *(const float4*)&Bs[kk][tx * 8];
      float4 b1 = *(const float4*)&Bs[kk][tx * 8 + 4];
      float av[8] = {a0.x, a0.y, a0.z, a0.w, a1.x, a1.y, a1.z, a1.w};
      float bv[8] = {b0.x, b0.y, b0.z, b0.w, b1.x, b1.y, b1.z, b1.w};
#pragma unroll
      for (int i = 0; i < 8; ++i)
#pragma unroll
        for (int j = 0; j < 8; ++j) acc[i][j] += av[i] * bv[j];
    }
    __syncthreads();
  }
#pragma unroll
  for (int i = 0; i < 8; ++i) {
    size_t row = (size_t)(m0 + ty * 8 + i);
    float4 o0 = make_float4(acc[i][0], acc[i][1], acc[i][2], acc[i][3]);
    float4 o1 = make_float4(acc[i][4], acc[i][5], acc[i][6], acc[i][7]);
    *(float4*)&Cm[row * 512 + n0 + tx * 8] = o0;
    *(float4*)&Cm[row * 512 + n0 + tx * 8 + 4] = o1;
  }
}

// ---------------------------------------------------------------------------
// focus/keep computation (shared).
// ---------------------------------------------------------------------------
__device__ __forceinline__ void focus_keep(
    const unsigned char* klab, const float* kscr, int* hist8, float* s_var,
    int* s_sk, int* s_ck, int tid, int lane, int wv)
{
  if (tid < GSZ) atomicAdd(&hist8[klab[tid]], 1);
  if (wv == 0) {
    double x0 = (double)kscr[lane], x1 = (double)kscr[lane + 64];
    double s = x0 + x1;
#pragma unroll
    for (int off = 32; off > 0; off >>= 1) s += __shfl_xor(s, off);
    double mean = s * (1.0 / 128.0);
    double d0 = x0 - mean, d1 = x1 - mean;
    double vs = d0 * d0 + d1 * d1;
#pragma unroll
    for (int off = 32; off > 0; off >>= 1) vs += __shfl_xor(vs, off);
    if (lane == 0) *s_var = (float)(vs * (1.0 / 128.0));
  }
  __syncthreads();
  if (tid == 0) {
    int bc = hist8[0];
    for (int l = 1; l < 8; ++l)
      if (hist8[l] > bc) bc = hist8[l];
    float purity = (float)bc * (1.0f / GSZ);
    float focus = 0.5f + 0.25f * purity - 0.25f * (*s_var);
    focus = fminf(fmaxf(focus, 0.25f), 0.75f);
    int keep = (int)ceilf(focus * (float)WSZ);
    keep = min(max(keep, 1), WSZ);
    int ck = keep >> 3, rem = keep & 7;          // round-half-even(keep/8)
    if (rem > 4 || (rem == 4 && (ck & 1))) ck++;
    if (ck < 1) ck = 1;
    int sk = keep - ck;
    if (sk < 1) sk = 1;
    *s_sk = sk;
    *s_ck = ck;
  }
  __syncthreads();
}

// ---------------------------------------------------------------------------
// attn v9 (verbatim R0 kernel — verified 399us, absmax 0.0039): QK fp32 VALU
// -> rank (threshold search) -> PV via 3-term split-bf16 MFMA with V^T tile
// staged in LDS. All restructure attempts (R1-R6) lost to restaging/spills;
// this is the known-good operating point.
// ---------------------------------------------------------------------------
__global__ __launch_bounds__(256, 3) void attn_v9(
    const float* __restrict__ q, const float* __restrict__ k,
    const float* __restrict__ vf,
    const int* __restrict__ labels, const float* __restrict__ scores,
    float* __restrict__ attn_out, unsigned short* __restrict__ opl)
{
  const int bx = blockIdx.x;
  const int c = bx >> 10;
  const int rblk = bx & 1023;
  const int h = rblk & 7;
  const int g = (rblk >> 3) & 31;
  const int b = rblk >> 8;
  const int r0 = c * CHUNK;
  const int tid = threadIdx.x;
  const int lane = tid & 63, wv = tid >> 6;
  const int lm = lane & 15, lq = lane >> 4;

  // att row = 264 fp32 (1056 B): fp32 logits, later hosts phi[0..263] (528B)
  // + pmid[0..263] (528B) overlays in the SAME row (wave-private, race-free).
  __shared__ float att[CHUNK][264];
  __shared__ __align__(16) unsigned char vbuf[18432];  // ktile f32[64][68] / vtT u16[2][64][72]
  float (*ktile)[68] = (float (*)[68])vbuf;
  unsigned short* vtT = (unsigned short*)vbuf;         // plane stride 4608 shorts
  __shared__ unsigned char klab[WSZ];
  __shared__ float kscr[WSZ];
  __shared__ int hist8[8];
  __shared__ float s_var;
  __shared__ int s_sk, s_ck;

  {
    int j = tid;
    int pos = g * GSZ + j;
    int tok = pos < NN ? pos : (2 * NN - 1 - pos);
    klab[j] = (unsigned char)labels[b * NN + tok];
    kscr[j] = scores[b * NN + tok];
  }
  if (tid < 8) hist8[tid] = 0;
  __syncthreads();
  focus_keep(klab, kscr, hist8, &s_var, &s_sk, &s_ck, tid, lane, wv);
  const int same_keep = s_sk, cross_keep = s_ck;

  const int rp = tid >> 4, jx = tid & 15;
  const int srow = tid >> 4, sd4 = (tid & 15) * 4;
  const float* q0p = q + (size_t)(b * NN + g * GSZ + r0 + rp) * DIMM + h * DH;
  const float* q1p = q0p + (size_t)16 * DIMM;

  // ---- QK^T: fp32 VALU, arithmetic identical to R8 (selection-critical) ----
  for (int jt = 0; jt < 4; ++jt) {
#pragma unroll
    for (int p = 0; p < 64; p += 16) {
      int j = jt * 64 + srow + p;
      int pos = g * GSZ + j;
      int tok = pos < NN ? pos : (2 * NN - 1 - pos);
      *(float4*)&ktile[srow + p][sd4] =
          *(const float4*)&k[(size_t)(b * NN + tok) * DIMM + h * DH + sd4];
    }
    __syncthreads();
    float acc0[4] = {0.f, 0.f, 0.f, 0.f}, acc1[4] = {0.f, 0.f, 0.f, 0.f};
#pragma unroll
    for (int dd = 0; dd < DH; dd += 4) {
      float4 q0 = *(const float4*)(q0p + dd);
      float4 q1 = *(const float4*)(q1p + dd);
#pragma unroll
      for (int jj = 0; jj < 4; ++jj) {
        float4 kv = *(const float4*)&ktile[jx + 16 * jj][dd];
        acc0[jj] += q0.x * kv.x + q0.y * kv.y + q0.z * kv.z + q0.w * kv.w;
        acc1[jj] += q1.x * kv.x + q1.y * kv.y + q1.z * kv.z + q1.w * kv.w;
      }
    }
#pragma unroll
    for (int jj = 0; jj < 4; ++jj) {
      att[rp][jt * 64 + jx + 16 * jj] = acc0[jj] * 0.125f;
      att[rp + 16][jt * 64 + jx + 16 * jj] = acc1[jj] * 0.125f;
    }
    __syncthreads();
  }

  // ---- rank: identical compute; stores p as in-row bf16 hi/mid overlays ----
  {
    int kl0[4];
    float ks0[4];
#pragma unroll
    for (int m = 0; m < 4; ++m) {
      kl0[m] = klab[lane + 64 * m];
      ks0[m] = kscr[lane + 64 * m];
    }
    for (int sp = 0; sp < 4; ++sp) {
      const int rA = wv * 8 + 2 * sp, rB = rA + 1;
      const int qLA = klab[r0 + rA], qLB = klab[r0 + rB];
      const float qSA = kscr[r0 + rA], qSB = kscr[r0 + rB];
      float aA[4], aB[4];
      float mxA = -INFINITY, mxB = -INFINITY;
#pragma unroll
      for (int m = 0; m < 4; ++m) {
        aA[m] = att[rA][lane + 64 * m];
        aB[m] = att[rB][lane + 64 * m];
        mxA = fmaxf(mxA, aA[m]);
        mxB = fmaxf(mxB, aB[m]);
      }
#pragma unroll
      for (int off = 32; off > 0; off >>= 1) {
        mxA = fmaxf(mxA, __shfl_xor(mxA, off));
        mxB = fmaxf(mxB, __shfl_xor(mxB, off));
      }
      unsigned fsA[4], fcA[4], fsB[4], fcB[4];
      bool cdA[4], cdB[4];
#pragma unroll
      for (int m = 0; m < 4; ++m) {
        aA[m] = expf(aA[m] - mxA);
        aB[m] = expf(aB[m] - mxB);
        cdA[m] = (kl0[m] == qLA);
        cdB[m] = (kl0[m] == qLB);
        fsA[m] = cdA[m] ? __float_as_uint(aA[m]) : 0u;
        fsB[m] = cdB[m] ? __float_as_uint(aB[m]) : 0u;
        fcA[m] = __float_as_uint(aA[m] * (qSA * ks0[m]));
        fcB[m] = __float_as_uint(aB[m] * (qSB * ks0[m]));
      }
      unsigned tsA = 0, tcA = 0, tsB = 0, tcB = 0;
      for (int bit = 29; bit >= 0; --bit) {
        unsigned csA = tsA | (1u << bit), ccA = tcA | (1u << bit);
        unsigned csB = tsB | (1u << bit), ccB = tcB | (1u << bit);
        int nsA = 0, ncA = 0, nsB = 0, ncB = 0;
#pragma unroll
        for (int m = 0; m < 4; ++m) {
          nsA += __popcll(__ballot(fsA[m] >= csA));
          ncA += __popcll(__ballot(fcA[m] >= ccA));
          nsB += __popcll(__ballot(fsB[m] >= csB));
          ncB += __popcll(__ballot(fcB[m] >= ccB));
        }
        if (nsA >= same_keep) tsA = csA;
        if (ncA >= cross_keep) tcA = ccA;
        if (nsB >= same_keep) tsB = csB;
        if (ncB >= cross_keep) tcB = ccB;
      }
#pragma unroll
      for (int rsel = 0; rsel < 2; ++rsel) {
        const int rr = rsel ? rB : rA;
        const unsigned ts = rsel ? tsB : tsA, tc = rsel ? tcB : tcA;
        unsigned* fs = rsel ? fsB : fsA;
        unsigned* fc = rsel ? fcB : fcA;
        float* a = rsel ? aB : aA;
        bool* cand = rsel ? cdB : cdA;
        unsigned long long beqs[4], beqc[4];
        int gts = 0, gtc = 0;
#pragma unroll
        for (int m = 0; m < 4; ++m) {
          gts += __popcll(__ballot(fs[m] > ts));
          gtc += __popcll(__ballot(fc[m] > tc));
          beqs[m] = __ballot(fs[m] == ts);
          beqc[m] = __ballot(fc[m] == tc);
        }
        const int rs = same_keep - gts, rc = cross_keep - gtc;
        float pv[4];
        float S = 0.f;
        int pres = 0, prec = 0;
#pragma unroll
        for (int m = 0; m < 4; ++m) {
          int mbs = __builtin_amdgcn_mbcnt_hi((unsigned)(beqs[m] >> 32),
                     __builtin_amdgcn_mbcnt_lo((unsigned)beqs[m], 0));
          int mbc = __builtin_amdgcn_mbcnt_hi((unsigned)(beqc[m] >> 32),
                     __builtin_amdgcn_mbcnt_lo((unsigned)beqc[m], 0));
          bool keep_s = cand[m] && ((fs[m] > ts) || ((fs[m] == ts) && (pres + mbs < rs)));
          bool keep_c = (!cand[m]) && ((fc[m] > tc) || ((fc[m] == tc) && (prec + mbc < rc)));
          pv[m] = (keep_s || keep_c) ? a[m] : 0.f;
          S += pv[m];
          pres += __popcll(beqs[m]);
          prec += __popcll(beqc[m]);
        }
#pragma unroll
        for (int off = 32; off > 0; off >>= 1) S += __shfl_xor(S, off);
        const float inv = 1.0f / S;
        size_t gb = ((((size_t)b * NGRP + g) * HH + h) * GSZ + (r0 + rr)) * WSZ + lane;
        unsigned short* prow = (unsigned short*)&att[rr][0];
#pragma unroll
        for (int m = 0; m < 4; ++m) {
          float p = pv[m] * inv;
          attn_out[gb + 64 * m] = p;
          unsigned short hh = bf16rne(p);
          prow[lane + 64 * m] = hh;                          // phi
          prow[264 + lane + 64 * m] = bf16rne(p - bf16tof(hh)); // pmid
        }
      }
    }
  }

  // ---- PV via MFMA: D(32x64) = P(32x256) @ V(256x64), 3-term split ----
  f32x4 acc2[2] = {(f32x4){0.f, 0.f, 0.f, 0.f}, (f32x4){0.f, 0.f, 0.f, 0.f}};
  for (int jt = 0; jt < 4; ++jt) {
    __syncthreads();   // overlays done (jt=0) / prior MFMA reads done (jt>0)
    // stage V^T tile: vtT[pl][d][j], 64 j of this jt; pair-packed b32 writes
    {
      const int dx_ = tid & 15, jh = tid >> 4;      // jh 0..15
#pragma unroll
      for (int ps = 0; ps < 2; ++ps) {
        int jl0 = ps * 32 + 2 * jh;
        float4 v0, v1;
#pragma unroll
        for (int qq = 0; qq < 2; ++qq) {
          int pos = g * GSZ + jt * 64 + jl0 + qq;
          int tok = pos < NN ? pos : (2 * NN - 1 - pos);
          float4 vv = *(const float4*)&vf[(size_t)(b * NN + tok) * DIMM + h * DH + dx_ * 4];
          if (qq == 0) v0 = vv; else v1 = vv;
        }
        const float* a0 = (const float*)&v0;
        const float* a1 = (const float*)&v1;
#pragma unroll
        for (int i = 0; i < 4; ++i) {
          int d = dx_ * 4 + i;
          unsigned short h0 = bf16rne(a0[i]);
          unsigned short h1 = bf16rne(a1[i]);
          unsigned short m0 = bf16rne(a0[i] - bf16tof(h0));
          unsigned short m1 = bf16rne(a1[i] - bf16tof(h1));
          *(unsigned*)&vtT[0 * 4608 + d * 72 + jl0] = (unsigned)h0 | ((unsigned)h1 << 16);
          *(unsigned*)&vtT[1 * 4608 + d * 72 + jl0] = (unsigned)m0 | ((unsigned)m1 << 16);
        }
      }
    }
    __syncthreads();
#pragma unroll
    for (int kt = 0; kt < 2; ++kt) {
      const int koff = jt * 64 + kt * 32 + lq * 8;
      short8 ahi[2], ami[2];
#pragma unroll
      for (int mt = 0; mt < 2; ++mt) {
        const unsigned short* arow = (const unsigned short*)&att[mt * 16 + lm][0];
        ahi[mt] = *(const short8*)&arow[koff];
        ami[mt] = *(const short8*)&arow[264 + koff];
      }
      const int vo = (wv * 16 + lm) * 72 + kt * 32 + lq * 8;
      short8 bhi = *(const short8*)&vtT[vo];
      short8 bmi = *(const short8*)&vtT[4608 + vo];
#pragma unroll
      for (int mt = 0; mt < 2; ++mt) {
        acc2[mt] = __builtin_amdgcn_mfma_f32_16x16x32_bf16(ahi[mt], bhi, acc2[mt], 0, 0, 0);
        acc2[mt] = __builtin_amdgcn_mfma_f32_16x16x32_bf16(ahi[mt], bmi, acc2[mt], 0, 0, 0);
        acc2[mt] = __builtin_amdgcn_mfma_f32_16x16x32_bf16(ami[mt], bhi, acc2[mt], 0, 0, 0);
      }
    }
  }

  // ---- o epilogue: C/D col=lane&15 (d), row=lq*4+r (+mt*16); 2 bf16 planes --
  {
    size_t rowbase = (size_t)(b * NN + g * GSZ + r0);
#pragma unroll
    for (int mt = 0; mt < 2; ++mt)
#pragma unroll
      for (int r = 0; r < 4; ++r) {
        int row = mt * 16 + lq * 4 + r;
        float val = acc2[mt][r];
        unsigned short hh = bf16rne(val);
        size_t oaddr = (rowbase + row) * 512 + h * 64 + wv * 16 + lm;
        opl[oaddr] = hh;
        opl[MK + oaddr] = bf16rne(val - bf16tof(hh));
      }
  }
}

// ---------------------------------------------------------------------------
// Fallback attn (fp32 q/k/v in, fp32 o out aliasing q) — small-ws path only.
// ---------------------------------------------------------------------------
__global__ __launch_bounds__(256, 3) void attn_f32(
    const float* q, const float* __restrict__ k, const float* __restrict__ v,
    const int* __restrict__ labels, const float* __restrict__ scores,
    float* __restrict__ attn_out, float* o)
{
  const int bx = blockIdx.x;
  const int c = bx >> 10;
  const int rblk = bx & 1023;
  const int h = rblk & 7;
  const int g = (rblk >> 3) & 31;
  const int b = rblk >> 8;
  const int r0 = c * CHUNK;
  const int tid = threadIdx.x;
  const int lane = tid & 63, wv = tid >> 6;

  __shared__ float att[CHUNK][WSZ + 4];
  __shared__ float ktile[64][DH + 4];
  __shared__ unsigned char klab[WSZ];
  __shared__ float kscr[WSZ];
  __shared__ int hist8[8];
  __shared__ float s_var;
  __shared__ int s_sk, s_ck;

  {
    int j = tid;
    int pos = g * GSZ + j;
    int tok = pos < NN ? pos : (2 * NN - 1 - pos);
    klab[j] = (unsigned char)labels[b * NN + tok];
    kscr[j] = scores[b * NN + tok];
  }
  if (tid < 8) hist8[tid] = 0;
  __syncthreads();
  focus_keep(klab, kscr, hist8, &s_var, &s_sk, &s_ck, tid, lane, wv);
  const int same_keep = s_sk, cross_keep = s_ck;

  const int rp = tid >> 4, jx = tid & 15;
  const int srow = tid >> 4, sd4 = (tid & 15) * 4;
  const float* q0p = q + (size_t)(b * NN + g * GSZ + r0 + rp) * DIMM + h * DH;
  const float* q1p = q0p + (size_t)16 * DIMM;

  for (int jt = 0; jt < 4; ++jt) {
#pragma unroll
    for (int p = 0; p < 64; p += 16) {
      int j = jt * 64 + srow + p;
      int pos = g * GSZ + j;
      int tok = pos < NN ? pos : (2 * NN - 1 - pos);
      *(float4*)&ktile[srow + p][sd4] =
          *(const float4*)&k[(size_t)(b * NN + tok) * DIMM + h * DH + sd4];
    }
    __syncthreads();
    float acc0[4] = {0.f, 0.f, 0.f, 0.f}, acc1[4] = {0.f, 0.f, 0.f, 0.f};
#pragma unroll
    for (int dd = 0; dd < DH; dd += 4) {
      float4 q0 = *(const float4*)(q0p + dd);
      float4 q1 = *(const float4*)(q1p + dd);
#pragma unroll
      for (int jj = 0; jj < 4; ++jj) {
        float4 kv = *(const float4*)&ktile[jx + 16 * jj][dd];
        acc0[jj] += q0.x * kv.x + q0.y * kv.y + q0.z * kv.z + q0.w * kv.w;
        acc1[jj] += q1.x * kv.x + q1.y * kv.y + q1.z * kv.z + q1.w * kv.w;
      }
    }
#pragma unroll
    for (int jj = 0; jj < 4; ++jj) {
      att[rp][jt * 64 + jx + 16 * jj] = acc0[jj] * 0.125f;
      att[rp + 16][jt * 64 + jx + 16 * jj] = acc1[jj] * 0.125f;
    }
    __syncthreads();
  }

  {
    int kl0[4];
    float ks0[4];
#pragma unroll
    for (int m = 0; m < 4; ++m) {
      kl0[m] = klab[lane + 64 * m];
      ks0[m] = kscr[lane + 64 * m];
    }
    for (int sp = 0; sp < 4; ++sp) {
      const int rA = wv * 8 + 2 * sp, rB = rA + 1;
      const int qLA = klab[r0 + rA], qLB = klab[r0 + rB];
      const float qSA = kscr[r0 + rA], qSB = kscr[r0 + rB];
      float aA[4], aB[4];
      float mxA = -INFINITY, mxB = -INFINITY;
#pragma unroll
      for (int m = 0; m < 4; ++m) {
        aA[m] = att[rA][lane + 64 * m];
        aB[m] = att[rB][lane + 64 * m];
        mxA = fmaxf(mxA, aA[m]);
        mxB = fmaxf(mxB, aB[m]);
      }
#pragma unroll
      for (int off = 32; off > 0; off >>= 1) {
        mxA = fmaxf(mxA, __shfl_xor(mxA, off));
        mxB = fmaxf(mxB, __shfl_xor(mxB, off));
      }
      unsigned fsA[4], fcA[4], fsB[4], fcB[4];
      bool cdA[4], cdB[4];
#pragma unroll
      for (int m = 0; m < 4; ++m) {
        aA[m] = expf(aA[m] - mxA);
        aB[m] = expf(aB[m] - mxB);
        cdA[m] = (kl0[m] == qLA);
        cdB[m] = (kl0[m] == qLB);
        fsA[m] = cdA[m] ? __float_as_uint(aA[m]) : 0u;
        fsB[m] = cdB[m] ? __float_as_uint(aB[m]) : 0u;
        fcA[m] = __float_as_uint(aA[m] * (qSA * ks0[m]));
        fcB[m] = __float_as_uint(aB[m] * (qSB * ks0[m]));
      }
      unsigned tsA = 0, tcA = 0, tsB = 0, tcB = 0;
      for (int bit = 29; bit >= 0; --bit) {
        unsigned csA = tsA | (1u << bit), ccA = tcA | (1u << bit);
        unsigned csB = tsB | (1u << bit), ccB = tcB | (1u << bit);
        int nsA = 0, ncA = 0, nsB = 0, ncB = 0;
#pragma unroll
        for (int m = 0; m < 4; ++m) {
          nsA += __popcll(__ballot(fsA[m] >= csA));
          ncA += __popcll(__ballot(fcA[m] >= ccA));
          nsB += __popcll(__ballot(fsB[m] >= csB));
          ncB += __popcll(__ballot(fcB[m] >= ccB));
        }
        if (nsA >= same_keep) tsA = csA;
        if (ncA >= cross_keep) tcA = ccA;
        if (nsB >= same_keep) tsB = csB;
        if (ncB >= cross_keep) tcB = ccB;
      }
#pragma unroll
      for (int rsel = 0; rsel < 2; ++rsel) {
        const int rr = rsel ? rB : rA;
        const unsigned ts = rsel ? tsB : tsA, tc = rsel ? tcB : tcA;
        unsigned* fs = rsel ? fsB : fsA;
        unsigned* fc = rsel ? fcB : fcA;
        float* a = rsel ? aB : aA;
        bool* cand = rsel ? cdB : cdA;
        unsigned long long beqs[4], beqc[4];
        int gts = 0, gtc = 0;
#pragma unroll
        for (int m = 0; m < 4; ++m) {
          gts += __popcll(__ballot(fs[m] > ts));
          gtc += __popcll(__ballot(fc[m] > tc));
          beqs[m] = __ballot(fs[m] == ts);
          beqc[m] = __ballot(fc[m] == tc);
        }
        const int rs = same_keep - gts, rc = cross_keep - gtc;
        float pv[4];
        float S = 0.f;
        int pres = 0, prec = 0;
#pragma unroll
        for (int m = 0; m < 4; ++m) {
          int mbs = __builtin_amdgcn_mbcnt_hi((unsigned)(beqs[m] >> 32),
                     __builtin_amdgcn_mbcnt_lo((unsigned)beqs[m], 0));
          int mbc = __builtin_amdgcn_mbcnt_hi((unsigned)(beqc[m] >> 32),
                     __builtin_amdgcn_mbcnt_lo((unsigned)beqc[m], 0));
          bool keep_s = cand[m] && ((fs[m] > ts) || ((fs[m] == ts) && (pres + mbs < rs)));
          bool keep_c = (!cand[m]) && ((fc[m] > tc) || ((fc[m] == tc) && (prec + mbc < rc)));
          pv[m] = (keep_s || keep_c) ? a[m] : 0.f;
          S += pv[m];
          pres += __popcll(beqs[m]);
          prec += __popcll(beqc[m]);
        }
#pragma unroll
        for (int off = 32; off > 0; off >>= 1) S += __shfl_xor(S, off);
        const float inv = 1.0f / S;
        size_t gb = ((((size_t)b * NGRP + g) * HH + h) * GSZ + (r0 + rr)) * WSZ + lane;
#pragma unroll
        for (int m = 0; m < 4; ++m) {
          float p = pv[m] * inv;
          att[rr][lane + 64 * m] = p;
          attn_out[gb + 64 * m] = p;
        }
      }
    }
  }
  __syncthreads();

  const int dx = jx;
  float oa0[4] = {0.f, 0.f, 0.f, 0.f}, oa1[4] = {0.f, 0.f, 0.f, 0.f};
  for (int jt = 0; jt < 4; ++jt) {
#pragma unroll
    for (int p = 0; p < 64; p += 16) {
      int j = jt * 64 + srow + p;
      int pos = g * GSZ + j;
      int tok = pos < NN ? pos : (2 * NN - 1 - pos);
      *(float4*)&ktile[srow + p][sd4] =
          *(const float4*)&v[(size_t)(b * NN + tok) * DIMM + h * DH + sd4];
    }
    __syncthreads();
#pragma unroll 4
    for (int jg = 0; jg < 16; ++jg) {
      float4 p0 = *(const float4*)&att[rp][jt * 64 + jg * 4];
      float4 p1 = *(const float4*)&att[rp + 16][jt * 64 + jg * 4];
      float4 v0 = *(const float4*)&ktile[jg * 4 + 0][dx * 4];
      float4 v1 = *(const float4*)&ktile[jg * 4 + 1][dx * 4];
      float4 v2 = *(const float4*)&ktile[jg * 4 + 2][dx * 4];
      float4 v3 = *(const float4*)&ktile[jg * 4 + 3][dx * 4];
      oa0[0] += p0.x * v0.x + p0.y * v1.x + p0.z * v2.x + p0.w * v3.x;
      oa0[1] += p0.x * v0.y + p0.y * v1.y + p0.z * v2.y + p0.w * v3.y;
      oa0[2] += p0.x * v0.z + p0.y * v1.z + p0.z * v2.z + p0.w * v3.z;
      oa0[3] += p0.x * v0.w + p0.y * v1.w + p0.z * v2.w + p0.w * v3.w;
      oa1[0] += p1.x * v0.x + p1.y * v1.x + p1.z * v2.x + p1.w * v3.x;
      oa1[1] += p1.x * v0.y + p1.y * v1.y + p1.z * v2.y + p1.w * v3.y;
      oa1[2] += p1.x * v0.z + p1.y * v1.z + p1.z * v2.z + p1.w * v3.z;
      oa1[3] += p1.x * v0.w + p1.y * v1.w + p1.z * v2.w + p1.w * v3.w;
    }
    __syncthreads();
  }
  {
    size_t ob0 = (size_t)(b * NN + g * GSZ + r0 + rp) * DIMM + h * DH + dx * 4;
    *(float4*)&o[ob0] = make_float4(oa0[0], oa0[1], oa0[2], oa0[3]);
    *(float4*)&o[ob0 + (size_t)16 * DIMM] = make_float4(oa1[0], oa1[1], oa1[2], oa1[3]);
  }
}

// ---------------------------------------------------------------------------
extern "C" void kernel_launch(void* const* d_in, const int* in_sizes, int n_in,
                              void* d_out, int out_size, void* d_ws, size_t ws_size,
                              hipStream_t stream) {
  const float* x      = (const float*)d_in[0];
  const int*   labels = (const int*)d_in[1];
  const float* scores = (const float*)d_in[2];
  const float* Wq     = (const float*)d_in[3];
  const float* Wk     = (const float*)d_in[4];
  const float* Wv     = (const float*)d_in[5];
  const float* Wproj  = (const float*)d_in[6];

  float* out = (float*)d_out;                               // (B, N, DIM)
  float* attn_out = out + (size_t)BB * NN * DIMM;           // (B, ng, H, gs, ws)

  // layout: qb|kb|vf (fp32) | xpl (3 planes; reused as opl) | weights
  float* qb = (float*)d_ws;
  float* kb = qb + (size_t)MK;
  float* vf = kb + (size_t)MK;
  unsigned short* xpl  = (unsigned short*)(vf + (size_t)MK);
  unsigned short* wqkv = xpl + 3 * (size_t)MK;
  unsigned short* wpp  = wqkv + 9 * (size_t)WK;
  const size_t required = 3 * (size_t)MK * 4 + 3 * (size_t)MK * 2 + 11 * (size_t)WK * 2;

  if (ws_size >= required) {
    split_planes<<<dim3(MK / 1024), 256, 0, stream>>>(x, xpl);
    split_w<<<dim3(4 * WK / 256), 256, 0, stream>>>(Wq, Wk, Wv, Wproj, wqkv, wpp);
    // q,k fp32 via 6-term (bit-identical to R5/R8 selection inputs); v 3-term
    mfma_gemm<3, 6><<<dim3(4, 128, 2), 256, 0, stream>>>(xpl, wqkv, qb);
    mfma_gemm<2, 3><<<dim3(4, 128, 1), 256, 0, stream>>>(xpl, wqkv + 6 * (size_t)WK, vf);
    attn_v9<<<dim3(BB * NGRP * HH * 4), 256, 0, stream>>>(
        qb, kb, vf, labels, scores, attn_out, xpl);
    mfma_gemm<2, 3><<<dim3(4, 128, 1), 256, 0, stream>>>(xpl, wpp, out);
  } else {
    const size_t SZ = (size_t)BB * NN * DIMM;
    float* q2 = (float*)d_ws;
    float* k2 = q2 + SZ;
    float* v2 = k2 + SZ;
    gemm512<<<dim3(4, 128, 3), 256, 0, stream>>>(x, Wq, Wk, Wv, q2, k2, v2);
    attn_f32<<<dim3(BB * NGRP * HH * 4), 256, 0, stream>>>(
        q2, k2, v2, labels, scores, attn_out, q2);
    gemm512<<<dim3(4, 128, 1), 256, 0, stream>>>(q2, Wproj, Wproj, Wproj, out, out, out);
  }
}

// Round 8
// 702.192 us; speedup vs baseline: 4.2805x; 1.0387x over previous
//
#include <hip/hip_runtime.h>

#define BB 4
#define NN 4096
#define DIMM 512
#define HH 8
#define DH 64
#define GSZ 128
#define NGRP 32
#define WSZ 256
#define CHUNK 32

#define MK 8388608u     // 16384*512 elements (x / q / k / v / o planes)
#define WK 262144u      // 512*512

typedef short short8 __attribute__((ext_vector_type(8)));
typedef float f32x4 __attribute__((ext_vector_type(4)));

__device__ inline unsigned short bf16rne(float f) {
  unsigned u = __float_as_uint(f);
  unsigned r = u + 0x7FFFu + ((u >> 16) & 1u);
  return (unsigned short)(r >> 16);
}
__device__ inline float bf16tof(unsigned short h) {
  return __uint_as_float(((unsigned)h) << 16);
}

// async global->LDS, 16B per lane; dest = wave-uniform base + lane*16.
__device__ __forceinline__ void gload_lds16(const void* g, void* l) {
  __builtin_amdgcn_global_load_lds(
      (const __attribute__((address_space(1))) void*)g,
      (__attribute__((address_space(3))) void*)l, 16, 0, 0);
}

// ---------------------------------------------------------------------------
// split_planes: fp32 -> 3 bf16 planes (hi, mid, lo); exact residual split
// ---------------------------------------------------------------------------
__global__ __launch_bounds__(256) void split_planes(
    const float* __restrict__ X, unsigned short* __restrict__ P)
{
  unsigned idx = (blockIdx.x * 256u + threadIdx.x) * 4u;
  float4 xv = *(const float4*)&X[idx];
  float xs[4] = {xv.x, xv.y, xv.z, xv.w};
  ushort4 hv, mv, lv;
  unsigned short* hp = (unsigned short*)&hv;
  unsigned short* mp = (unsigned short*)&mv;
  unsigned short* lp = (unsigned short*)&lv;
#pragma unroll
  for (int i = 0; i < 4; ++i) {
    unsigned short h = bf16rne(xs[i]);
    float r1 = xs[i] - bf16tof(h);
    unsigned short m = bf16rne(r1);
    float r2 = r1 - bf16tof(m);
    hp[i] = h;
    mp[i] = m;
    lp[i] = bf16rne(r2);
  }
  *(ushort4*)&P[idx] = hv;
  *(ushort4*)&P[MK + idx] = mv;
  *(ushort4*)&P[2u * MK + idx] = lv;
}

// ---------------------------------------------------------------------------
// split_w: weights -> transposed (N x K) bf16 planes.
// ---------------------------------------------------------------------------
__global__ __launch_bounds__(256) void split_w(
    const float* __restrict__ Wq, const float* __restrict__ Wk,
    const float* __restrict__ Wv, const float* __restrict__ Wpj,
    unsigned short* __restrict__ wqkv, unsigned short* __restrict__ wproj)
{
  unsigned e = blockIdx.x * 256u + threadIdx.x;     // over 4 * 2^18
  int mz = e >> 18;
  unsigned rem = e & (WK - 1u);
  unsigned kk = rem >> 9, n = rem & 511u;
  const float* src = (mz == 0) ? Wq : (mz == 1) ? Wk : (mz == 2) ? Wv : Wpj;
  float w = src[kk * 512u + n];
  unsigned short h = bf16rne(w);
  float r1 = w - bf16tof(h);
  unsigned short m = bf16rne(r1);
  float r2 = r1 - bf16tof(m);
  unsigned short l = bf16rne(r2);
  unsigned o = n * 512u + kk;
  if (mz < 3) {
    unsigned short* base = wqkv + (unsigned)mz * 3u * WK;
    base[o] = h;
    base[WK + o] = m;
    base[2u * WK + o] = l;
  } else {
    wproj[o] = h;
    wproj[WK + o] = m;
  }
}

// ---------------------------------------------------------------------------
// gemm_body: one 128x128 tile of C = A(16384x512) @ W(512x512), split-bf16
// MFMA, global_load_lds width=16 staging into linear LDS (v16 structure,
// verified bit-identical at R7). m0/n0 passed in (caller does the XCD-aware
// swizzle decode); LDS buffers passed in so multiple instantiations in one
// kernel share a single allocation.
// ---------------------------------------------------------------------------
template <int NP, int NT>
__device__ __forceinline__ void gemm_body(
    int m0, int n0,
    const unsigned short* __restrict__ Ap,   // NP planes, plane stride MK
    const unsigned short* __restrict__ Wz,   // NP planes, plane stride WK
    float* __restrict__ Cz,
    unsigned short* Asl, unsigned short* Wsl)
{
  constexpr int ta[6] = {0, 0, 1, 1, 0, 2};
  constexpr int tw[6] = {0, 1, 0, 1, 2, 0};
  const int tid = threadIdx.x;
  const int lane = tid & 63, wv = tid >> 6;
  const int wm = (wv >> 1) * 64, wn = (wv & 1) * 64;
  const int lm = lane & 15, lk = (lane >> 4) * 8;

  f32x4 acc[4][4];
#pragma unroll
  for (int i = 0; i < 4; ++i)
#pragma unroll
    for (int j = 0; j < 4; ++j) acc[i][j] = (f32x4){0.f, 0.f, 0.f, 0.f};

  const int lrow = lane >> 2;          // 0..15 within a 16-row chunk
  const int lcol8 = (lane & 3) * 8;    // short offset within row (0,8,16,24)

  for (int k0 = 0; k0 < 512; k0 += 32) {
#pragma unroll
    for (int i = 0; i < NP * 4; ++i) {
      int c = wv * (NP * 4) + i;
      bool isW = c >= NP * 8;
      int cc = isW ? c - NP * 8 : c;
      int p = cc >> 3, r0 = (cc & 7) * 16;
      const unsigned short* gsrc =
          (isW ? Wz + (size_t)p * WK + (size_t)(n0 + r0 + lrow) * 512
               : Ap + (size_t)p * MK + (size_t)(m0 + r0 + lrow) * 512)
          + k0 + lcol8;
      unsigned short* ldst = (isW ? &Wsl[p * 4096 + r0 * 32]
                                  : &Asl[p * 4096 + r0 * 32]);
      gload_lds16(gsrc, ldst);
    }
    __syncthreads();   // drains vmcnt (compiler emits full waitcnt)

    short8 a[NP][4];
#pragma unroll
    for (int p = 0; p < NP; ++p)
#pragma unroll
      for (int fm = 0; fm < 4; ++fm)
        a[p][fm] = *(const short8*)&Asl[p * 4096 + (wm + fm * 16 + lm) * 32 + lk];

#pragma unroll
    for (int fn = 0; fn < 4; ++fn) {
      short8 bf[NP];
#pragma unroll
      for (int p = 0; p < NP; ++p)
        bf[p] = *(const short8*)&Wsl[p * 4096 + (wn + fn * 16 + lm) * 32 + lk];
#pragma unroll
      for (int fm = 0; fm < 4; ++fm) {
#pragma unroll
        for (int t = 0; t < NT; ++t)
          acc[fm][fn] = __builtin_amdgcn_mfma_f32_16x16x32_bf16(
              a[ta[t]][fm], bf[tw[t]], acc[fm][fn], 0, 0, 0);
      }
    }
    __syncthreads();
  }

  const int rq = (lane >> 4) * 4;
#pragma unroll
  for (int fm = 0; fm < 4; ++fm)
#pragma unroll
    for (int fn = 0; fn < 4; ++fn) {
      int row = m0 + wm + fm * 16 + rq;
      int col = n0 + wn + fn * 16 + lm;
#pragma unroll
      for (int r = 0; r < 4; ++r)
        Cz[(size_t)(row + r) * 512 + col] = acc[fm][fn][r];
    }
}

// ---------------------------------------------------------------------------
// mfma_gemm_qkv: ONE launch for q,k (6-term, blocks 0..1023) + v (3-term,
// blocks 1024..1535). 1536 blocks = exactly 2 x (256 CU x 3 blocks/CU at
// 48KB LDS): two full occupancy rounds, no ragged tails (was 1024 + 512
// with 768-resident rounds). XCD-chunked swizzle: XCD k (= bid%8) owns
// 16 consecutive m-rows, so all 8 (z,n) sharers of an A-tile hit the same
// XCD L2 (A-tile = 384KB x 128 rows shared by 4n x 2z blocks). Work
// remap + launch merge only — per-tile arithmetic bit-identical.
// ---------------------------------------------------------------------------
__global__ __launch_bounds__(256) void mfma_gemm_qkv(
    const unsigned short* __restrict__ xpl,
    const unsigned short* __restrict__ wqkv,
    float* __restrict__ qkb,    // qb (z=0), kb (z=1) contiguous, stride MK
    float* __restrict__ vf)
{
  __shared__ unsigned short Asl[3 * 4096];
  __shared__ unsigned short Wsl[3 * 4096];
  const int bid = blockIdx.x;
  if (bid < 1024) {
    int swz = (bid & 7) * 128 + (bid >> 3);    // bijective on [0,1024)
    int m = swz >> 3, r = swz & 7;
    int z = r >> 2, n = r & 3;
    gemm_body<3, 6>(m * 128, n * 128, xpl, wqkv + (size_t)z * 3 * WK,
                    qkb + (size_t)z * MK, Asl, Wsl);
  } else {
    int bv = bid - 1024;                        // 1024%8==0: xcd id = bv%8
    int swz = (bv & 7) * 64 + (bv >> 3);        // bijective on [0,512)
    int m = swz >> 2, n = swz & 3;
    gemm_body<2, 3>(m * 128, n * 128, xpl, wqkv + 6 * (size_t)WK, vf, Asl, Wsl);
  }
}

// ---------------------------------------------------------------------------
// mfma_gemm_pj: proj GEMM (o planes @ wproj), 512 blocks, XCD swizzle.
// ---------------------------------------------------------------------------
__global__ __launch_bounds__(256) void mfma_gemm_pj(
    const unsigned short* __restrict__ opl,
    const unsigned short* __restrict__ wpp,
    float* __restrict__ out)
{
  __shared__ unsigned short Asl[2 * 4096];
  __shared__ unsigned short Wsl[2 * 4096];
  const int bid = blockIdx.x;
  int swz = (bid & 7) * 64 + (bid >> 3);        // bijective on [0,512)
  int m = swz >> 2, n = swz & 3;
  gemm_body<2, 3>(m * 128, n * 128, opl, wpp, out, Asl, Wsl);
}

// ---------------------------------------------------------------------------
// Fallback fp32 GEMM (only if ws too small for planes).
// ---------------------------------------------------------------------------
__global__ __launch_bounds__(256) void gemm512(
    const float* __restrict__ A,
    const float* __restrict__ W0, const float* __restrict__ W1, const float* __restrict__ W2,
    float* __restrict__ C0, float* __restrict__ C1, float* __restrict__ C2)
{
  const int z = blockIdx.z;
  const float* Wm = (z == 0) ? W0 : (z == 1 ? W1 : W2);
  float* Cm = (z == 0) ? C0 : (z == 1 ? C1 : C2);
  const int n0 = blockIdx.x * 128;
  const int m0 = blockIdx.y * 128;
  const int tid = threadIdx.x;
  const int tx = tid & 15, ty = tid >> 4;

  __shared__ float As[32][132];
  __shared__ float Bs[32][132];

  float acc[8][8];
#pragma unroll
  for (int i = 0; i < 8; ++i)
#pragma unroll
    for (int j = 0; j < 8; ++j) acc[i][j] = 0.f;

  for (int k0 = 0; k0 < 512; k0 += 32) {
    {
      const int c4 = tid & 7, r = tid >> 3;
#pragma unroll
      for (int p = 0; p < 128; p += 32) {
        float4 av = *(const float4*)&A[(size_t)(m0 + r + p) * 512 + k0 + c4 * 4];
        As[c4 * 4 + 0][r + p] = av.x;
        As[c4 * 4 + 1][r + p] = av.y;
        As[c4 * 4 + 2][r + p] = av.z;
        As[c4 * 4 + 3][r + p] = av.w;
      }
      const int j4 = tid & 31, rb = tid >> 5;
#pragma unroll
      for (int p = 0; p < 32; p += 8) {
        *(float4*)&Bs[rb + p][j4 * 4] =
            *(const float4*)&Wm[(size_t)(k0 + rb + p) * 512 + n0 + j4 * 4];
      }
    }
    __syncthreads();
#pragma unroll
    for (int kk = 0; kk < 32; ++kk) {
      float4 a0 = *(const float4*)&As[kk][ty * 8];
      float4 a1 = *(const float4*)&As[kk][ty * 8 + 4];
      float4 b0 = *(const float4*)&Bs[kk][tx * 8];
      float4 b1 = *(const float4*)&Bs[kk][tx * 8 + 4];
      float av[8] = {a0.x, a0.y, a0.z, a0.w, a1.x, a1.y, a1.z, a1.w};
      float bv[8] = {b0.x, b0.y, b0.z, b0.w, b1.x, b1.y, b1.z, b1.w};
#pragma unroll
      for (int i = 0; i < 8; ++i)
#pragma unroll
        for (int j = 0; j < 8; ++j) acc[i][j] += av[i] * bv[j];
    }
    __syncthreads();
  }
#pragma unroll
  for (int i = 0; i < 8; ++i) {
    size_t row = (size_t)(m0 + ty * 8 + i);
    float4 o0 = make_float4(acc[i][0], acc[i][1], acc[i][2], acc[i][3]);
    float4 o1 = make_float4(acc[i][4], acc[i][5], acc[i][6], acc[i][7]);
    *(float4*)&Cm[row * 512 + n0 + tx * 8] = o0;
    *(float4*)&Cm[row * 512 + n0 + tx * 8 + 4] = o1;
  }
}

// ---------------------------------------------------------------------------
// focus/keep computation (shared).
// ---------------------------------------------------------------------------
__device__ __forceinline__ void focus_keep(
    const unsigned char* klab, const float* kscr, int* hist8, float* s_var,
    int* s_sk, int* s_ck, int tid, int lane, int wv)
{
  if (tid < GSZ) atomicAdd(&hist8[klab[tid]], 1);
  if (wv == 0) {
    double x0 = (double)kscr[lane], x1 = (double)kscr[lane + 64];
    double s = x0 + x1;
#pragma unroll
    for (int off = 32; off > 0; off >>= 1) s += __shfl_xor(s, off);
    double mean = s * (1.0 / 128.0);
    double d0 = x0 - mean, d1 = x1 - mean;
    double vs = d0 * d0 + d1 * d1;
#pragma unroll
    for (int off = 32; off > 0; off >>= 1) vs += __shfl_xor(vs, off);
    if (lane == 0) *s_var = (float)(vs * (1.0 / 128.0));
  }
  __syncthreads();
  if (tid == 0) {
    int bc = hist8[0];
    for (int l = 1; l < 8; ++l)
      if (hist8[l] > bc) bc = hist8[l];
    float purity = (float)bc * (1.0f / GSZ);
    float focus = 0.5f + 0.25f * purity - 0.25f * (*s_var);
    focus = fminf(fmaxf(focus, 0.25f), 0.75f);
    int keep = (int)ceilf(focus * (float)WSZ);
    keep = min(max(keep, 1), WSZ);
    int ck = keep >> 3, rem = keep & 7;          // round-half-even(keep/8)
    if (rem > 4 || (rem == 4 && (ck & 1))) ck++;
    if (ck < 1) ck = 1;
    int sk = keep - ck;
    if (sk < 1) sk = 1;
    *s_sk = sk;
    *s_ck = ck;
  }
  __syncthreads();
}

// ---------------------------------------------------------------------------
// attn v9 (verbatim — verified 399-401us, absmax 0.0039): QK fp32 VALU
// -> rank (threshold search) -> PV via 3-term split-bf16 MFMA with V^T tile
// staged in LDS. All restructure attempts (R1-R6) lost to restaging/spills;
// this is the known-good operating point.
// ---------------------------------------------------------------------------
__global__ __launch_bounds__(256, 3) void attn_v9(
    const float* __restrict__ q, const float* __restrict__ k,
    const float* __restrict__ vf,
    const int* __restrict__ labels, const float* __restrict__ scores,
    float* __restrict__ attn_out, unsigned short* __restrict__ opl)
{
  const int bx = blockIdx.x;
  const int c = bx >> 10;
  const int rblk = bx & 1023;
  const int h = rblk & 7;
  const int g = (rblk >> 3) & 31;
  const int b = rblk >> 8;
  const int r0 = c * CHUNK;
  const int tid = threadIdx.x;
  const int lane = tid & 63, wv = tid >> 6;
  const int lm = lane & 15, lq = lane >> 4;

  // att row = 264 fp32 (1056 B): fp32 logits, later hosts phi[0..263] (528B)
  // + pmid[0..263] (528B) overlays in the SAME row (wave-private, race-free).
  __shared__ float att[CHUNK][264];
  __shared__ __align__(16) unsigned char vbuf[18432];  // ktile f32[64][68] / vtT u16[2][64][72]
  float (*ktile)[68] = (float (*)[68])vbuf;
  unsigned short* vtT = (unsigned short*)vbuf;         // plane stride 4608 shorts
  __shared__ unsigned char klab[WSZ];
  __shared__ float kscr[WSZ];
  __shared__ int hist8[8];
  __shared__ float s_var;
  __shared__ int s_sk, s_ck;

  {
    int j = tid;
    int pos = g * GSZ + j;
    int tok = pos < NN ? pos : (2 * NN - 1 - pos);
    klab[j] = (unsigned char)labels[b * NN + tok];
    kscr[j] = scores[b * NN + tok];
  }
  if (tid < 8) hist8[tid] = 0;
  __syncthreads();
  focus_keep(klab, kscr, hist8, &s_var, &s_sk, &s_ck, tid, lane, wv);
  const int same_keep = s_sk, cross_keep = s_ck;

  const int rp = tid >> 4, jx = tid & 15;
  const int srow = tid >> 4, sd4 = (tid & 15) * 4;
  const float* q0p = q + (size_t)(b * NN + g * GSZ + r0 + rp) * DIMM + h * DH;
  const float* q1p = q0p + (size_t)16 * DIMM;

  // ---- QK^T: fp32 VALU, arithmetic identical to R8 (selection-critical) ----
  for (int jt = 0; jt < 4; ++jt) {
#pragma unroll
    for (int p = 0; p < 64; p += 16) {
      int j = jt * 64 + srow + p;
      int pos = g * GSZ + j;
      int tok = pos < NN ? pos : (2 * NN - 1 - pos);
      *(float4*)&ktile[srow + p][sd4] =
          *(const float4*)&k[(size_t)(b * NN + tok) * DIMM + h * DH + sd4];
    }
    __syncthreads();
    float acc0[4] = {0.f, 0.f, 0.f, 0.f}, acc1[4] = {0.f, 0.f, 0.f, 0.f};
#pragma unroll
    for (int dd = 0; dd < DH; dd += 4) {
      float4 q0 = *(const float4*)(q0p + dd);
      float4 q1 = *(const float4*)(q1p + dd);
#pragma unroll
      for (int jj = 0; jj < 4; ++jj) {
        float4 kv = *(const float4*)&ktile[jx + 16 * jj][dd];
        acc0[jj] += q0.x * kv.x + q0.y * kv.y + q0.z * kv.z + q0.w * kv.w;
        acc1[jj] += q1.x * kv.x + q1.y * kv.y + q1.z * kv.z + q1.w * kv.w;
      }
    }
#pragma unroll
    for (int jj = 0; jj < 4; ++jj) {
      att[rp][jt * 64 + jx + 16 * jj] = acc0[jj] * 0.125f;
      att[rp + 16][jt * 64 + jx + 16 * jj] = acc1[jj] * 0.125f;
    }
    __syncthreads();
  }

  // ---- rank: identical compute; stores p as in-row bf16 hi/mid overlays ----
  {
    int kl0[4];
    float ks0[4];
#pragma unroll
    for (int m = 0; m < 4; ++m) {
      kl0[m] = klab[lane + 64 * m];
      ks0[m] = kscr[lane + 64 * m];
    }
    for (int sp = 0; sp < 4; ++sp) {
      const int rA = wv * 8 + 2 * sp, rB = rA + 1;
      const int qLA = klab[r0 + rA], qLB = klab[r0 + rB];
      const float qSA = kscr[r0 + rA], qSB = kscr[r0 + rB];
      float aA[4], aB[4];
      float mxA = -INFINITY, mxB = -INFINITY;
#pragma unroll
      for (int m = 0; m < 4; ++m) {
        aA[m] = att[rA][lane + 64 * m];
        aB[m] = att[rB][lane + 64 * m];
        mxA = fmaxf(mxA, aA[m]);
        mxB = fmaxf(mxB, aB[m]);
      }
#pragma unroll
      for (int off = 32; off > 0; off >>= 1) {
        mxA = fmaxf(mxA, __shfl_xor(mxA, off));
        mxB = fmaxf(mxB, __shfl_xor(mxB, off));
      }
      unsigned fsA[4], fcA[4], fsB[4], fcB[4];
      bool cdA[4], cdB[4];
#pragma unroll
      for (int m = 0; m < 4; ++m) {
        aA[m] = expf(aA[m] - mxA);
        aB[m] = expf(aB[m] - mxB);
        cdA[m] = (kl0[m] == qLA);
        cdB[m] = (kl0[m] == qLB);
        fsA[m] = cdA[m] ? __float_as_uint(aA[m]) : 0u;
        fsB[m] = cdB[m] ? __float_as_uint(aB[m]) : 0u;
        fcA[m] = __float_as_uint(aA[m] * (qSA * ks0[m]));
        fcB[m] = __float_as_uint(aB[m] * (qSB * ks0[m]));
      }
      unsigned tsA = 0, tcA = 0, tsB = 0, tcB = 0;
      for (int bit = 29; bit >= 0; --bit) {
        unsigned csA = tsA | (1u << bit), ccA = tcA | (1u << bit);
        unsigned csB = tsB | (1u << bit), ccB = tcB | (1u << bit);
        int nsA = 0, ncA = 0, nsB = 0, ncB = 0;
#pragma unroll
        for (int m = 0; m < 4; ++m) {
          nsA += __popcll(__ballot(fsA[m] >= csA));
          ncA += __popcll(__ballot(fcA[m] >= ccA));
          nsB += __popcll(__ballot(fsB[m] >= csB));
          ncB += __popcll(__ballot(fcB[m] >= ccB));
        }
        if (nsA >= same_keep) tsA = csA;
        if (ncA >= cross_keep) tcA = ccA;
        if (nsB >= same_keep) tsB = csB;
        if (ncB >= cross_keep) tcB = ccB;
      }
#pragma unroll
      for (int rsel = 0; rsel < 2; ++rsel) {
        const int rr = rsel ? rB : rA;
        const unsigned ts = rsel ? tsB : tsA, tc = rsel ? tcB : tcA;
        unsigned* fs = rsel ? fsB : fsA;
        unsigned* fc = rsel ? fcB : fcA;
        float* a = rsel ? aB : aA;
        bool* cand = rsel ? cdB : cdA;
        unsigned long long beqs[4], beqc[4];
        int gts = 0, gtc = 0;
#pragma unroll
        for (int m = 0; m < 4; ++m) {
          gts += __popcll(__ballot(fs[m] > ts));
          gtc += __popcll(__ballot(fc[m] > tc));
          beqs[m] = __ballot(fs[m] == ts);
          beqc[m] = __ballot(fc[m] == tc);
        }
        const int rs = same_keep - gts, rc = cross_keep - gtc;
        float pv[4];
        float S = 0.f;
        int pres = 0, prec = 0;
#pragma unroll
        for (int m = 0; m < 4; ++m) {
          int mbs = __builtin_amdgcn_mbcnt_hi((unsigned)(beqs[m] >> 32),
                     __builtin_amdgcn_mbcnt_lo((unsigned)beqs[m], 0));
          int mbc = __builtin_amdgcn_mbcnt_hi((unsigned)(beqc[m] >> 32),
                     __builtin_amdgcn_mbcnt_lo((unsigned)beqc[m], 0));
          bool keep_s = cand[m] && ((fs[m] > ts) || ((fs[m] == ts) && (pres + mbs < rs)));
          bool keep_c = (!cand[m]) && ((fc[m] > tc) || ((fc[m] == tc) && (prec + mbc < rc)));
          pv[m] = (keep_s || keep_c) ? a[m] : 0.f;
          S += pv[m];
          pres += __popcll(beqs[m]);
          prec += __popcll(beqc[m]);
        }
#pragma unroll
        for (int off = 32; off > 0; off >>= 1) S += __shfl_xor(S, off);
        const float inv = 1.0f / S;
        size_t gb = ((((size_t)b * NGRP + g) * HH + h) * GSZ + (r0 + rr)) * WSZ + lane;
        unsigned short* prow = (unsigned short*)&att[rr][0];
#pragma unroll
        for (int m = 0; m < 4; ++m) {
          float p = pv[m] * inv;
          attn_out[gb + 64 * m] = p;
          unsigned short hh = bf16rne(p);
          prow[lane + 64 * m] = hh;                          // phi
          prow[264 + lane + 64 * m] = bf16rne(p - bf16tof(hh)); // pmid
        }
      }
    }
  }

  // ---- PV via MFMA: D(32x64) = P(32x256) @ V(256x64), 3-term split ----
  f32x4 acc2[2] = {(f32x4){0.f, 0.f, 0.f, 0.f}, (f32x4){0.f, 0.f, 0.f, 0.f}};
  for (int jt = 0; jt < 4; ++jt) {
    __syncthreads();   // overlays done (jt=0) / prior MFMA reads done (jt>0)
    // stage V^T tile: vtT[pl][d][j], 64 j of this jt; pair-packed b32 writes
    {
      const int dx_ = tid & 15, jh = tid >> 4;      // jh 0..15
#pragma unroll
      for (int ps = 0; ps < 2; ++ps) {
        int jl0 = ps * 32 + 2 * jh;
        float4 v0, v1;
#pragma unroll
        for (int qq = 0; qq < 2; ++qq) {
          int pos = g * GSZ + jt * 64 + jl0 + qq;
          int tok = pos < NN ? pos : (2 * NN - 1 - pos);
          float4 vv = *(const float4*)&vf[(size_t)(b * NN + tok) * DIMM + h * DH + dx_ * 4];
          if (qq == 0) v0 = vv; else v1 = vv;
        }
        const float* a0 = (const float*)&v0;
        const float* a1 = (const float*)&v1;
#pragma unroll
        for (int i = 0; i < 4; ++i) {
          int d = dx_ * 4 + i;
          unsigned short h0 = bf16rne(a0[i]);
          unsigned short h1 = bf16rne(a1[i]);
          unsigned short m0 = bf16rne(a0[i] - bf16tof(h0));
          unsigned short m1 = bf16rne(a1[i] - bf16tof(h1));
          *(unsigned*)&vtT[0 * 4608 + d * 72 + jl0] = (unsigned)h0 | ((unsigned)h1 << 16);
          *(unsigned*)&vtT[1 * 4608 + d * 72 + jl0] = (unsigned)m0 | ((unsigned)m1 << 16);
        }
      }
    }
    __syncthreads();
#pragma unroll
    for (int kt = 0; kt < 2; ++kt) {
      const int koff = jt * 64 + kt * 32 + lq * 8;
      short8 ahi[2], ami[2];
#pragma unroll
      for (int mt = 0; mt < 2; ++mt) {
        const unsigned short* arow = (const unsigned short*)&att[mt * 16 + lm][0];
        ahi[mt] = *(const short8*)&arow[koff];
        ami[mt] = *(const short8*)&arow[264 + koff];
      }
      const int vo = (wv * 16 + lm) * 72 + kt * 32 + lq * 8;
      short8 bhi = *(const short8*)&vtT[vo];
      short8 bmi = *(const short8*)&vtT[4608 + vo];
#pragma unroll
      for (int mt = 0; mt < 2; ++mt) {
        acc2[mt] = __builtin_amdgcn_mfma_f32_16x16x32_bf16(ahi[mt], bhi, acc2[mt], 0, 0, 0);
        acc2[mt] = __builtin_amdgcn_mfma_f32_16x16x32_bf16(ahi[mt], bmi, acc2[mt], 0, 0, 0);
        acc2[mt] = __builtin_amdgcn_mfma_f32_16x16x32_bf16(ami[mt], bhi, acc2[mt], 0, 0, 0);
      }
    }
  }

  // ---- o epilogue: C/D col=lane&15 (d), row=lq*4+r (+mt*16); 2 bf16 planes --
  {
    size_t rowbase = (size_t)(b * NN + g * GSZ + r0);
#pragma unroll
    for (int mt = 0; mt < 2; ++mt)
#pragma unroll
      for (int r = 0; r < 4; ++r) {
        int row = mt * 16 + lq * 4 + r;
        float val = acc2[mt][r];
        unsigned short hh = bf16rne(val);
        size_t oaddr = (rowbase + row) * 512 + h * 64 + wv * 16 + lm;
        opl[oaddr] = hh;
        opl[MK + oaddr] = bf16rne(val - bf16tof(hh));
      }
  }
}

// ---------------------------------------------------------------------------
// Fallback attn (fp32 q/k/v in, fp32 o out aliasing q) — small-ws path only.
// ---------------------------------------------------------------------------
__global__ __launch_bounds__(256, 3) void attn_f32(
    const float* q, const float* __restrict__ k, const float* __restrict__ v,
    const int* __restrict__ labels, const float* __restrict__ scores,
    float* __restrict__ attn_out, float* o)
{
  const int bx = blockIdx.x;
  const int c = bx >> 10;
  const int rblk = bx & 1023;
  const int h = rblk & 7;
  const int g = (rblk >> 3) & 31;
  const int b = rblk >> 8;
  const int r0 = c * CHUNK;
  const int tid = threadIdx.x;
  const int lane = tid & 63, wv = tid >> 6;

  __shared__ float att[CHUNK][WSZ + 4];
  __shared__ float ktile[64][DH + 4];
  __shared__ unsigned char klab[WSZ];
  __shared__ float kscr[WSZ];
  __shared__ int hist8[8];
  __shared__ float s_var;
  __shared__ int s_sk, s_ck;

  {
    int j = tid;
    int pos = g * GSZ + j;
    int tok = pos < NN ? pos : (2 * NN - 1 - pos);
    klab[j] = (unsigned char)labels[b * NN + tok];
    kscr[j] = scores[b * NN + tok];
  }
  if (tid < 8) hist8[tid] = 0;
  __syncthreads();
  focus_keep(klab, kscr, hist8, &s_var, &s_sk, &s_ck, tid, lane, wv);
  const int same_keep = s_sk, cross_keep = s_ck;

  const int rp = tid >> 4, jx = tid & 15;
  const int srow = tid >> 4, sd4 = (tid & 15) * 4;
  const float* q0p = q + (size_t)(b * NN + g * GSZ + r0 + rp) * DIMM + h * DH;
  const float* q1p = q0p + (size_t)16 * DIMM;

  for (int jt = 0; jt < 4; ++jt) {
#pragma unroll
    for (int p = 0; p < 64; p += 16) {
      int j = jt * 64 + srow + p;
      int pos = g * GSZ + j;
      int tok = pos < NN ? pos : (2 * NN - 1 - pos);
      *(float4*)&ktile[srow + p][sd4] =
          *(const float4*)&k[(size_t)(b * NN + tok) * DIMM + h * DH + sd4];
    }
    __syncthreads();
    float acc0[4] = {0.f, 0.f, 0.f, 0.f}, acc1[4] = {0.f, 0.f, 0.f, 0.f};
#pragma unroll
    for (int dd = 0; dd < DH; dd += 4) {
      float4 q0 = *(const float4*)(q0p + dd);
      float4 q1 = *(const float4*)(q1p + dd);
#pragma unroll
      for (int jj = 0; jj < 4; ++jj) {
        float4 kv = *(const float4*)&ktile[jx + 16 * jj][dd];
        acc0[jj] += q0.x * kv.x + q0.y * kv.y + q0.z * kv.z + q0.w * kv.w;
        acc1[jj] += q1.x * kv.x + q1.y * kv.y + q1.z * kv.z + q1.w * kv.w;
      }
    }
#pragma unroll
    for (int jj = 0; jj < 4; ++jj) {
      att[rp][jt * 64 + jx + 16 * jj] = acc0[jj] * 0.125f;
      att[rp + 16][jt * 64 + jx + 16 * jj] = acc1[jj] * 0.125f;
    }
    __syncthreads();
  }

  {
    int kl0[4];
    float ks0[4];
#pragma unroll
    for (int m = 0; m < 4; ++m) {
      kl0[m] = klab[lane + 64 * m];
      ks0[m] = kscr[lane + 64 * m];
    }
    for (int sp = 0; sp < 4; ++sp) {
      const int rA = wv * 8 + 2 * sp, rB = rA + 1;
      const int qLA = klab[r0 + rA], qLB = klab[r0 + rB];
      const float qSA = kscr[r0 + rA], qSB = kscr[r0 + rB];
      float aA[4], aB[4];
      float mxA = -INFINITY, mxB = -INFINITY;
#pragma unroll
      for (int m = 0; m < 4; ++m) {
        aA[m] = att[rA][lane + 64 * m];
        aB[m] = att[rB][lane + 64 * m];
        mxA = fmaxf(mxA, aA[m]);
        mxB = fmaxf(mxB, aB[m]);
      }
#pragma unroll
      for (int off = 32; off > 0; off >>= 1) {
        mxA = fmaxf(mxA, __shfl_xor(mxA, off));
        mxB = fmaxf(mxB, __shfl_xor(mxB, off));
      }
      unsigned fsA[4], fcA[4], fsB[4], fcB[4];
      bool cdA[4], cdB[4];
#pragma unroll
      for (int m = 0; m < 4; ++m) {
        aA[m] = expf(aA[m] - mxA);
        aB[m] = expf(aB[m] - mxB);
        cdA[m] = (kl0[m] == qLA);
        cdB[m] = (kl0[m] == qLB);
        fsA[m] = cdA[m] ? __float_as_uint(aA[m]) : 0u;
        fsB[m] = cdB[m] ? __float_as_uint(aB[m]) : 0u;
        fcA[m] = __float_as_uint(aA[m] * (qSA * ks0[m]));
        fcB[m] = __float_as_uint(aB[m] * (qSB * ks0[m]));
      }
      unsigned tsA = 0, tcA = 0, tsB = 0, tcB = 0;
      for (int bit = 29; bit >= 0; --bit) {
        unsigned csA = tsA | (1u << bit), ccA = tcA | (1u << bit);
        unsigned csB = tsB | (1u << bit), ccB = tcB | (1u << bit);
        int nsA = 0, ncA = 0, nsB = 0, ncB = 0;
#pragma unroll
        for (int m = 0; m < 4; ++m) {
          nsA += __popcll(__ballot(fsA[m] >= csA));
          ncA += __popcll(__ballot(fcA[m] >= ccA));
          nsB += __popcll(__ballot(fsB[m] >= csB));
          ncB += __popcll(__ballot(fcB[m] >= ccB));
        }
        if (nsA >= same_keep) tsA = csA;
        if (ncA >= cross_keep) tcA = ccA;
        if (nsB >= same_keep) tsB = csB;
        if (ncB >= cross_keep) tcB = ccB;
      }
#pragma unroll
      for (int rsel = 0; rsel < 2; ++rsel) {
        const int rr = rsel ? rB : rA;
        const unsigned ts = rsel ? tsB : tsA, tc = rsel ? tcB : tcA;
        unsigned* fs = rsel ? fsB : fsA;
        unsigned* fc = rsel ? fcB : fcA;
        float* a = rsel ? aB : aA;
        bool* cand = rsel ? cdB : cdA;
        unsigned long long beqs[4], beqc[4];
        int gts = 0, gtc = 0;
#pragma unroll
        for (int m = 0; m < 4; ++m) {
          gts += __popcll(__ballot(fs[m] > ts));
          gtc += __popcll(__ballot(fc[m] > tc));
          beqs[m] = __ballot(fs[m] == ts);
          beqc[m] = __ballot(fc[m] == tc);
        }
        const int rs = same_keep - gts, rc = cross_keep - gtc;
        float pv[4];
        float S = 0.f;
        int pres = 0, prec = 0;
#pragma unroll
        for (int m = 0; m < 4; ++m) {
          int mbs = __builtin_amdgcn_mbcnt_hi((unsigned)(beqs[m] >> 32),
                     __builtin_amdgcn_mbcnt_lo((unsigned)beqs[m], 0));
          int mbc = __builtin_amdgcn_mbcnt_hi((unsigned)(beqc[m] >> 32),
                     __builtin_amdgcn_mbcnt_lo((unsigned)beqc[m], 0));
          bool keep_s = cand[m] && ((fs[m] > ts) || ((fs[m] == ts) && (pres + mbs < rs)));
          bool keep_c = (!cand[m]) && ((fc[m] > tc) || ((fc[m] == tc) && (prec + mbc < rc)));
          pv[m] = (keep_s || keep_c) ? a[m] : 0.f;
          S += pv[m];
          pres += __popcll(beqs[m]);
          prec += __popcll(beqc[m]);
        }
#pragma unroll
        for (int off = 32; off > 0; off >>= 1) S += __shfl_xor(S, off);
        const float inv = 1.0f / S;
        size_t gb = ((((size_t)b * NGRP + g) * HH + h) * GSZ + (r0 + rr)) * WSZ + lane;
#pragma unroll
        for (int m = 0; m < 4; ++m) {
          float p = pv[m] * inv;
          att[rr][lane + 64 * m] = p;
          attn_out[gb + 64 * m] = p;
        }
      }
    }
  }
  __syncthreads();

  const int dx = jx;
  float oa0[4] = {0.f, 0.f, 0.f, 0.f}, oa1[4] = {0.f, 0.f, 0.f, 0.f};
  for (int jt = 0; jt < 4; ++jt) {
#pragma unroll
    for (int p = 0; p < 64; p += 16) {
      int j = jt * 64 + srow + p;
      int pos = g * GSZ + j;
      int tok = pos < NN ? pos : (2 * NN - 1 - pos);
      *(float4*)&ktile[srow + p][sd4] =
          *(const float4*)&v[(size_t)(b * NN + tok) * DIMM + h * DH + sd4];
    }
    __syncthreads();
#pragma unroll 4
    for (int jg = 0; jg < 16; ++jg) {
      float4 p0 = *(const float4*)&att[rp][jt * 64 + jg * 4];
      float4 p1 = *(const float4*)&att[rp + 16][jt * 64 + jg * 4];
      float4 v0 = *(const float4*)&ktile[jg * 4 + 0][dx * 4];
      float4 v1 = *(const float4*)&ktile[jg * 4 + 1][dx * 4];
      float4 v2 = *(const float4*)&ktile[jg * 4 + 2][dx * 4];
      float4 v3 = *(const float4*)&ktile[jg * 4 + 3][dx * 4];
      oa0[0] += p0.x * v0.x + p0.y * v1.x + p0.z * v2.x + p0.w * v3.x;
      oa0[1] += p0.x * v0.y + p0.y * v1.y + p0.z * v2.y + p0.w * v3.y;
      oa0[2] += p0.x * v0.z + p0.y * v1.z + p0.z * v2.z + p0.w * v3.z;
      oa0[3] += p0.x * v0.w + p0.y * v1.w + p0.z * v2.w + p0.w * v3.w;
      oa1[0] += p1.x * v0.x + p1.y * v1.x + p1.z * v2.x + p1.w * v3.x;
      oa1[1] += p1.x * v0.y + p1.y * v1.y + p1.z * v2.y + p1.w * v3.y;
      oa1[2] += p1.x * v0.z + p1.y * v1.z + p1.z * v2.z + p1.w * v3.z;
      oa1[3] += p1.x * v0.w + p1.y * v1.w + p1.z * v2.w + p1.w * v3.w;
    }
    __syncthreads();
  }
  {
    size_t ob0 = (size_t)(b * NN + g * GSZ + r0 + rp) * DIMM + h * DH + dx * 4;
    *(float4*)&o[ob0] = make_float4(oa0[0], oa0[1], oa0[2], oa0[3]);
    *(float4*)&o[ob0 + (size_t)16 * DIMM] = make_float4(oa1[0], oa1[1], oa1[2], oa1[3]);
  }
}

// ---------------------------------------------------------------------------
extern "C" void kernel_launch(void* const* d_in, const int* in_sizes, int n_in,
                              void* d_out, int out_size, void* d_ws, size_t ws_size,
                              hipStream_t stream) {
  const float* x      = (const float*)d_in[0];
  const int*   labels = (const int*)d_in[1];
  const float* scores = (const float*)d_in[2];
  const float* Wq     = (const float*)d_in[3];
  const float* Wk     = (const float*)d_in[4];
  const float* Wv     = (const float*)d_in[5];
  const float* Wproj  = (const float*)d_in[6];

  float* out = (float*)d_out;                               // (B, N, DIM)
  float* attn_out = out + (size_t)BB * NN * DIMM;           // (B, ng, H, gs, ws)

  // layout: qb|kb|vf (fp32) | xpl (3 planes; reused as opl) | weights
  float* qb = (float*)d_ws;
  float* kb = qb + (size_t)MK;
  float* vf = kb + (size_t)MK;
  unsigned short* xpl  = (unsigned short*)(vf + (size_t)MK);
  unsigned short* wqkv = xpl + 3 * (size_t)MK;
  unsigned short* wpp  = wqkv + 9 * (size_t)WK;
  const size_t required = 3 * (size_t)MK * 4 + 3 * (size_t)MK * 2 + 11 * (size_t)WK * 2;

  if (ws_size >= required) {
    split_planes<<<dim3(MK / 1024), 256, 0, stream>>>(x, xpl);
    split_w<<<dim3(4 * WK / 256), 256, 0, stream>>>(Wq, Wk, Wv, Wproj, wqkv, wpp);
    // q,k fp32 via 6-term + v 3-term in ONE 1536-block launch (2 exact
    // occupancy rounds at 3 blocks/CU), XCD-chunked work assignment.
    mfma_gemm_qkv<<<dim3(1536), 256, 0, stream>>>(xpl, wqkv, qb, vf);
    attn_v9<<<dim3(BB * NGRP * HH * 4), 256, 0, stream>>>(
        qb, kb, vf, labels, scores, attn_out, xpl);
    mfma_gemm_pj<<<dim3(512), 256, 0, stream>>>(xpl, wpp, out);
  } else {
    const size_t SZ = (size_t)BB * NN * DIMM;
    float* q2 = (float*)d_ws;
    float* k2 = q2 + SZ;
    float* v2 = k2 + SZ;
    gemm512<<<dim3(4, 128, 3), 256, 0, stream>>>(x, Wq, Wk, Wv, q2, k2, v2);
    attn_f32<<<dim3(BB * NGRP * HH * 4), 256, 0, stream>>>(
        q2, k2, v2, labels, scores, attn_out, q2);
    gemm512<<<dim3(4, 128, 1), 256, 0, stream>>>(q2, Wproj, Wproj, Wproj, out, out, out);
  }
}